// Round 3
// baseline (255.393 us; speedup 1.0000x reference)
//
#include <hip/hip_runtime.h>

#define NW 14
#define NL 3
#define NGAT 42            // 3 layers x 14 rotation gates
#define DIM 16384          // 2^14 amplitudes
#define BLOCK 1024

// ---------------------------------------------------------------------------
// MFMA formulation (round 9) with WRITER-FRAME layout (round 10/11).
// Round 14: LATENCY-BOUND restructure. Evidence: r12 (same VALU count, moved
// between phases) changed time +7%; r13 (+10% bank conflicts) changed time 0%
// -> neither VALU-throughput nor LDS-conflict bound; the 24 lockstep barriers
// serialize read-latency, splitpk chains, and MFMA latency. Fix: move the
// MFMAs ABOVE the mid-batch barrier (it only protects the in-place stores):
//   bar -> [all 16 scattered reads | build NEXT batch's A-table | convert |
//           24 mfma -> regs] -> bar -> [8 clean b128 stores] -> bar
// A-table is double-buffered (batch r builds r+1's table concurrently with
// its own reads; +4KiB static LDS). One extra startup barrier seeds atab[0].
// Twist reverted to legacy (2,4,8) — r13's searched twist measured MORE
// conflicts (model wrong) and zero time delta.
// Arithmetic order is bit-identical to r11 (same splitpk, same mfma order).
// ---------------------------------------------------------------------------

typedef float        f4  __attribute__((ext_vector_type(4)));
typedef short        s8v __attribute__((ext_vector_type(8)));
typedef unsigned int u4v __attribute__((ext_vector_type(4)));

constexpr int parity14(int v) { int p = 0; for (int i = 0; i < NW; ++i) p ^= (v >> i) & 1; return p; }
constexpr int hibit(int v) { int h = -1; for (int i = 0; i < NW; ++i) if ((v >> i) & 1) h = i; return h; }

struct Lin { int col[NW]; };

constexpr int lin_apply(const Lin& M, int x) {
    int r = 0;
    for (int i = 0; i < NW; ++i) if ((x >> i) & 1) r ^= M.col[i];
    return r;
}
constexpr Lin lin_inverse(const Lin& M) {
    int E[NW] = {}, P[NW] = {};
    for (int i = 0; i < NW; ++i) {
        int v = M.col[i], p = 1 << i;
        while (v) {
            int h = hibit(v);
            if (!E[h]) { E[h] = v; P[h] = p; break; }
            v ^= E[h]; p ^= P[h];
        }
    }
    Lin R{};
    for (int i = 0; i < NW; ++i) {
        int v = 1 << i, p = 0;
        while (v) { int h = hibit(v); v ^= E[h]; p ^= P[h]; }
        R.col[i] = p;
    }
    return R;
}
constexpr Lin lin_compose(const Lin& A, const Lin& B) {
    Lin R{};
    for (int i = 0; i < NW; ++i) R.col[i] = lin_apply(A, B.col[i]);
    return R;
}

// ---- algorithm structure (frames, cosets, duality corrections) ----
struct Alg {
    int ngates[12];
    int gidx[12][4];
    int basisA[12][4];
    int comboA[12][16];
    int cvecA[12][10];
    Lin F[12];
    int Rf[NW];         // final Z-row masks for the tail features
};

constexpr Alg make_alg() {
    Alg A{};
    int R[NW] = {}, C[NW] = {};
    for (int p = 0; p < NW; ++p) { R[p] = 1 << p; C[p] = 1 << p; }
    int bi = 0;
    for (int l = 0; l < NL; ++l) {
        const int sizes[4] = {4, 4, 4, 2};
        int w0 = 0;
        for (int s = 0; s < 4; ++s) {
            const int ng = sizes[s];
            A.ngates[bi] = ng;
            int basis[4] = {}, rr[4] = {};
            for (int j = 0; j < ng; ++j) {
                int w = w0 + j, p = 13 - w;
                basis[j] = C[p];
                rr[j] = R[p];
                A.gidx[bi][j] = l * NW + w;
            }
            // echelon for independence
            int ech[4] = {}; int ne = 0;
            for (int j = 0; j < ng; ++j) {
                int v = basis[j];
                bool ch = true;
                while (ch) { ch = false;
                    for (int k = 0; k < ne; ++k)
                        if (v && ((v >> hibit(ech[k])) & 1)) { v ^= ech[k]; ch = true; }
                }
                ech[ne++] = v;
            }
            // pad to 4 from null space of gate parity masks
            int nb = ng;
            for (int cand = 1; cand < DIM && nb < 4; ++cand) {
                bool ok = true;
                for (int j = 0; j < ng; ++j) if (parity14(cand & rr[j])) { ok = false; break; }
                if (!ok) continue;
                int v = cand;
                bool ch = true;
                while (ch) { ch = false;
                    for (int k = 0; k < ne; ++k)
                        if (v && ((v >> hibit(ech[k])) & 1)) { v ^= ech[k]; ch = true; }
                }
                if (v) { basis[nb++] = cand; ech[ne++] = v; }
            }
            // pivots & non-pivot positions
            int piv[4] = {};
            for (int k = 0; k < 4; ++k) piv[k] = hibit(ech[k]);
            for (int a = 0; a < 4; ++a)
                for (int b2 = a + 1; b2 < 4; ++b2)
                    if (piv[b2] < piv[a]) { int t = piv[a]; piv[a] = piv[b2]; piv[b2] = t; }
            int npp[10] = {}; int nn = 0;
            for (int bit = 0; bit < NW; ++bit) {
                bool isp = false;
                for (int k = 0; k < 4; ++k) if (piv[k] == bit) isp = true;
                if (!isp) npp[nn++] = bit;
            }
            // duality-corrected coset directions
            for (int k = 0; k < 10; ++k) {
                int c = 1 << npp[k];
                for (int j = 0; j < ng; ++j) if ((rr[j] >> npp[k]) & 1) c ^= basis[j];
                A.cvecA[bi][k] = c;
            }
            for (int e = 0; e < 16; ++e) {
                int v = 0;
                for (int j = 0; j < 4; ++j) if ((e >> j) & 1) v ^= basis[j];
                A.comboA[bi][e] = v;
            }
            for (int j = 0; j < 4; ++j) A.basisA[bi][j] = basis[j];
            for (int j = 0; j < 4; ++j) A.F[bi].col[j] = basis[j];
            for (int k = 0; k < 10; ++k) A.F[bi].col[4 + k] = A.cvecA[bi][k];
            w0 += ng;
            ++bi;
        }
        // CNOT chain (w,w+1) w=0..12 then (13,0)
        for (int w = 0; w < NW; ++w) {
            int c = w, t = (w + 1) % NW;
            int pc = 13 - c, pt = 13 - t;
            R[pt] ^= R[pc];
            C[pc] ^= C[pt];
        }
    }
    for (int p = 0; p < NW; ++p) A.Rf[p] = R[p];
    return A;
}

// ---- legacy twist (r13's searched twist measured MORE conflicts; reverted) ----
struct Twist { unsigned t[10]; };
constexpr Twist find_twist() {
    Twist best{};
    best.t[0] = 2; best.t[1] = 4; best.t[2] = 8;
    for (int k = 3; k < 10; ++k) best.t[k] = 0;
    return best;
}
constexpr Twist TW = find_twist();

struct BatchP {
    int ngates;
    int gidx[4];
    unsigned rdy[10];   // byte: 8 * Lambda_{r-1}(cvec_r[k])  (y-bit directions)
    unsigned rde[16];   // byte: 8 * Lambda_{r-1}(combo_r[e]) (e-directions)
};
struct PlanP {
    BatchP b[12];
    unsigned stB[14];   // staging: byte 8 * Lambda_0(1<<bit)
    unsigned ykey[14];  // tail: parity mask over key = y | (q<<10)
    int zsel[14];       // tail: Walsh index from basis[0,1] parities
    unsigned tw[10];    // T twist columns (idx units)
};

constexpr PlanP make_planp() {
    Alg A = make_alg();
    PlanP P{};
    for (int bi = 0; bi < 12; ++bi) {
        P.b[bi].ngates = A.ngates[bi];
        for (int j = 0; j < 4; ++j) P.b[bi].gidx[j] = A.gidx[bi][j];
    }
    // T: packed(e, y) -> idx = e ^ (y<<4) ^ twist(y)
    Lin T{};
    for (int j = 0; j < 4; ++j) T.col[j] = 1 << j;
    for (int k = 0; k < 10; ++k) T.col[4 + k] = (1 << (4 + k)) ^ (int)TW.t[k];

    // Lambda_w = T o F_w^{-1}; staging uses Lambda_0, reader r uses Lambda_{r-1}
    {
        Lin L0 = lin_compose(T, lin_inverse(A.F[0]));
        for (int bit = 0; bit < NW; ++bit) P.stB[bit] = (unsigned)lin_apply(L0, 1 << bit) * 8u;
    }
    for (int r = 1; r < 12; ++r) {
        Lin Lw = lin_compose(T, lin_inverse(A.F[r - 1]));
        for (int k = 0; k < 10; ++k) P.b[r].rdy[k] = (unsigned)lin_apply(Lw, A.cvecA[r][k]) * 8u;
        for (int e = 0; e < 16; ++e) P.b[r].rde[e] = (unsigned)lin_apply(Lw, A.comboA[r][e]) * 8u;
    }
    for (int w = 0; w < NW; ++w) {
        int zrw = A.Rf[13 - w];
        unsigned ym = 0;
        for (int k = 0; k < 10; ++k) ym |= (unsigned)parity14(A.cvecA[11][k] & zrw) << k;
        int qm = parity14(A.basisA[11][2] & zrw) | (parity14(A.basisA[11][3] & zrw) << 1);
        P.ykey[w] = ym | ((unsigned)qm << 10);
        P.zsel[w] = parity14(A.basisA[11][0] & zrw) | (parity14(A.basisA[11][1] & zrw) << 1);
    }
    for (int k = 0; k < 10; ++k) P.tw[k] = TW.t[k];
    return P;
}

constexpr PlanP PL = make_planp();

// per-tile byte offsets in the writer frame: y bits 4,5 plus their twists
constexpr unsigned TILE_OFF[4] = {
    0u,
    (1u << 11) ^ (PL.tw[4] << 3),
    (1u << 12) ^ (PL.tw[5] << 3),
    (1u << 11) ^ (1u << 12) ^ ((PL.tw[4] ^ PL.tw[5]) << 3)
};

// fp32 (r,i) -> packed bf16 hi dword + lo dword. hi = truncation (lo absorbs
// the residual; round only lo) — 8 VALU.
__device__ __forceinline__ void splitpk(float r, float i, unsigned& hi, unsigned& lo) {
    const unsigned tr = __float_as_uint(r);
    const unsigned ti = __float_as_uint(i);
    hi = __builtin_amdgcn_perm(ti, tr, 0x07060302u);
    const float lr = r - __uint_as_float(tr & 0xffff0000u);
    const float li = i - __uint_as_float(ti & 0xffff0000u);
    const unsigned ur = __float_as_uint(lr) + 0x8000u;
    const unsigned ui = __float_as_uint(li) + 0x8000u;
    lo = __builtin_amdgcn_perm(ui, ur, 0x07060302u);
}

__device__ __forceinline__ f4 mf(u4v a, u4v b, f4 c) {
    return __builtin_amdgcn_mfma_f32_16x16x32_bf16(
        __builtin_bit_cast(s8v, a), __builtin_bit_cast(s8v, b), c, 0, 0, 0);
}

// scattered-read base for reader batch B: XOR-select over y-bits (n,wid) and
// q-part; per-tile t adds rdy[4]/rdy[5]; 4 entries at {0, rde1, rde2, rde3}.
#define RD_SREP(B)                                                     \
    unsigned srep = 0;                                                 \
    srep ^= (n & 1u)   ? B.rdy[0] : 0u;                                \
    srep ^= (n & 2u)   ? B.rdy[1] : 0u;                                \
    srep ^= (n & 4u)   ? B.rdy[2] : 0u;                                \
    srep ^= (n & 8u)   ? B.rdy[3] : 0u;                                \
    srep ^= (wid & 1u) ? B.rdy[6] : 0u;                                \
    srep ^= (wid & 2u) ? B.rdy[7] : 0u;                                \
    srep ^= (wid & 4u) ? B.rdy[8] : 0u;                                \
    srep ^= (wid & 8u) ? B.rdy[9] : 0u;                                \
    srep ^= (q & 1u)   ? B.rde[4] : 0u;                                \
    srep ^= (q & 2u)   ? B.rde[8] : 0u;

// build the 4 A-tables (16x32 bf16 hi/lo, real & imag row pairs) for batch BI
// into 'at' (1024 dwords). Call under (tid < 256).
template <int BI>
__device__ __forceinline__ void build_atab(const float* __restrict__ gm,
                                           unsigned* __restrict__ at) {
    constexpr BatchP B = PL.b[BI];
    const unsigned tid = threadIdx.x;
    const unsigned m = tid >> 4, ein = tid & 15u;
    float wr = 1.f, wi = 0.f;
    #pragma unroll
    for (int j = 0; j < 4; ++j) {
        if (j < B.ngates) {
            const unsigned mj = (m >> j) & 1u, ej = (ein >> j) & 1u;
            const float ur = gm[B.gidx[j] * 8 + (int)(mj * 4u + ej * 2u)];
            const float ui = gm[B.gidx[j] * 8 + (int)(mj * 4u + ej * 2u) + 1];
            const float nr = wr * ur - wi * ui;
            const float ni = wr * ui + wi * ur;
            wr = nr; wi = ni;
        }
    }
    if (B.ngates < 4 && (((m ^ ein) >> B.ngates) != 0u)) { wr = 0.f; wi = 0.f; }
    unsigned twr = __float_as_uint(wr) + 0x8000u;
    unsigned twi = __float_as_uint(wi) + 0x8000u;
    float lr = wr - __uint_as_float(twr & 0xffff0000u);
    float li = wi - __uint_as_float(twi & 0xffff0000u);
    unsigned tlr = __float_as_uint(lr) + 0x8000u;
    unsigned tli = __float_as_uint(li) + 0x8000u;
    const unsigned o = m * 16u + ein;
    at[o]        = __builtin_amdgcn_perm(twi ^ 0x80000000u, twr, 0x07060302u); // (Wr_hi,-Wi_hi)
    at[256 + o]  = __builtin_amdgcn_perm(tli ^ 0x80000000u, tlr, 0x07060302u); // (Wr_lo,-Wi_lo)
    at[512 + o]  = __builtin_amdgcn_perm(twr, twi, 0x07060302u);               // (Wi_hi, Wr_hi)
    at[768 + o]  = __builtin_amdgcn_perm(tlr, tli, 0x07060302u);               // (Wi_lo, Wr_lo)
}

// one mfma batch. Entry contract: preceded by a barrier with state readable
// and atab buffer (BI&1) ready. Exit: state updated, trailing barrier done.
template <int BI>
__device__ __forceinline__ void mfma_batch(char* __restrict__ lds, const float* __restrict__ gm,
                                           unsigned* __restrict__ atab, const unsigned bnq) {
    constexpr BatchP B = PL.b[BI];
    const unsigned tid = threadIdx.x;
    const unsigned lane = tid & 63u, wid = tid >> 6;
    const unsigned n = lane & 15u, q = lane >> 4;
    const unsigned* __restrict__ acur = atab + (BI & 1) * 1024;
    unsigned* __restrict__ anxt = atab + ((BI + 1) & 1) * 1024;

    // ---- main region: reads | next-atab build | convert | mfma -> regs ----
    const u4v A0 = *(const u4v*)&acur[(n << 4) + (q << 2)];
    const u4v A1 = *(const u4v*)&acur[256 + (n << 4) + (q << 2)];
    const u4v A2 = *(const u4v*)&acur[512 + (n << 4) + (q << 2)];
    const u4v A3 = *(const u4v*)&acur[768 + (n << 4) + (q << 2)];

    f4 ar[4], ai[4];
    if constexpr (BI == 0) {
        f4 v01[4], v23[4];
        #pragma unroll
        for (int t = 0; t < 4; ++t) {
            const unsigned a0 = bnq ^ TILE_OFF[t];
            v01[t] = *(const f4*)(lds + a0);
            v23[t] = *(const f4*)(lds + (a0 ^ 16u));
        }
        if (tid < 256) build_atab<BI + 1>(gm, anxt);
        #pragma unroll
        for (int t = 0; t < 4; ++t) {
            unsigned h0, l0, h1, l1, h2, l2, h3, l3;
            splitpk(v01[t].x, v01[t].y, h0, l0);
            splitpk(v01[t].z, v01[t].w, h1, l1);
            splitpk(v23[t].x, v23[t].y, h2, l2);
            splitpk(v23[t].z, v23[t].w, h3, l3);
            u4v h; h.x = h0; h.y = h1; h.z = h2; h.w = h3;
            u4v l; l.x = l0; l.y = l1; l.z = l2; l.w = l3;
            f4 r_ = {0.f, 0.f, 0.f, 0.f};
            f4 i_ = {0.f, 0.f, 0.f, 0.f};
            r_ = mf(A0, h, r_);
            i_ = mf(A2, h, i_);
            r_ = mf(A1, h, r_);
            i_ = mf(A3, h, i_);
            r_ = mf(A0, l, r_);
            i_ = mf(A2, l, i_);
            ar[t] = r_; ai[t] = i_;
        }
    } else {
        RD_SREP(B)
        float2 c[4][4];
        #pragma unroll
        for (int t = 0; t < 4; ++t) {
            const unsigned st = srep ^ ((t & 1) ? B.rdy[4] : 0u) ^ ((t & 2) ? B.rdy[5] : 0u);
            c[t][0] = *(const float2*)(lds + st);
            c[t][1] = *(const float2*)(lds + (st ^ B.rde[1]));
            c[t][2] = *(const float2*)(lds + (st ^ B.rde[2]));
            c[t][3] = *(const float2*)(lds + (st ^ B.rde[3]));
        }
        if constexpr (BI < 10) { if (tid < 256) build_atab<BI + 1>(gm, anxt); }
        #pragma unroll
        for (int t = 0; t < 4; ++t) {
            unsigned h0, l0, h1, l1, h2, l2, h3, l3;
            splitpk(c[t][0].x, c[t][0].y, h0, l0);
            splitpk(c[t][1].x, c[t][1].y, h1, l1);
            splitpk(c[t][2].x, c[t][2].y, h2, l2);
            splitpk(c[t][3].x, c[t][3].y, h3, l3);
            u4v h; h.x = h0; h.y = h1; h.z = h2; h.w = h3;
            u4v l; l.x = l0; l.y = l1; l.z = l2; l.w = l3;
            f4 r_ = {0.f, 0.f, 0.f, 0.f};
            f4 i_ = {0.f, 0.f, 0.f, 0.f};
            r_ = mf(A0, h, r_);
            i_ = mf(A2, h, i_);
            r_ = mf(A1, h, r_);
            i_ = mf(A3, h, i_);
            r_ = mf(A0, l, r_);
            i_ = mf(A2, l, i_);
            ar[t] = r_; ai[t] = i_;
        }
    }

    __syncthreads();   // all reads done (WAR) + anxt ready

    // ---- store region: clean writer-frame b128 stores ----
    #pragma unroll
    for (int t = 0; t < 4; ++t) {
        const unsigned a0 = bnq ^ TILE_OFF[t];
        const f4 s01 = {ar[t].x, ai[t].x, ar[t].y, ai[t].y};
        const f4 s23 = {ar[t].z, ai[t].z, ar[t].w, ai[t].w};
        *(f4*)(lds + a0)         = s01;
        *(f4*)(lds + (a0 ^ 16u)) = s23;
    }
    __syncthreads();   // stores visible for next batch
}

// complex 2x2 butterfly
#define BFC(A, B_, ua, ub) { const float2 t0 = A, t1 = B_; \
    A.x  = ua.x * t0.x - ua.y * t0.y + ua.z * t1.x - ua.w * t1.y; \
    A.y  = ua.x * t0.y + ua.y * t0.x + ua.z * t1.y + ua.w * t1.x; \
    B_.x = ub.x * t0.x - ub.y * t0.y + ub.z * t1.x - ub.w * t1.y; \
    B_.y = ub.x * t0.y + ub.y * t0.x + ub.z * t1.y + ub.w * t1.x; }

__device__ __forceinline__ float tail_batch(char* __restrict__ lds, const float* __restrict__ gm,
                                            const float* __restrict__ g_hw) {
    constexpr BatchP B = PL.b[11];   // ngates == 2
    const unsigned tid = threadIdx.x;
    const unsigned lane = tid & 63u, wid = tid >> 6;
    const unsigned n = lane & 15u, q = lane >> 4;
    // entry: mfma_batch<10>'s trailing barrier already done — no sync needed
    const f4 u0a = *(const f4*)&gm[B.gidx[0] * 8];
    const f4 u0b = *(const f4*)&gm[B.gidx[0] * 8 + 4];
    const f4 u1a = *(const f4*)&gm[B.gidx[1] * 8];
    const f4 u1b = *(const f4*)&gm[B.gidx[1] * 8 + 4];
    float hwv[NW];
    #pragma unroll
    for (int w = 0; w < NW; ++w) hwv[w] = g_hw[w];
    float acc = 0.f;
    RD_SREP(B)
    #pragma unroll
    for (int t = 0; t < 4; ++t) {
        const unsigned st = srep ^ ((t & 1) ? B.rdy[4] : 0u) ^ ((t & 2) ? B.rdy[5] : 0u);
        float2 c0 = *(const float2*)(lds + st);
        float2 c1 = *(const float2*)(lds + (st ^ B.rde[1]));
        float2 c2 = *(const float2*)(lds + (st ^ B.rde[2]));
        float2 c3 = *(const float2*)(lds + (st ^ B.rde[3]));
        BFC(c0, c1, u0a, u0b)  BFC(c2, c3, u0a, u0b)   // gate 0: slot bit 0
        BFC(c0, c2, u1a, u1b)  BFC(c1, c3, u1a, u1b)   // gate 1: slot bit 1
        const float p0 = c0.x * c0.x + c0.y * c0.y;
        const float p1 = c1.x * c1.x + c1.y * c1.y;
        const float p2 = c2.x * c2.x + c2.y * c2.y;
        const float p3 = c3.x * c3.x + c3.y * c3.y;
        const float sa = p0 + p1, sb = p0 - p1, sc = p2 + p3, sd = p2 - p3;
        const float W4[4] = {sa + sc, sb + sd, sa - sc, sb - sd};
        const unsigned y = (wid << 6) | ((unsigned)t << 4) | n;
        const unsigned key = y | (q << 10);
        #pragma unroll
        for (int w = 0; w < NW; ++w) {
            const unsigned sg = ((unsigned)__popc(key & PL.ykey[w])) << 31;
            const float s = __uint_as_float(__float_as_uint(hwv[w]) ^ sg);
            acc += W4[PL.zsel[w]] * s;
        }
    }
    return acc;
}

__global__ __launch_bounds__(BLOCK) void qsim_kernel(
    const float* __restrict__ g_sr, const float* __restrict__ g_si,
    const float* __restrict__ g_params, const float* __restrict__ g_hw,
    const float* __restrict__ g_hb, float* __restrict__ g_out)
{
    extern __shared__ char lds[];                    // 16384 float2 entries (128 KiB)
    __shared__ __align__(16) float gm[NGAT * 8];
    __shared__ __align__(16) unsigned atab[2048];    // DOUBLE-buffered A-tables (2 x 4KiB)
    __shared__ float red[BLOCK / 64];

    const unsigned tid = threadIdx.x;
    const int b = blockIdx.x;
    const float* __restrict__ srcr = g_sr + (size_t)b * DIM;
    const float* __restrict__ srci = g_si + (size_t)b * DIM;

    // ---- gate matrices U = RZ @ RY @ RX ----
    if (tid < NGAT) {
        const float tx = g_params[tid * 3 + 0];
        const float ty = g_params[tid * 3 + 1];
        const float tz = g_params[tid * 3 + 2];
        const float cx = cosf(0.5f * tx), sx = sinf(0.5f * tx);
        const float cy = cosf(0.5f * ty), sy = sinf(0.5f * ty);
        const float cz = cosf(0.5f * tz), sz = sinf(0.5f * tz);
        const float a00r = cy * cx,  a00i = sy * sx;
        const float a01r = -sy * cx, a01i = -cy * sx;
        const float a10r = sy * cx,  a10i = -cy * sx;
        const float a11r = cy * cx,  a11i = -sy * sx;
        gm[tid * 8 + 0] = cz * a00r + sz * a00i;
        gm[tid * 8 + 1] = cz * a00i - sz * a00r;
        gm[tid * 8 + 2] = cz * a01r + sz * a01i;
        gm[tid * 8 + 3] = cz * a01i - sz * a01r;
        gm[tid * 8 + 4] = cz * a10r - sz * a10i;
        gm[tid * 8 + 5] = cz * a10i + sz * a10r;
        gm[tid * 8 + 6] = cz * a11r - sz * a11i;
        gm[tid * 8 + 7] = cz * a11i + sz * a11r;
    }

    // writer-frame base for this thread (computed ONCE; T twist folded in)
    const unsigned lane0 = tid & 63u, wid0 = tid >> 6;
    const unsigned n0 = lane0 & 15u, q0 = lane0 >> 4;
    unsigned twv = 0;
    #pragma unroll
    for (int k = 0; k < 4; ++k) twv ^= ((n0 >> k) & 1u) ? PL.tw[k] : 0u;
    #pragma unroll
    for (int k = 0; k < 4; ++k) twv ^= ((wid0 >> k) & 1u) ? PL.tw[6 + k] : 0u;
    const unsigned bnq = ((wid0 << 10) ^ (n0 << 4) ^ (q0 << 2) ^ twv) << 3;

    // ---- staging: global fp32 -> Lambda_0 layout (so batch 0 reads clean T) ----
    unsigned bb = 0;
    #pragma unroll
    for (int k = 0; k < 10; ++k) bb ^= ((tid >> k) & 1u) ? PL.stB[k + 2] : 0u;
    #pragma unroll
    for (int it = 0; it < 4; ++it) {
        const int x = (int)tid * 4 + it * 4096;
        const f4 r4 = *(const f4*)(srcr + x);
        const f4 i4 = *(const f4*)(srci + x);
        const unsigned base = bb ^ ((it & 1) ? PL.stB[12] : 0u) ^ ((it & 2) ? PL.stB[13] : 0u);
        *(float2*)(lds + base) = make_float2(r4.x, i4.x);
        *(float2*)(lds + (base ^ PL.stB[0])) = make_float2(r4.y, i4.y);
        *(float2*)(lds + (base ^ PL.stB[1])) = make_float2(r4.z, i4.z);
        *(float2*)(lds + (base ^ (PL.stB[0] ^ PL.stB[1]))) = make_float2(r4.w, i4.w);
    }

    __syncthreads();                        // gm + staged state visible
    if (tid < 256) build_atab<0>(gm, atab); // seed atab buffer 0
    __syncthreads();                        // atab[0] ready

    mfma_batch<0>(lds, gm, atab, bnq);
    mfma_batch<1>(lds, gm, atab, bnq);
    mfma_batch<2>(lds, gm, atab, bnq);
    mfma_batch<3>(lds, gm, atab, bnq);
    mfma_batch<4>(lds, gm, atab, bnq);
    mfma_batch<5>(lds, gm, atab, bnq);
    mfma_batch<6>(lds, gm, atab, bnq);
    mfma_batch<7>(lds, gm, atab, bnq);
    mfma_batch<8>(lds, gm, atab, bnq);
    mfma_batch<9>(lds, gm, atab, bnq);
    mfma_batch<10>(lds, gm, atab, bnq);

    float acc = tail_batch(lds, gm, g_hw);

    // ---- reduce ----
    #pragma unroll
    for (int off = 32; off > 0; off >>= 1) acc += __shfl_down(acc, off);
    const int lane = tid & 63, wid = tid >> 6;
    if (lane == 0) red[wid] = acc;
    __syncthreads();
    if (tid == 0) {
        float s = 0.0f;
        #pragma unroll
        for (int k = 0; k < BLOCK / 64; ++k) s += red[k];
        g_out[b] = s + g_hb[0];
    }
}

extern "C" void kernel_launch(void* const* d_in, const int* in_sizes, int n_in,
                              void* d_out, int out_size, void* d_ws, size_t ws_size,
                              hipStream_t stream) {
    const float* sr = (const float*)d_in[0];
    const float* si = (const float*)d_in[1];
    const float* vp = (const float*)d_in[2];
    const float* hw = (const float*)d_in[3];
    const float* hb = (const float*)d_in[4];
    float* out = (float*)d_out;

    dim3 grid(out_size);          // 1024 batch elements, one block each
    dim3 block(BLOCK);
    size_t shmem = (size_t)DIM * sizeof(float2);  // 128 KiB dynamic LDS
    qsim_kernel<<<grid, block, shmem, stream>>>(sr, si, vp, hw, hb, out);
}

// Round 4
// 240.984 us; speedup vs baseline: 1.0598x; 1.0598x over previous
//
#include <hip/hip_runtime.h>

#define NW 14
#define NL 3
#define NGAT 42            // 3 layers x 14 rotation gates
#define DIM 16384          // 2^14 amplitudes
#define BLOCK 1024

// ---------------------------------------------------------------------------
// MFMA formulation (round 9) with WRITER-FRAME layout (round 10/11).
// Round 15: structure = r11/r13 two-barrier shape (measured best, 154us;
// r12/r14 phase restructures both regressed ~7%). New: CORRECTED bank-
// conflict twist search. Hardware handles wave64 ds_read_b64 in two 32-lane
// phases; each phase maps 32 accesses onto 16 8-byte bank-pairs (byte bits
// [6:3]); 2-way is free. Free read <=> the 5 half-wave lane-direction
// vectors {Lambda(cvec0..3), Lambda(basis2)} project onto bits [6:3] with
// rank >= 4. Writer/batch-0 b128 (16-lane phases over 8 16B-quads) needs
// rank{t0>>1..t3>>1} >= 3 (legacy twist satisfies it -> writes measured
// clean). r13's search used the wrong granularity (full-wave, 6 vectors,
// weak constraint) and was counterproductive. Objective: sum of capped
// ranks over 11 reader batches + staging, coordinate descent from legacy
// + one random start. Runtime cost unchanged (twist folded into bnq once).
// ---------------------------------------------------------------------------

typedef float        f4  __attribute__((ext_vector_type(4)));
typedef short        s8v __attribute__((ext_vector_type(8)));
typedef unsigned int u4v __attribute__((ext_vector_type(4)));

constexpr int parity14(int v) { int p = 0; for (int i = 0; i < NW; ++i) p ^= (v >> i) & 1; return p; }
constexpr int hibit(int v) { int h = -1; for (int i = 0; i < NW; ++i) if ((v >> i) & 1) h = i; return h; }

struct Lin { int col[NW]; };

constexpr int lin_apply(const Lin& M, int x) {
    int r = 0;
    for (int i = 0; i < NW; ++i) if ((x >> i) & 1) r ^= M.col[i];
    return r;
}
constexpr Lin lin_inverse(const Lin& M) {
    int E[NW] = {}, P[NW] = {};
    for (int i = 0; i < NW; ++i) {
        int v = M.col[i], p = 1 << i;
        while (v) {
            int h = hibit(v);
            if (!E[h]) { E[h] = v; P[h] = p; break; }
            v ^= E[h]; p ^= P[h];
        }
    }
    Lin R{};
    for (int i = 0; i < NW; ++i) {
        int v = 1 << i, p = 0;
        while (v) { int h = hibit(v); v ^= E[h]; p ^= P[h]; }
        R.col[i] = p;
    }
    return R;
}
constexpr Lin lin_compose(const Lin& A, const Lin& B) {
    Lin R{};
    for (int i = 0; i < NW; ++i) R.col[i] = lin_apply(A, B.col[i]);
    return R;
}

// ---- algorithm structure (frames, cosets, duality corrections) ----
struct Alg {
    int ngates[12];
    int gidx[12][4];
    int basisA[12][4];
    int comboA[12][16];
    int cvecA[12][10];
    Lin F[12];
    int Rf[NW];         // final Z-row masks for the tail features
};

constexpr Alg make_alg() {
    Alg A{};
    int R[NW] = {}, C[NW] = {};
    for (int p = 0; p < NW; ++p) { R[p] = 1 << p; C[p] = 1 << p; }
    int bi = 0;
    for (int l = 0; l < NL; ++l) {
        const int sizes[4] = {4, 4, 4, 2};
        int w0 = 0;
        for (int s = 0; s < 4; ++s) {
            const int ng = sizes[s];
            A.ngates[bi] = ng;
            int basis[4] = {}, rr[4] = {};
            for (int j = 0; j < ng; ++j) {
                int w = w0 + j, p = 13 - w;
                basis[j] = C[p];
                rr[j] = R[p];
                A.gidx[bi][j] = l * NW + w;
            }
            // echelon for independence
            int ech[4] = {}; int ne = 0;
            for (int j = 0; j < ng; ++j) {
                int v = basis[j];
                bool ch = true;
                while (ch) { ch = false;
                    for (int k = 0; k < ne; ++k)
                        if (v && ((v >> hibit(ech[k])) & 1)) { v ^= ech[k]; ch = true; }
                }
                ech[ne++] = v;
            }
            // pad to 4 from null space of gate parity masks
            int nb = ng;
            for (int cand = 1; cand < DIM && nb < 4; ++cand) {
                bool ok = true;
                for (int j = 0; j < ng; ++j) if (parity14(cand & rr[j])) { ok = false; break; }
                if (!ok) continue;
                int v = cand;
                bool ch = true;
                while (ch) { ch = false;
                    for (int k = 0; k < ne; ++k)
                        if (v && ((v >> hibit(ech[k])) & 1)) { v ^= ech[k]; ch = true; }
                }
                if (v) { basis[nb++] = cand; ech[ne++] = v; }
            }
            // pivots & non-pivot positions
            int piv[4] = {};
            for (int k = 0; k < 4; ++k) piv[k] = hibit(ech[k]);
            for (int a = 0; a < 4; ++a)
                for (int b2 = a + 1; b2 < 4; ++b2)
                    if (piv[b2] < piv[a]) { int t = piv[a]; piv[a] = piv[b2]; piv[b2] = t; }
            int npp[10] = {}; int nn = 0;
            for (int bit = 0; bit < NW; ++bit) {
                bool isp = false;
                for (int k = 0; k < 4; ++k) if (piv[k] == bit) isp = true;
                if (!isp) npp[nn++] = bit;
            }
            // duality-corrected coset directions
            for (int k = 0; k < 10; ++k) {
                int c = 1 << npp[k];
                for (int j = 0; j < ng; ++j) if ((rr[j] >> npp[k]) & 1) c ^= basis[j];
                A.cvecA[bi][k] = c;
            }
            for (int e = 0; e < 16; ++e) {
                int v = 0;
                for (int j = 0; j < 4; ++j) if ((e >> j) & 1) v ^= basis[j];
                A.comboA[bi][e] = v;
            }
            for (int j = 0; j < 4; ++j) A.basisA[bi][j] = basis[j];
            for (int j = 0; j < 4; ++j) A.F[bi].col[j] = basis[j];
            for (int k = 0; k < 10; ++k) A.F[bi].col[4 + k] = A.cvecA[bi][k];
            w0 += ng;
            ++bi;
        }
        // CNOT chain (w,w+1) w=0..12 then (13,0)
        for (int w = 0; w < NW; ++w) {
            int c = w, t = (w + 1) % NW;
            int pc = 13 - c, pt = 13 - t;
            R[pt] ^= R[pc];
            C[pc] ^= C[pt];
        }
    }
    for (int p = 0; p < NW; ++p) A.Rf[p] = R[p];
    return A;
}

// ---- compile-time bank-conflict twist search (corrected model) ----
struct Twist { unsigned t[10]; };

// rank of 4-bit vectors over GF(2)
constexpr int rank4v(const int* v, int nv) {
    int b3 = 0, b2 = 0, b1 = 0, b0 = 0, rk = 0;
    for (int i = 0; i < nv; ++i) {
        int x = v[i] & 15;
        if (x & 8) { if (b3) x ^= b3; else { b3 = x; ++rk; continue; } }
        if (x & 4) { if (b2) x ^= b2; else { b2 = x; ++rk; continue; } }
        if (x & 2) { if (b1) x ^= b1; else { b1 = x; ++rk; continue; } }
        if (x & 1) { if (b0) x ^= b0; else { b0 = x; ++rk; continue; } }
    }
    return rk;
}

// image of pre-vector u (packed (e,y) space) under the low-4 idx projection
constexpr int img4(int u, const unsigned* t) {
    int r = u & 15;
    for (int k = 0; k < 10; ++k) if ((u >> (4 + k)) & 1) r ^= (int)t[k];
    return r;
}

constexpr int cap4(int x) { return x > 4 ? 4 : x; }

// objective: b64 readers are conflict-free iff the 5 half-wave lane-direction
// vectors project to bank-pair bits (idx low 4) with rank >= 4 (2-way free).
// HARD: writer/batch-0 b128 16-lane phases need rank{t0>>1..t3>>1} >= 3.
constexpr int eval_twist(const unsigned* t, const int (*preR)[5], const int* preS) {
    {
        int w[4] = { (int)(t[0] >> 1), (int)(t[1] >> 1),
                     (int)(t[2] >> 1), (int)(t[3] >> 1) };
        if (rank4v(w, 4) < 3) return -1;
    }
    int sc = 0;
    for (int r = 1; r < 12; ++r) {
        int v[5];
        for (int i = 0; i < 5; ++i) v[i] = img4(preR[r][i], t);
        sc += cap4(rank4v(v, 5));
    }
    {
        int v[5];
        for (int i = 0; i < 5; ++i) v[i] = img4(preS[i], t);
        sc += cap4(rank4v(v, 5));
    }
    return sc;   // max 12*4 = 48
}

constexpr Twist find_twist() {
    Alg A = make_alg();
    // half-wave lane-direction pre-images (twist-independent), packed domain:
    // reader batch r: F_{r-1}^{-1} of {cvec_r[0..3], basis_r[2]}
    int preR[12][5] = {};
    for (int r = 1; r < 12; ++r) {
        Lin Fi = lin_inverse(A.F[r - 1]);
        for (int k = 0; k < 4; ++k) preR[r][k] = lin_apply(Fi, A.cvecA[r][k]);
        preR[r][4] = lin_apply(Fi, A.basisA[r][2]);
    }
    // staging b64 writes: half-wave lane dims = tid bits 2..6 through F_0^{-1}
    int preS[5] = {};
    {
        Lin F0i = lin_inverse(A.F[0]);
        for (int k = 0; k < 5; ++k) preS[k] = lin_apply(F0i, 1 << (k + 2));
    }
    Twist best{};
    best.t[0] = 2; best.t[1] = 4; best.t[2] = 8;
    for (int k = 3; k < 10; ++k) best.t[k] = 0;
    int bs = eval_twist(best.t, preR, preS);
    unsigned x = 0x9E3779B9u;
    for (int s = 0; s < 2; ++s) {
        Twist cur{};
        if (s == 0) {
            cur = best;
        } else {
            for (int k = 0; k < 10; ++k) {
                x = x * 1664525u + 1013904223u;
                cur.t[k] = ((x >> 13) & 7u) << 1;
            }
        }
        int cs = eval_twist(cur.t, preR, preS);
        for (int pass = 0; pass < 2; ++pass) {
            for (int k = 0; k < 10; ++k) {
                unsigned bc = cur.t[k];
                int bv = cs;
                for (unsigned c = 0; c < 16; c += 2) {
                    cur.t[k] = c;
                    const int e = eval_twist(cur.t, preR, preS);
                    if (e > bv) { bv = e; bc = c; }
                }
                cur.t[k] = bc;
                cs = bv;
            }
        }
        if (cs > bs) { bs = cs; best = cur; }
    }
    return best;
}

constexpr Twist TW = find_twist();

struct BatchP {
    int ngates;
    int gidx[4];
    unsigned rdy[10];   // byte: 8 * Lambda_{r-1}(cvec_r[k])  (y-bit directions)
    unsigned rde[16];   // byte: 8 * Lambda_{r-1}(combo_r[e]) (e-directions)
};
struct PlanP {
    BatchP b[12];
    unsigned stB[14];   // staging: byte 8 * Lambda_0(1<<bit)
    unsigned ykey[14];  // tail: parity mask over key = y | (q<<10)
    int zsel[14];       // tail: Walsh index from basis[0,1] parities
    unsigned tw[10];    // T twist columns (idx units)
};

constexpr PlanP make_planp() {
    Alg A = make_alg();
    PlanP P{};
    for (int bi = 0; bi < 12; ++bi) {
        P.b[bi].ngates = A.ngates[bi];
        for (int j = 0; j < 4; ++j) P.b[bi].gidx[j] = A.gidx[bi][j];
    }
    // T: packed(e, y) -> idx = e ^ (y<<4) ^ twist(y)
    Lin T{};
    for (int j = 0; j < 4; ++j) T.col[j] = 1 << j;
    for (int k = 0; k < 10; ++k) T.col[4 + k] = (1 << (4 + k)) ^ (int)TW.t[k];

    // Lambda_w = T o F_w^{-1}; staging uses Lambda_0, reader r uses Lambda_{r-1}
    {
        Lin L0 = lin_compose(T, lin_inverse(A.F[0]));
        for (int bit = 0; bit < NW; ++bit) P.stB[bit] = (unsigned)lin_apply(L0, 1 << bit) * 8u;
    }
    for (int r = 1; r < 12; ++r) {
        Lin Lw = lin_compose(T, lin_inverse(A.F[r - 1]));
        for (int k = 0; k < 10; ++k) P.b[r].rdy[k] = (unsigned)lin_apply(Lw, A.cvecA[r][k]) * 8u;
        for (int e = 0; e < 16; ++e) P.b[r].rde[e] = (unsigned)lin_apply(Lw, A.comboA[r][e]) * 8u;
    }
    for (int w = 0; w < NW; ++w) {
        int zrw = A.Rf[13 - w];
        unsigned ym = 0;
        for (int k = 0; k < 10; ++k) ym |= (unsigned)parity14(A.cvecA[11][k] & zrw) << k;
        int qm = parity14(A.basisA[11][2] & zrw) | (parity14(A.basisA[11][3] & zrw) << 1);
        P.ykey[w] = ym | ((unsigned)qm << 10);
        P.zsel[w] = parity14(A.basisA[11][0] & zrw) | (parity14(A.basisA[11][1] & zrw) << 1);
    }
    for (int k = 0; k < 10; ++k) P.tw[k] = TW.t[k];
    return P;
}

constexpr PlanP PL = make_planp();

// per-tile byte offsets in the writer frame: y bits 4,5 plus their twists
constexpr unsigned TILE_OFF[4] = {
    0u,
    (1u << 11) ^ (PL.tw[4] << 3),
    (1u << 12) ^ (PL.tw[5] << 3),
    (1u << 11) ^ (1u << 12) ^ ((PL.tw[4] ^ PL.tw[5]) << 3)
};

// fp32 (r,i) -> packed bf16 hi dword + lo dword. hi = truncation (lo absorbs
// the residual; round only lo) — 8 VALU.
__device__ __forceinline__ void splitpk(float r, float i, unsigned& hi, unsigned& lo) {
    const unsigned tr = __float_as_uint(r);
    const unsigned ti = __float_as_uint(i);
    hi = __builtin_amdgcn_perm(ti, tr, 0x07060302u);
    const float lr = r - __uint_as_float(tr & 0xffff0000u);
    const float li = i - __uint_as_float(ti & 0xffff0000u);
    const unsigned ur = __float_as_uint(lr) + 0x8000u;
    const unsigned ui = __float_as_uint(li) + 0x8000u;
    lo = __builtin_amdgcn_perm(ui, ur, 0x07060302u);
}

__device__ __forceinline__ f4 mf(u4v a, u4v b, f4 c) {
    return __builtin_amdgcn_mfma_f32_16x16x32_bf16(
        __builtin_bit_cast(s8v, a), __builtin_bit_cast(s8v, b), c, 0, 0, 0);
}

// scattered-read base for reader batch B: XOR-select over y-bits (n,wid) and
// q-part; per-tile t adds rdy[4]/rdy[5]; 4 entries at {0, rde1, rde2, rde3}.
#define RD_SREP(B)                                                     \
    unsigned srep = 0;                                                 \
    srep ^= (n & 1u)   ? B.rdy[0] : 0u;                                \
    srep ^= (n & 2u)   ? B.rdy[1] : 0u;                                \
    srep ^= (n & 4u)   ? B.rdy[2] : 0u;                                \
    srep ^= (n & 8u)   ? B.rdy[3] : 0u;                                \
    srep ^= (wid & 1u) ? B.rdy[6] : 0u;                                \
    srep ^= (wid & 2u) ? B.rdy[7] : 0u;                                \
    srep ^= (wid & 4u) ? B.rdy[8] : 0u;                                \
    srep ^= (wid & 8u) ? B.rdy[9] : 0u;                                \
    srep ^= (q & 1u)   ? B.rde[4] : 0u;                                \
    srep ^= (q & 2u)   ? B.rde[8] : 0u;

template <int BI>
__device__ __forceinline__ void mfma_batch(char* __restrict__ lds, const float* __restrict__ gm,
                                           unsigned* __restrict__ atab, const unsigned bnq) {
    constexpr BatchP B = PL.b[BI];
    const unsigned tid = threadIdx.x;
    const unsigned lane = tid & 63u, wid = tid >> 6;
    const unsigned n = lane & 15u, q = lane >> 4;

    __syncthreads();   // prev batch stores visible; prev atab reads done

    // ---- A-table build (threads 0..255), concurrent with phase A ----
    if (tid < 256) {
        const unsigned m = tid >> 4, ein = tid & 15u;
        float wr = 1.f, wi = 0.f;
        #pragma unroll
        for (int j = 0; j < 4; ++j) {
            if (j < B.ngates) {
                const unsigned mj = (m >> j) & 1u, ej = (ein >> j) & 1u;
                const float ur = gm[B.gidx[j] * 8 + (int)(mj * 4u + ej * 2u)];
                const float ui = gm[B.gidx[j] * 8 + (int)(mj * 4u + ej * 2u) + 1];
                const float nr = wr * ur - wi * ui;
                const float ni = wr * ui + wi * ur;
                wr = nr; wi = ni;
            }
        }
        if (B.ngates < 4 && (((m ^ ein) >> B.ngates) != 0u)) { wr = 0.f; wi = 0.f; }
        unsigned twr = __float_as_uint(wr) + 0x8000u;
        unsigned twi = __float_as_uint(wi) + 0x8000u;
        float lr = wr - __uint_as_float(twr & 0xffff0000u);
        float li = wi - __uint_as_float(twi & 0xffff0000u);
        unsigned tlr = __float_as_uint(lr) + 0x8000u;
        unsigned tli = __float_as_uint(li) + 0x8000u;
        const unsigned o = m * 16u + ein;
        atab[o]        = __builtin_amdgcn_perm(twi ^ 0x80000000u, twr, 0x07060302u); // (Wr_hi,-Wi_hi)
        atab[256 + o]  = __builtin_amdgcn_perm(tli ^ 0x80000000u, tlr, 0x07060302u); // (Wr_lo,-Wi_lo)
        atab[512 + o]  = __builtin_amdgcn_perm(twr, twi, 0x07060302u);               // (Wi_hi, Wr_hi)
        atab[768 + o]  = __builtin_amdgcn_perm(tlr, tli, 0x07060302u);               // (Wi_lo, Wr_lo)
    }

    // ---- phase A: read + convert all 4 tiles (all reads precede all writes) ----
    u4v bhi[4], blo[4];
    if constexpr (BI == 0) {
        #pragma unroll
        for (int t = 0; t < 4; ++t) {
            const unsigned a0 = bnq ^ TILE_OFF[t];
            const f4 v01 = *(const f4*)(lds + a0);
            const f4 v23 = *(const f4*)(lds + (a0 ^ 16u));
            unsigned h0, l0, h1, l1, h2, l2, h3, l3;
            splitpk(v01.x, v01.y, h0, l0);
            splitpk(v01.z, v01.w, h1, l1);
            splitpk(v23.x, v23.y, h2, l2);
            splitpk(v23.z, v23.w, h3, l3);
            u4v h; h.x = h0; h.y = h1; h.z = h2; h.w = h3;
            u4v l; l.x = l0; l.y = l1; l.z = l2; l.w = l3;
            bhi[t] = h; blo[t] = l;
        }
    } else {
        RD_SREP(B)
        #pragma unroll
        for (int t = 0; t < 4; ++t) {
            const unsigned st = srep ^ ((t & 1) ? B.rdy[4] : 0u) ^ ((t & 2) ? B.rdy[5] : 0u);
            const float2 c0 = *(const float2*)(lds + st);
            const float2 c1 = *(const float2*)(lds + (st ^ B.rde[1]));
            const float2 c2 = *(const float2*)(lds + (st ^ B.rde[2]));
            const float2 c3 = *(const float2*)(lds + (st ^ B.rde[3]));
            unsigned h0, l0, h1, l1, h2, l2, h3, l3;
            splitpk(c0.x, c0.y, h0, l0);
            splitpk(c1.x, c1.y, h1, l1);
            splitpk(c2.x, c2.y, h2, l2);
            splitpk(c3.x, c3.y, h3, l3);
            u4v h; h.x = h0; h.y = h1; h.z = h2; h.w = h3;
            u4v l; l.x = l0; l.y = l1; l.z = l2; l.w = l3;
            bhi[t] = h; blo[t] = l;
        }
    }

    __syncthreads();   // all reads done + atab ready

    // ---- phase B: mfma + clean writer-frame b128 stores ----
    const u4v A0 = *(const u4v*)&atab[(n << 4) + (q << 2)];
    const u4v A1 = *(const u4v*)&atab[256 + (n << 4) + (q << 2)];
    const u4v A2 = *(const u4v*)&atab[512 + (n << 4) + (q << 2)];
    const u4v A3 = *(const u4v*)&atab[768 + (n << 4) + (q << 2)];

    #pragma unroll
    for (int t = 0; t < 4; ++t) {
        f4 ar = {0.f, 0.f, 0.f, 0.f};
        f4 ai = {0.f, 0.f, 0.f, 0.f};
        ar = mf(A0, bhi[t], ar);
        ai = mf(A2, bhi[t], ai);
        ar = mf(A1, bhi[t], ar);
        ai = mf(A3, bhi[t], ai);
        ar = mf(A0, blo[t], ar);
        ai = mf(A2, blo[t], ai);
        const unsigned a0 = bnq ^ TILE_OFF[t];
        const f4 s01 = {ar.x, ai.x, ar.y, ai.y};
        const f4 s23 = {ar.z, ai.z, ar.w, ai.w};
        *(f4*)(lds + a0)         = s01;
        *(f4*)(lds + (a0 ^ 16u)) = s23;
    }
}

// complex 2x2 butterfly
#define BFC(A, B_, ua, ub) { const float2 t0 = A, t1 = B_; \
    A.x  = ua.x * t0.x - ua.y * t0.y + ua.z * t1.x - ua.w * t1.y; \
    A.y  = ua.x * t0.y + ua.y * t0.x + ua.z * t1.y + ua.w * t1.x; \
    B_.x = ub.x * t0.x - ub.y * t0.y + ub.z * t1.x - ub.w * t1.y; \
    B_.y = ub.x * t0.y + ub.y * t0.x + ub.z * t1.y + ub.w * t1.x; }

__device__ __forceinline__ float tail_batch(char* __restrict__ lds, const float* __restrict__ gm,
                                            const float* __restrict__ g_hw) {
    constexpr BatchP B = PL.b[11];   // ngates == 2
    const unsigned tid = threadIdx.x;
    const unsigned lane = tid & 63u, wid = tid >> 6;
    const unsigned n = lane & 15u, q = lane >> 4;
    __syncthreads();
    const f4 u0a = *(const f4*)&gm[B.gidx[0] * 8];
    const f4 u0b = *(const f4*)&gm[B.gidx[0] * 8 + 4];
    const f4 u1a = *(const f4*)&gm[B.gidx[1] * 8];
    const f4 u1b = *(const f4*)&gm[B.gidx[1] * 8 + 4];
    float hwv[NW];
    #pragma unroll
    for (int w = 0; w < NW; ++w) hwv[w] = g_hw[w];
    float acc = 0.f;
    RD_SREP(B)
    #pragma unroll
    for (int t = 0; t < 4; ++t) {
        const unsigned st = srep ^ ((t & 1) ? B.rdy[4] : 0u) ^ ((t & 2) ? B.rdy[5] : 0u);
        float2 c0 = *(const float2*)(lds + st);
        float2 c1 = *(const float2*)(lds + (st ^ B.rde[1]));
        float2 c2 = *(const float2*)(lds + (st ^ B.rde[2]));
        float2 c3 = *(const float2*)(lds + (st ^ B.rde[3]));
        BFC(c0, c1, u0a, u0b)  BFC(c2, c3, u0a, u0b)   // gate 0: slot bit 0
        BFC(c0, c2, u1a, u1b)  BFC(c1, c3, u1a, u1b)   // gate 1: slot bit 1
        const float p0 = c0.x * c0.x + c0.y * c0.y;
        const float p1 = c1.x * c1.x + c1.y * c1.y;
        const float p2 = c2.x * c2.x + c2.y * c2.y;
        const float p3 = c3.x * c3.x + c3.y * c3.y;
        const float sa = p0 + p1, sb = p0 - p1, sc = p2 + p3, sd = p2 - p3;
        const float W4[4] = {sa + sc, sb + sd, sa - sc, sb - sd};
        const unsigned y = (wid << 6) | ((unsigned)t << 4) | n;
        const unsigned key = y | (q << 10);
        #pragma unroll
        for (int w = 0; w < NW; ++w) {
            const unsigned sg = ((unsigned)__popc(key & PL.ykey[w])) << 31;
            const float s = __uint_as_float(__float_as_uint(hwv[w]) ^ sg);
            acc += W4[PL.zsel[w]] * s;
        }
    }
    return acc;
}

__global__ __launch_bounds__(BLOCK) void qsim_kernel(
    const float* __restrict__ g_sr, const float* __restrict__ g_si,
    const float* __restrict__ g_params, const float* __restrict__ g_hw,
    const float* __restrict__ g_hb, float* __restrict__ g_out)
{
    extern __shared__ char lds[];                    // 16384 float2 entries (128 KiB)
    __shared__ __align__(16) float gm[NGAT * 8];
    __shared__ __align__(16) unsigned atab[1024];    // 4 A-tables, 16x32 bf16 each
    __shared__ float red[BLOCK / 64];

    const unsigned tid = threadIdx.x;
    const int b = blockIdx.x;
    const float* __restrict__ srcr = g_sr + (size_t)b * DIM;
    const float* __restrict__ srci = g_si + (size_t)b * DIM;

    // ---- gate matrices U = RZ @ RY @ RX ----
    if (tid < NGAT) {
        const float tx = g_params[tid * 3 + 0];
        const float ty = g_params[tid * 3 + 1];
        const float tz = g_params[tid * 3 + 2];
        const float cx = cosf(0.5f * tx), sx = sinf(0.5f * tx);
        const float cy = cosf(0.5f * ty), sy = sinf(0.5f * ty);
        const float cz = cosf(0.5f * tz), sz = sinf(0.5f * tz);
        const float a00r = cy * cx,  a00i = sy * sx;
        const float a01r = -sy * cx, a01i = -cy * sx;
        const float a10r = sy * cx,  a10i = -cy * sx;
        const float a11r = cy * cx,  a11i = -sy * sx;
        gm[tid * 8 + 0] = cz * a00r + sz * a00i;
        gm[tid * 8 + 1] = cz * a00i - sz * a00r;
        gm[tid * 8 + 2] = cz * a01r + sz * a01i;
        gm[tid * 8 + 3] = cz * a01i - sz * a01r;
        gm[tid * 8 + 4] = cz * a10r - sz * a10i;
        gm[tid * 8 + 5] = cz * a10i + sz * a10r;
        gm[tid * 8 + 6] = cz * a11r - sz * a11i;
        gm[tid * 8 + 7] = cz * a11i + sz * a11r;
    }

    // writer-frame base for this thread (computed ONCE; T twist folded in)
    const unsigned lane0 = tid & 63u, wid0 = tid >> 6;
    const unsigned n0 = lane0 & 15u, q0 = lane0 >> 4;
    unsigned twv = 0;
    #pragma unroll
    for (int k = 0; k < 4; ++k) twv ^= ((n0 >> k) & 1u) ? PL.tw[k] : 0u;
    #pragma unroll
    for (int k = 0; k < 4; ++k) twv ^= ((wid0 >> k) & 1u) ? PL.tw[6 + k] : 0u;
    const unsigned bnq = ((wid0 << 10) ^ (n0 << 4) ^ (q0 << 2) ^ twv) << 3;

    // ---- staging: global fp32 -> Lambda_0 layout (so batch 0 reads clean T) ----
    unsigned bb = 0;
    #pragma unroll
    for (int k = 0; k < 10; ++k) bb ^= ((tid >> k) & 1u) ? PL.stB[k + 2] : 0u;
    #pragma unroll
    for (int it = 0; it < 4; ++it) {
        const int x = (int)tid * 4 + it * 4096;
        const f4 r4 = *(const f4*)(srcr + x);
        const f4 i4 = *(const f4*)(srci + x);
        const unsigned base = bb ^ ((it & 1) ? PL.stB[12] : 0u) ^ ((it & 2) ? PL.stB[13] : 0u);
        *(float2*)(lds + base) = make_float2(r4.x, i4.x);
        *(float2*)(lds + (base ^ PL.stB[0])) = make_float2(r4.y, i4.y);
        *(float2*)(lds + (base ^ PL.stB[1])) = make_float2(r4.z, i4.z);
        *(float2*)(lds + (base ^ (PL.stB[0] ^ PL.stB[1]))) = make_float2(r4.w, i4.w);
    }

    mfma_batch<0>(lds, gm, atab, bnq);
    mfma_batch<1>(lds, gm, atab, bnq);
    mfma_batch<2>(lds, gm, atab, bnq);
    mfma_batch<3>(lds, gm, atab, bnq);
    mfma_batch<4>(lds, gm, atab, bnq);
    mfma_batch<5>(lds, gm, atab, bnq);
    mfma_batch<6>(lds, gm, atab, bnq);
    mfma_batch<7>(lds, gm, atab, bnq);
    mfma_batch<8>(lds, gm, atab, bnq);
    mfma_batch<9>(lds, gm, atab, bnq);
    mfma_batch<10>(lds, gm, atab, bnq);

    float acc = tail_batch(lds, gm, g_hw);

    // ---- reduce ----
    #pragma unroll
    for (int off = 32; off > 0; off >>= 1) acc += __shfl_down(acc, off);
    const int lane = tid & 63, wid = tid >> 6;
    if (lane == 0) red[wid] = acc;
    __syncthreads();
    if (tid == 0) {
        float s = 0.0f;
        #pragma unroll
        for (int k = 0; k < BLOCK / 64; ++k) s += red[k];
        g_out[b] = s + g_hb[0];
    }
}

extern "C" void kernel_launch(void* const* d_in, const int* in_sizes, int n_in,
                              void* d_out, int out_size, void* d_ws, size_t ws_size,
                              hipStream_t stream) {
    const float* sr = (const float*)d_in[0];
    const float* si = (const float*)d_in[1];
    const float* vp = (const float*)d_in[2];
    const float* hw = (const float*)d_in[3];
    const float* hb = (const float*)d_in[4];
    float* out = (float*)d_out;

    dim3 grid(out_size);          // 1024 batch elements, one block each
    dim3 block(BLOCK);
    size_t shmem = (size_t)DIM * sizeof(float2);  // 128 KiB dynamic LDS
    qsim_kernel<<<grid, block, shmem, stream>>>(sr, si, vp, hw, hb, out);
}

// Round 5
// 205.927 us; speedup vs baseline: 1.2402x; 1.1702x over previous
//
#include <hip/hip_runtime.h>

#define NW 14
#define NL 3
#define NGAT 42            // 3 layers x 14 rotation gates
#define DIM 16384          // 2^14 amplitudes
#define BLOCK 1024

// ---------------------------------------------------------------------------
// Round 16: FP16 state @ 4 B/amp -> 64 KiB dynamic LDS -> 2 blocks/CU.
// Evidence chain: r12/r14 (phase moves) and r13/r15 (conflict moves: halved
// conflicts, 0 time delta) show the r11 structure is latency-bound at
// 1 block/CU with 24 lockstep barriers. The fix is cross-block overlap:
// 2 blocks/CU share no barriers, so one block's read phase hides under the
// other's mfma phase. 4 B/amp also cascades:
//   - no splitpk anywhere: a scattered b32 read IS the f16 MFMA B-dword
//     (mfma_f32_16x16x32_f16, same fragment geometry as bf16 variant)
//   - W as f16 hi+lo in the A-tables: 4 mfma/tile (was 6), and per-batch
//     arithmetic error ~2^-21 (better than the 3-product bf16 scheme)
//   - state stores use RNE casts (RTZ would give biased shrinkage ~1e-3
//     over 11 round-trips); storage rounding = unbiased 2^-12/batch walk
//   - LDS traffic halves; writes 1 b128/tile; batch-0 reads 1 b128/tile
// Twist search re-derived for 4 B geometry: banks = idx bits [4:0]; twist
// restricted to idx bits [3:2] (keeps 4-slot b128 write contiguity); writer
// hard constraint = rank-3 span on the 3-bit quad-bank space.
// __launch_bounds__(1024, 8) caps VGPR at 64 (needed for 8 waves/SIMD).
// ---------------------------------------------------------------------------

typedef float        f4  __attribute__((ext_vector_type(4)));
typedef _Float16     h8  __attribute__((ext_vector_type(8)));
typedef unsigned int u4v __attribute__((ext_vector_type(4)));

constexpr int parity14(int v) { int p = 0; for (int i = 0; i < NW; ++i) p ^= (v >> i) & 1; return p; }
constexpr int hibit(int v) { int h = -1; for (int i = 0; i < NW; ++i) if ((v >> i) & 1) h = i; return h; }

struct Lin { int col[NW]; };

constexpr int lin_apply(const Lin& M, int x) {
    int r = 0;
    for (int i = 0; i < NW; ++i) if ((x >> i) & 1) r ^= M.col[i];
    return r;
}
constexpr Lin lin_inverse(const Lin& M) {
    int E[NW] = {}, P[NW] = {};
    for (int i = 0; i < NW; ++i) {
        int v = M.col[i], p = 1 << i;
        while (v) {
            int h = hibit(v);
            if (!E[h]) { E[h] = v; P[h] = p; break; }
            v ^= E[h]; p ^= P[h];
        }
    }
    Lin R{};
    for (int i = 0; i < NW; ++i) {
        int v = 1 << i, p = 0;
        while (v) { int h = hibit(v); v ^= E[h]; p ^= P[h]; }
        R.col[i] = p;
    }
    return R;
}
constexpr Lin lin_compose(const Lin& A, const Lin& B) {
    Lin R{};
    for (int i = 0; i < NW; ++i) R.col[i] = lin_apply(A, B.col[i]);
    return R;
}

// ---- algorithm structure (frames, cosets, duality corrections) ----
struct Alg {
    int ngates[12];
    int gidx[12][4];
    int basisA[12][4];
    int comboA[12][16];
    int cvecA[12][10];
    Lin F[12];
    int Rf[NW];         // final Z-row masks for the tail features
};

constexpr Alg make_alg() {
    Alg A{};
    int R[NW] = {}, C[NW] = {};
    for (int p = 0; p < NW; ++p) { R[p] = 1 << p; C[p] = 1 << p; }
    int bi = 0;
    for (int l = 0; l < NL; ++l) {
        const int sizes[4] = {4, 4, 4, 2};
        int w0 = 0;
        for (int s = 0; s < 4; ++s) {
            const int ng = sizes[s];
            A.ngates[bi] = ng;
            int basis[4] = {}, rr[4] = {};
            for (int j = 0; j < ng; ++j) {
                int w = w0 + j, p = 13 - w;
                basis[j] = C[p];
                rr[j] = R[p];
                A.gidx[bi][j] = l * NW + w;
            }
            // echelon for independence
            int ech[4] = {}; int ne = 0;
            for (int j = 0; j < ng; ++j) {
                int v = basis[j];
                bool ch = true;
                while (ch) { ch = false;
                    for (int k = 0; k < ne; ++k)
                        if (v && ((v >> hibit(ech[k])) & 1)) { v ^= ech[k]; ch = true; }
                }
                ech[ne++] = v;
            }
            // pad to 4 from null space of gate parity masks
            int nb = ng;
            for (int cand = 1; cand < DIM && nb < 4; ++cand) {
                bool ok = true;
                for (int j = 0; j < ng; ++j) if (parity14(cand & rr[j])) { ok = false; break; }
                if (!ok) continue;
                int v = cand;
                bool ch = true;
                while (ch) { ch = false;
                    for (int k = 0; k < ne; ++k)
                        if (v && ((v >> hibit(ech[k])) & 1)) { v ^= ech[k]; ch = true; }
                }
                if (v) { basis[nb++] = cand; ech[ne++] = v; }
            }
            // pivots & non-pivot positions
            int piv[4] = {};
            for (int k = 0; k < 4; ++k) piv[k] = hibit(ech[k]);
            for (int a = 0; a < 4; ++a)
                for (int b2 = a + 1; b2 < 4; ++b2)
                    if (piv[b2] < piv[a]) { int t = piv[a]; piv[a] = piv[b2]; piv[b2] = t; }
            int npp[10] = {}; int nn = 0;
            for (int bit = 0; bit < NW; ++bit) {
                bool isp = false;
                for (int k = 0; k < 4; ++k) if (piv[k] == bit) isp = true;
                if (!isp) npp[nn++] = bit;
            }
            // duality-corrected coset directions
            for (int k = 0; k < 10; ++k) {
                int c = 1 << npp[k];
                for (int j = 0; j < ng; ++j) if ((rr[j] >> npp[k]) & 1) c ^= basis[j];
                A.cvecA[bi][k] = c;
            }
            for (int e = 0; e < 16; ++e) {
                int v = 0;
                for (int j = 0; j < 4; ++j) if ((e >> j) & 1) v ^= basis[j];
                A.comboA[bi][e] = v;
            }
            for (int j = 0; j < 4; ++j) A.basisA[bi][j] = basis[j];
            for (int j = 0; j < 4; ++j) A.F[bi].col[j] = basis[j];
            for (int k = 0; k < 10; ++k) A.F[bi].col[4 + k] = A.cvecA[bi][k];
            w0 += ng;
            ++bi;
        }
        // CNOT chain (w,w+1) w=0..12 then (13,0)
        for (int w = 0; w < NW; ++w) {
            int c = w, t = (w + 1) % NW;
            int pc = 13 - c, pt = 13 - t;
            R[pt] ^= R[pc];
            C[pc] ^= C[pt];
        }
    }
    for (int p = 0; p < NW; ++p) A.Rf[p] = R[p];
    return A;
}

// ---- compile-time bank-conflict twist search (4 B/amp geometry) ----
struct Twist { unsigned t[10]; };

// rank of width-bit vectors over GF(2)
constexpr int rankv(const int* v, int nv, int width) {
    int basis[8] = {};
    int rk = 0;
    for (int i = 0; i < nv; ++i) {
        int x = v[i] & ((1 << width) - 1);
        for (int b = width - 1; b >= 0; --b) {
            if (!((x >> b) & 1)) continue;
            if (basis[b]) { x ^= basis[b]; continue; }
            basis[b] = x; ++rk; break;
        }
    }
    return rk;
}

// bank-image of pre-vector u (packed (e,y) space): idx bits [4:0];
// twist lives in bits [3:2] so it never touches bit 4 (= y0).
constexpr int img5(int u, const unsigned* t) {
    int r = u & 31;
    for (int k = 0; k < 10; ++k) if ((u >> (4 + k)) & 1) r ^= (int)t[k];
    return r;
}

constexpr int cap4(int x) { return x > 4 ? 4 : x; }

// b32 readers: conflict-free-enough iff the 5 half-wave lane-direction
// vectors project onto banks (idx [4:0]) with rank >= 4 (2-way is free).
// HARD: writer b128 quad-bank span {q0, n0..n3} on idx bits [4:2] rank 3.
constexpr int eval5(const unsigned* t, const int (*preR)[5], const int* preS) {
    {
        int w[5] = { 1, 4 ^ (int)(t[0] >> 2), (int)(t[1] >> 2),
                     (int)(t[2] >> 2), (int)(t[3] >> 2) };
        if (rankv(w, 5, 3) < 3) return -1;
    }
    int sc = 0;
    for (int r = 1; r < 12; ++r) {
        int v[5];
        for (int i = 0; i < 5; ++i) v[i] = img5(preR[r][i], t);
        sc += cap4(rankv(v, 5, 5));
    }
    {
        int v[5];
        for (int i = 0; i < 5; ++i) v[i] = img5(preS[i], t);
        sc += cap4(rankv(v, 5, 5));
    }
    return sc;   // max 12*4 = 48
}

constexpr Twist find_twist() {
    Alg A = make_alg();
    int preR[12][5] = {};
    for (int r = 1; r < 12; ++r) {
        Lin Fi = lin_inverse(A.F[r - 1]);
        for (int k = 0; k < 4; ++k) preR[r][k] = lin_apply(Fi, A.cvecA[r][k]);
        preR[r][4] = lin_apply(Fi, A.basisA[r][2]);
    }
    int preS[5] = {};
    {
        Lin F0i = lin_inverse(A.F[0]);
        for (int k = 0; k < 5; ++k) preS[k] = lin_apply(F0i, 1 << (k + 2));
    }
    Twist best{};
    for (int k = 0; k < 10; ++k) best.t[k] = 0;
    int bs = eval5(best.t, preR, preS);
    unsigned x = 0x9E3779B9u;
    for (int s = 0; s < 2; ++s) {
        Twist cur{};
        if (s == 0) {
            for (int k = 0; k < 10; ++k) cur.t[k] = 0;
        } else {
            for (int k = 0; k < 10; ++k) {
                x = x * 1664525u + 1013904223u;
                cur.t[k] = ((x >> 13) & 3u) << 2;   // {0,4,8,12}: idx bits [3:2] only
            }
        }
        int cs = eval5(cur.t, preR, preS);
        for (int pass = 0; pass < 2; ++pass) {
            for (int k = 0; k < 10; ++k) {
                unsigned bc = cur.t[k];
                int bv = cs;
                for (unsigned c = 0; c < 16; c += 4) {
                    cur.t[k] = c;
                    const int e = eval5(cur.t, preR, preS);
                    if (e > bv) { bv = e; bc = c; }
                }
                cur.t[k] = bc;
                cs = bv;
            }
        }
        if (cs > bs) { bs = cs; best = cur; }
    }
    return best;
}

constexpr Twist TW = find_twist();

struct BatchP {
    int ngates;
    int gidx[4];
    unsigned rdy[10];   // byte: 4 * Lambda_{r-1}(cvec_r[k])  (y-bit directions)
    unsigned rde[16];   // byte: 4 * Lambda_{r-1}(combo_r[e]) (e-directions)
};
struct PlanP {
    BatchP b[12];
    unsigned stB[14];   // staging: byte 4 * Lambda_0(1<<bit)
    unsigned ykey[14];  // tail: parity mask over key = y | (q<<10)
    int zsel[14];       // tail: Walsh index from basis[0,1] parities
    unsigned tw[10];    // T twist columns (idx units, bits [3:2] only)
};

constexpr PlanP make_planp() {
    Alg A = make_alg();
    PlanP P{};
    for (int bi = 0; bi < 12; ++bi) {
        P.b[bi].ngates = A.ngates[bi];
        for (int j = 0; j < 4; ++j) P.b[bi].gidx[j] = A.gidx[bi][j];
    }
    // T: packed(e, y) -> idx = e ^ (y<<4) ^ twist(y)
    Lin T{};
    for (int j = 0; j < 4; ++j) T.col[j] = 1 << j;
    for (int k = 0; k < 10; ++k) T.col[4 + k] = (1 << (4 + k)) ^ (int)TW.t[k];

    // Lambda_w = T o F_w^{-1}; staging uses Lambda_0, reader r uses Lambda_{r-1}
    {
        Lin L0 = lin_compose(T, lin_inverse(A.F[0]));
        for (int bit = 0; bit < NW; ++bit) P.stB[bit] = (unsigned)lin_apply(L0, 1 << bit) * 4u;
    }
    for (int r = 1; r < 12; ++r) {
        Lin Lw = lin_compose(T, lin_inverse(A.F[r - 1]));
        for (int k = 0; k < 10; ++k) P.b[r].rdy[k] = (unsigned)lin_apply(Lw, A.cvecA[r][k]) * 4u;
        for (int e = 0; e < 16; ++e) P.b[r].rde[e] = (unsigned)lin_apply(Lw, A.comboA[r][e]) * 4u;
    }
    for (int w = 0; w < NW; ++w) {
        int zrw = A.Rf[13 - w];
        unsigned ym = 0;
        for (int k = 0; k < 10; ++k) ym |= (unsigned)parity14(A.cvecA[11][k] & zrw) << k;
        int qm = parity14(A.basisA[11][2] & zrw) | (parity14(A.basisA[11][3] & zrw) << 1);
        P.ykey[w] = ym | ((unsigned)qm << 10);
        P.zsel[w] = parity14(A.basisA[11][0] & zrw) | (parity14(A.basisA[11][1] & zrw) << 1);
    }
    for (int k = 0; k < 10; ++k) P.tw[k] = TW.t[k];
    return P;
}

constexpr PlanP PL = make_planp();

// per-tile byte offsets: t-bits are y-bits 4,5 -> idx bits 8,9 -> byte<<2,
// plus their twist columns (idx bits [3:2] -> byte bits [5:4])
constexpr unsigned TILE_OFF[4] = {
    0u,
    (1u << 10) ^ (PL.tw[4] << 2),
    (1u << 11) ^ (PL.tw[5] << 2),
    (1u << 10) ^ (1u << 11) ^ ((PL.tw[4] ^ PL.tw[5]) << 2)
};

// fp32 (r,i) -> packed f16 dword, round-to-nearest-even (unbiased)
__device__ __forceinline__ unsigned pk_rn(float r, float i) {
    const unsigned hr = (unsigned)__builtin_bit_cast(unsigned short, (_Float16)r);
    const unsigned hi = (unsigned)__builtin_bit_cast(unsigned short, (_Float16)i);
    return hr | (hi << 16);
}
// packed f16 dword -> fp32 (r,i)
__device__ __forceinline__ float2 up(unsigned d) {
    float2 c;
    c.x = (float)__builtin_bit_cast(_Float16, (unsigned short)(d & 0xffffu));
    c.y = (float)__builtin_bit_cast(_Float16, (unsigned short)(d >> 16));
    return c;
}

__device__ __forceinline__ f4 mfh(u4v a, u4v b, f4 c) {
    return __builtin_amdgcn_mfma_f32_16x16x32_f16(
        __builtin_bit_cast(h8, a), __builtin_bit_cast(h8, b), c, 0, 0, 0);
}

// scattered-read base for reader batch B: XOR-select over y-bits (n,wid) and
// q-part; per-tile t adds rdy[4]/rdy[5]; 4 entries at {0, rde1, rde2, rde3}.
#define RD_SREP(B)                                                     \
    unsigned srep = 0;                                                 \
    srep ^= (n & 1u)   ? B.rdy[0] : 0u;                                \
    srep ^= (n & 2u)   ? B.rdy[1] : 0u;                                \
    srep ^= (n & 4u)   ? B.rdy[2] : 0u;                                \
    srep ^= (n & 8u)   ? B.rdy[3] : 0u;                                \
    srep ^= (wid & 1u) ? B.rdy[6] : 0u;                                \
    srep ^= (wid & 2u) ? B.rdy[7] : 0u;                                \
    srep ^= (wid & 4u) ? B.rdy[8] : 0u;                                \
    srep ^= (wid & 8u) ? B.rdy[9] : 0u;                                \
    srep ^= (q & 1u)   ? B.rde[4] : 0u;                                \
    srep ^= (q & 2u)   ? B.rde[8] : 0u;

template <int BI>
__device__ __forceinline__ void mfma_batch(char* __restrict__ lds, const float* __restrict__ gm,
                                           unsigned* __restrict__ atab, const unsigned bnq) {
    constexpr BatchP B = PL.b[BI];
    const unsigned tid = threadIdx.x;
    const unsigned lane = tid & 63u, wid = tid >> 6;
    const unsigned n = lane & 15u, q = lane >> 4;

    __syncthreads();   // prev batch stores visible; prev atab reads done

    // ---- A-table build (threads 0..255), f16 hi/lo, concurrent with phase A ----
    if (tid < 256) {
        const unsigned m = tid >> 4, ein = tid & 15u;
        float wr = 1.f, wi = 0.f;
        #pragma unroll
        for (int j = 0; j < 4; ++j) {
            if (j < B.ngates) {
                const unsigned mj = (m >> j) & 1u, ej = (ein >> j) & 1u;
                const float ur = gm[B.gidx[j] * 8 + (int)(mj * 4u + ej * 2u)];
                const float ui = gm[B.gidx[j] * 8 + (int)(mj * 4u + ej * 2u) + 1];
                const float nr = wr * ur - wi * ui;
                const float ni = wr * ui + wi * ur;
                wr = nr; wi = ni;
            }
        }
        if (B.ngates < 4 && (((m ^ ein) >> B.ngates) != 0u)) { wr = 0.f; wi = 0.f; }
        const float nwi = -wi;
        const unsigned h0 = pk_rn(wr, nwi);          // (Wr_hi, -Wi_hi) r-out
        const float2 h0f = up(h0);
        const unsigned l0 = pk_rn(wr - h0f.x, nwi - h0f.y);
        const unsigned h1 = pk_rn(wi, wr);           // (Wi_hi, Wr_hi) i-out
        const float2 h1f = up(h1);
        const unsigned l1 = pk_rn(wi - h1f.x, wr - h1f.y);
        const unsigned o = m * 16u + ein;
        atab[o]        = h0;
        atab[256 + o]  = l0;
        atab[512 + o]  = h1;
        atab[768 + o]  = l1;
    }

    // ---- phase A: pure loads (state IS the f16 B-fragment) ----
    u4v bfr[4];
    if constexpr (BI == 0) {
        #pragma unroll
        for (int t = 0; t < 4; ++t) {
            bfr[t] = *(const u4v*)(lds + (bnq ^ TILE_OFF[t]));
        }
    } else {
        RD_SREP(B)
        #pragma unroll
        for (int t = 0; t < 4; ++t) {
            const unsigned st = srep ^ ((t & 1) ? B.rdy[4] : 0u) ^ ((t & 2) ? B.rdy[5] : 0u);
            const unsigned c0 = *(const unsigned*)(lds + st);
            const unsigned c1 = *(const unsigned*)(lds + (st ^ B.rde[1]));
            const unsigned c2 = *(const unsigned*)(lds + (st ^ B.rde[2]));
            const unsigned c3 = *(const unsigned*)(lds + (st ^ B.rde[3]));
            u4v v; v.x = c0; v.y = c1; v.z = c2; v.w = c3;
            bfr[t] = v;
        }
    }

    __syncthreads();   // all reads done + atab ready

    // ---- phase B: 4 mfma/tile + RNE pack + 1 clean b128 store/tile ----
    const u4v A0 = *(const u4v*)&atab[(n << 4) + (q << 2)];
    const u4v A1 = *(const u4v*)&atab[256 + (n << 4) + (q << 2)];
    const u4v A2 = *(const u4v*)&atab[512 + (n << 4) + (q << 2)];
    const u4v A3 = *(const u4v*)&atab[768 + (n << 4) + (q << 2)];

    #pragma unroll
    for (int t = 0; t < 4; ++t) {
        f4 ar = {0.f, 0.f, 0.f, 0.f};
        f4 ai = {0.f, 0.f, 0.f, 0.f};
        ar = mfh(A0, bfr[t], ar);
        ai = mfh(A2, bfr[t], ai);
        ar = mfh(A1, bfr[t], ar);
        ai = mfh(A3, bfr[t], ai);
        u4v s;
        s.x = pk_rn(ar.x, ai.x);
        s.y = pk_rn(ar.y, ai.y);
        s.z = pk_rn(ar.z, ai.z);
        s.w = pk_rn(ar.w, ai.w);
        *(u4v*)(lds + (bnq ^ TILE_OFF[t])) = s;
    }
}

// complex 2x2 butterfly
#define BFC(A, B_, ua, ub) { const float2 t0 = A, t1 = B_; \
    A.x  = ua.x * t0.x - ua.y * t0.y + ua.z * t1.x - ua.w * t1.y; \
    A.y  = ua.x * t0.y + ua.y * t0.x + ua.z * t1.y + ua.w * t1.x; \
    B_.x = ub.x * t0.x - ub.y * t0.y + ub.z * t1.x - ub.w * t1.y; \
    B_.y = ub.x * t0.y + ub.y * t0.x + ub.z * t1.y + ub.w * t1.x; }

__device__ __forceinline__ float tail_batch(char* __restrict__ lds, const float* __restrict__ gm,
                                            const float* __restrict__ g_hw) {
    constexpr BatchP B = PL.b[11];   // ngates == 2
    const unsigned tid = threadIdx.x;
    const unsigned lane = tid & 63u, wid = tid >> 6;
    const unsigned n = lane & 15u, q = lane >> 4;
    __syncthreads();
    const f4 u0a = *(const f4*)&gm[B.gidx[0] * 8];
    const f4 u0b = *(const f4*)&gm[B.gidx[0] * 8 + 4];
    const f4 u1a = *(const f4*)&gm[B.gidx[1] * 8];
    const f4 u1b = *(const f4*)&gm[B.gidx[1] * 8 + 4];
    float hwv[NW];
    #pragma unroll
    for (int w = 0; w < NW; ++w) hwv[w] = g_hw[w];
    float acc = 0.f;
    RD_SREP(B)
    #pragma unroll
    for (int t = 0; t < 4; ++t) {
        const unsigned st = srep ^ ((t & 1) ? B.rdy[4] : 0u) ^ ((t & 2) ? B.rdy[5] : 0u);
        float2 c0 = up(*(const unsigned*)(lds + st));
        float2 c1 = up(*(const unsigned*)(lds + (st ^ B.rde[1])));
        float2 c2 = up(*(const unsigned*)(lds + (st ^ B.rde[2])));
        float2 c3 = up(*(const unsigned*)(lds + (st ^ B.rde[3])));
        BFC(c0, c1, u0a, u0b)  BFC(c2, c3, u0a, u0b)   // gate 0: slot bit 0
        BFC(c0, c2, u1a, u1b)  BFC(c1, c3, u1a, u1b)   // gate 1: slot bit 1
        const float p0 = c0.x * c0.x + c0.y * c0.y;
        const float p1 = c1.x * c1.x + c1.y * c1.y;
        const float p2 = c2.x * c2.x + c2.y * c2.y;
        const float p3 = c3.x * c3.x + c3.y * c3.y;
        const float sa = p0 + p1, sb = p0 - p1, sc = p2 + p3, sd = p2 - p3;
        const float W4[4] = {sa + sc, sb + sd, sa - sc, sb - sd};
        const unsigned y = (wid << 6) | ((unsigned)t << 4) | n;
        const unsigned key = y | (q << 10);
        #pragma unroll
        for (int w = 0; w < NW; ++w) {
            const unsigned sg = ((unsigned)__popc(key & PL.ykey[w])) << 31;
            const float s = __uint_as_float(__float_as_uint(hwv[w]) ^ sg);
            acc += W4[PL.zsel[w]] * s;
        }
    }
    return acc;
}

__global__ __launch_bounds__(BLOCK, 8) void qsim_kernel(
    const float* __restrict__ g_sr, const float* __restrict__ g_si,
    const float* __restrict__ g_params, const float* __restrict__ g_hw,
    const float* __restrict__ g_hb, float* __restrict__ g_out)
{
    extern __shared__ char lds[];                    // 16384 packed-f16 amps (64 KiB)
    __shared__ __align__(16) float gm[NGAT * 8];
    __shared__ __align__(16) unsigned atab[1024];    // 4 A-tables, 16x32 f16 each
    __shared__ float red[BLOCK / 64];

    const unsigned tid = threadIdx.x;
    const int b = blockIdx.x;
    const float* __restrict__ srcr = g_sr + (size_t)b * DIM;
    const float* __restrict__ srci = g_si + (size_t)b * DIM;

    // ---- gate matrices U = RZ @ RY @ RX ----
    if (tid < NGAT) {
        const float tx = g_params[tid * 3 + 0];
        const float ty = g_params[tid * 3 + 1];
        const float tz = g_params[tid * 3 + 2];
        const float cx = cosf(0.5f * tx), sx = sinf(0.5f * tx);
        const float cy = cosf(0.5f * ty), sy = sinf(0.5f * ty);
        const float cz = cosf(0.5f * tz), sz = sinf(0.5f * tz);
        const float a00r = cy * cx,  a00i = sy * sx;
        const float a01r = -sy * cx, a01i = -cy * sx;
        const float a10r = sy * cx,  a10i = -cy * sx;
        const float a11r = cy * cx,  a11i = -sy * sx;
        gm[tid * 8 + 0] = cz * a00r + sz * a00i;
        gm[tid * 8 + 1] = cz * a00i - sz * a00r;
        gm[tid * 8 + 2] = cz * a01r + sz * a01i;
        gm[tid * 8 + 3] = cz * a01i - sz * a01r;
        gm[tid * 8 + 4] = cz * a10r - sz * a10i;
        gm[tid * 8 + 5] = cz * a10i + sz * a10r;
        gm[tid * 8 + 6] = cz * a11r - sz * a11i;
        gm[tid * 8 + 7] = cz * a11i + sz * a11r;
    }

    // writer-frame base for this thread (computed ONCE; T twist folded in).
    // twist cols are in idx bits [3:2] -> twv & 3 == 0 -> b128 quads stay
    // contiguous in e (slots 4q..4q+3).
    const unsigned lane0 = tid & 63u, wid0 = tid >> 6;
    const unsigned n0 = lane0 & 15u, q0 = lane0 >> 4;
    unsigned twv = 0;
    #pragma unroll
    for (int k = 0; k < 4; ++k) twv ^= ((n0 >> k) & 1u) ? PL.tw[k] : 0u;
    #pragma unroll
    for (int k = 0; k < 4; ++k) twv ^= ((wid0 >> k) & 1u) ? PL.tw[6 + k] : 0u;
    const unsigned bnq = ((wid0 << 10) ^ (n0 << 4) ^ (q0 << 2) ^ twv) << 2;

    // ---- staging: global fp32 -> packed f16 in Lambda_0 layout ----
    unsigned bb = 0;
    #pragma unroll
    for (int k = 0; k < 10; ++k) bb ^= ((tid >> k) & 1u) ? PL.stB[k + 2] : 0u;
    #pragma unroll
    for (int it = 0; it < 4; ++it) {
        const int x = (int)tid * 4 + it * 4096;
        const f4 r4 = *(const f4*)(srcr + x);
        const f4 i4 = *(const f4*)(srci + x);
        const unsigned base = bb ^ ((it & 1) ? PL.stB[12] : 0u) ^ ((it & 2) ? PL.stB[13] : 0u);
        *(unsigned*)(lds + base) = pk_rn(r4.x, i4.x);
        *(unsigned*)(lds + (base ^ PL.stB[0])) = pk_rn(r4.y, i4.y);
        *(unsigned*)(lds + (base ^ PL.stB[1])) = pk_rn(r4.z, i4.z);
        *(unsigned*)(lds + (base ^ (PL.stB[0] ^ PL.stB[1]))) = pk_rn(r4.w, i4.w);
    }

    mfma_batch<0>(lds, gm, atab, bnq);
    mfma_batch<1>(lds, gm, atab, bnq);
    mfma_batch<2>(lds, gm, atab, bnq);
    mfma_batch<3>(lds, gm, atab, bnq);
    mfma_batch<4>(lds, gm, atab, bnq);
    mfma_batch<5>(lds, gm, atab, bnq);
    mfma_batch<6>(lds, gm, atab, bnq);
    mfma_batch<7>(lds, gm, atab, bnq);
    mfma_batch<8>(lds, gm, atab, bnq);
    mfma_batch<9>(lds, gm, atab, bnq);
    mfma_batch<10>(lds, gm, atab, bnq);

    float acc = tail_batch(lds, gm, g_hw);

    // ---- reduce ----
    #pragma unroll
    for (int off = 32; off > 0; off >>= 1) acc += __shfl_down(acc, off);
    const int lane = tid & 63, wid = tid >> 6;
    if (lane == 0) red[wid] = acc;
    __syncthreads();
    if (tid == 0) {
        float s = 0.0f;
        #pragma unroll
        for (int k = 0; k < BLOCK / 64; ++k) s += red[k];
        g_out[b] = s + g_hb[0];
    }
}

extern "C" void kernel_launch(void* const* d_in, const int* in_sizes, int n_in,
                              void* d_out, int out_size, void* d_ws, size_t ws_size,
                              hipStream_t stream) {
    const float* sr = (const float*)d_in[0];
    const float* si = (const float*)d_in[1];
    const float* vp = (const float*)d_in[2];
    const float* hw = (const float*)d_in[3];
    const float* hb = (const float*)d_in[4];
    float* out = (float*)d_out;

    dim3 grid(out_size);          // 1024 batch elements, one block each
    dim3 block(BLOCK);
    size_t shmem = (size_t)DIM * 4;  // 64 KiB dynamic LDS (packed f16 amps)
    qsim_kernel<<<grid, block, shmem, stream>>>(sr, si, vp, hw, hb, out);
}

// Round 6
// 205.023 us; speedup vs baseline: 1.2457x; 1.0044x over previous
//
#include <hip/hip_runtime.h>

#define NW 14
#define NL 3
#define NGAT 42            // 3 layers x 14 rotation gates
#define DIM 16384          // 2^14 amplitudes
#define BLOCK 1024

// ---------------------------------------------------------------------------
// Round 17: r16 (fp16 @ 4 B/amp, 2 blocks/CU, 121us steady) + CORRECTED
// b32 bank model in the twist search. A wave64 ds_read_b32 issues as two
// 32-lane phases over 32 banks (byte bits [6:2] = idx bits [4:0]); "2-way
// free" means <=1 access/bank/phase, so conflict-free requires the 5
// half-wave lane-direction vectors {Lambda(cvec0..3), Lambda(basis2)} to
// span the FULL 5-bit bank space (rank 5). r16 reused the 8B-era cap4
// objective (rank>=4 "good enough"), which ACCEPTS 2-way-in-phase ->
// measured conflicts rose to 1.52e7. Changes (address constants only):
//   - objective: sum of rank5 over 11 reader batches + tail + staging (max 60)
//   - twist space: idx bits [4:2] (was [3:2]); t_0 limited to [3:2] to keep
//     T unipotent/invertible; all t_k multiples of 4 -> b128 write quads
//     stay contiguous
//   - writer hard constraint in quad-bank space (idx [4:2]):
//     rank{4^(t0>>2), t1>>2, t2>>2, t3>>2} >= 3
// Everything else identical to r16.
// ---------------------------------------------------------------------------

typedef float        f4  __attribute__((ext_vector_type(4)));
typedef _Float16     h8  __attribute__((ext_vector_type(8)));
typedef unsigned int u4v __attribute__((ext_vector_type(4)));

constexpr int parity14(int v) { int p = 0; for (int i = 0; i < NW; ++i) p ^= (v >> i) & 1; return p; }
constexpr int hibit(int v) { int h = -1; for (int i = 0; i < NW; ++i) if ((v >> i) & 1) h = i; return h; }

struct Lin { int col[NW]; };

constexpr int lin_apply(const Lin& M, int x) {
    int r = 0;
    for (int i = 0; i < NW; ++i) if ((x >> i) & 1) r ^= M.col[i];
    return r;
}
constexpr Lin lin_inverse(const Lin& M) {
    int E[NW] = {}, P[NW] = {};
    for (int i = 0; i < NW; ++i) {
        int v = M.col[i], p = 1 << i;
        while (v) {
            int h = hibit(v);
            if (!E[h]) { E[h] = v; P[h] = p; break; }
            v ^= E[h]; p ^= P[h];
        }
    }
    Lin R{};
    for (int i = 0; i < NW; ++i) {
        int v = 1 << i, p = 0;
        while (v) { int h = hibit(v); v ^= E[h]; p ^= P[h]; }
        R.col[i] = p;
    }
    return R;
}
constexpr Lin lin_compose(const Lin& A, const Lin& B) {
    Lin R{};
    for (int i = 0; i < NW; ++i) R.col[i] = lin_apply(A, B.col[i]);
    return R;
}

// ---- algorithm structure (frames, cosets, duality corrections) ----
struct Alg {
    int ngates[12];
    int gidx[12][4];
    int basisA[12][4];
    int comboA[12][16];
    int cvecA[12][10];
    Lin F[12];
    int Rf[NW];         // final Z-row masks for the tail features
};

constexpr Alg make_alg() {
    Alg A{};
    int R[NW] = {}, C[NW] = {};
    for (int p = 0; p < NW; ++p) { R[p] = 1 << p; C[p] = 1 << p; }
    int bi = 0;
    for (int l = 0; l < NL; ++l) {
        const int sizes[4] = {4, 4, 4, 2};
        int w0 = 0;
        for (int s = 0; s < 4; ++s) {
            const int ng = sizes[s];
            A.ngates[bi] = ng;
            int basis[4] = {}, rr[4] = {};
            for (int j = 0; j < ng; ++j) {
                int w = w0 + j, p = 13 - w;
                basis[j] = C[p];
                rr[j] = R[p];
                A.gidx[bi][j] = l * NW + w;
            }
            // echelon for independence
            int ech[4] = {}; int ne = 0;
            for (int j = 0; j < ng; ++j) {
                int v = basis[j];
                bool ch = true;
                while (ch) { ch = false;
                    for (int k = 0; k < ne; ++k)
                        if (v && ((v >> hibit(ech[k])) & 1)) { v ^= ech[k]; ch = true; }
                }
                ech[ne++] = v;
            }
            // pad to 4 from null space of gate parity masks
            int nb = ng;
            for (int cand = 1; cand < DIM && nb < 4; ++cand) {
                bool ok = true;
                for (int j = 0; j < ng; ++j) if (parity14(cand & rr[j])) { ok = false; break; }
                if (!ok) continue;
                int v = cand;
                bool ch = true;
                while (ch) { ch = false;
                    for (int k = 0; k < ne; ++k)
                        if (v && ((v >> hibit(ech[k])) & 1)) { v ^= ech[k]; ch = true; }
                }
                if (v) { basis[nb++] = cand; ech[ne++] = v; }
            }
            // pivots & non-pivot positions
            int piv[4] = {};
            for (int k = 0; k < 4; ++k) piv[k] = hibit(ech[k]);
            for (int a = 0; a < 4; ++a)
                for (int b2 = a + 1; b2 < 4; ++b2)
                    if (piv[b2] < piv[a]) { int t = piv[a]; piv[a] = piv[b2]; piv[b2] = t; }
            int npp[10] = {}; int nn = 0;
            for (int bit = 0; bit < NW; ++bit) {
                bool isp = false;
                for (int k = 0; k < 4; ++k) if (piv[k] == bit) isp = true;
                if (!isp) npp[nn++] = bit;
            }
            // duality-corrected coset directions
            for (int k = 0; k < 10; ++k) {
                int c = 1 << npp[k];
                for (int j = 0; j < ng; ++j) if ((rr[j] >> npp[k]) & 1) c ^= basis[j];
                A.cvecA[bi][k] = c;
            }
            for (int e = 0; e < 16; ++e) {
                int v = 0;
                for (int j = 0; j < 4; ++j) if ((e >> j) & 1) v ^= basis[j];
                A.comboA[bi][e] = v;
            }
            for (int j = 0; j < 4; ++j) A.basisA[bi][j] = basis[j];
            for (int j = 0; j < 4; ++j) A.F[bi].col[j] = basis[j];
            for (int k = 0; k < 10; ++k) A.F[bi].col[4 + k] = A.cvecA[bi][k];
            w0 += ng;
            ++bi;
        }
        // CNOT chain (w,w+1) w=0..12 then (13,0)
        for (int w = 0; w < NW; ++w) {
            int c = w, t = (w + 1) % NW;
            int pc = 13 - c, pt = 13 - t;
            R[pt] ^= R[pc];
            C[pc] ^= C[pt];
        }
    }
    for (int p = 0; p < NW; ++p) A.Rf[p] = R[p];
    return A;
}

// ---- compile-time bank-conflict twist search (b32 rank-5 model) ----
struct Twist { unsigned t[10]; };

// rank of width-bit vectors over GF(2)
constexpr int rankv(const int* v, int nv, int width) {
    int basis[8] = {};
    int rk = 0;
    for (int i = 0; i < nv; ++i) {
        int x = v[i] & ((1 << width) - 1);
        for (int b = width - 1; b >= 0; --b) {
            if (!((x >> b) & 1)) continue;
            if (basis[b]) { x ^= basis[b]; continue; }
            basis[b] = x; ++rk; break;
        }
    }
    return rk;
}

// bank-image of pre-vector u (packed (e,y) space): idx bits [4:0]
constexpr int img5(int u, const unsigned* t) {
    int r = u & 31;
    for (int k = 0; k < 10; ++k) if ((u >> (4 + k)) & 1) r ^= (int)t[k];
    return r;
}

// b32 readers conflict-free iff the 5 half-wave lane-direction vectors span
// the 5-bit bank space (rank 5; 2-way-IN-PHASE is NOT free for b32).
// HARD: writer b128 quad-bank span {4^(t0>>2), t1>>2, t2>>2, t3>>2} rank 3.
constexpr int eval5(const unsigned* t, const int (*preR)[5], const int* preS) {
    {
        int w[4] = { 4 ^ (int)((t[0] >> 2) & 7), (int)((t[1] >> 2) & 7),
                     (int)((t[2] >> 2) & 7), (int)((t[3] >> 2) & 7) };
        if (rankv(w, 4, 3) < 3) return -1;
    }
    int sc = 0;
    for (int r = 1; r < 12; ++r) {
        int v[5];
        for (int i = 0; i < 5; ++i) v[i] = img5(preR[r][i], t);
        sc += rankv(v, 5, 5);
    }
    {
        int v[5];
        for (int i = 0; i < 5; ++i) v[i] = img5(preS[i], t);
        sc += rankv(v, 5, 5);
    }
    return sc;   // max 12*5 = 60
}

constexpr Twist find_twist() {
    Alg A = make_alg();
    int preR[12][5] = {};
    for (int r = 1; r < 12; ++r) {
        Lin Fi = lin_inverse(A.F[r - 1]);
        for (int k = 0; k < 4; ++k) preR[r][k] = lin_apply(Fi, A.cvecA[r][k]);
        preR[r][4] = lin_apply(Fi, A.basisA[r][2]);
    }
    int preS[5] = {};
    {
        Lin F0i = lin_inverse(A.F[0]);
        for (int k = 0; k < 5; ++k) preS[k] = lin_apply(F0i, 1 << (k + 2));
    }
    Twist best{};
    for (int k = 0; k < 10; ++k) best.t[k] = 0;
    int bs = eval5(best.t, preR, preS);
    unsigned x = 0x9E3779B9u;
    for (int s = 0; s < 2; ++s) {
        Twist cur{};
        if (s == 0) {
            for (int k = 0; k < 10; ++k) cur.t[k] = 0;
        } else {
            for (int k = 0; k < 10; ++k) {
                x = x * 1664525u + 1013904223u;
                const unsigned m = (k == 0) ? 3u : 7u;
                cur.t[k] = ((x >> 13) & m) << 2;
            }
        }
        int cs = eval5(cur.t, preR, preS);
        for (int pass = 0; pass < 2; ++pass) {
            for (int k = 0; k < 10; ++k) {
                unsigned bc = cur.t[k];
                int bv = cs;
                const unsigned lim = (k == 0) ? 16u : 32u;   // t0: bits[3:2] only
                for (unsigned c = 0; c < lim; c += 4) {
                    cur.t[k] = c;
                    const int e = eval5(cur.t, preR, preS);
                    if (e > bv) { bv = e; bc = c; }
                }
                cur.t[k] = bc;
                cs = bv;
            }
        }
        if (cs > bs) { bs = cs; best = cur; }
    }
    return best;
}

constexpr Twist TW = find_twist();

struct BatchP {
    int ngates;
    int gidx[4];
    unsigned rdy[10];   // byte: 4 * Lambda_{r-1}(cvec_r[k])  (y-bit directions)
    unsigned rde[16];   // byte: 4 * Lambda_{r-1}(combo_r[e]) (e-directions)
};
struct PlanP {
    BatchP b[12];
    unsigned stB[14];   // staging: byte 4 * Lambda_0(1<<bit)
    unsigned ykey[14];  // tail: parity mask over key = y | (q<<10)
    int zsel[14];       // tail: Walsh index from basis[0,1] parities
    unsigned tw[10];    // T twist columns (idx units, multiples of 4)
};

constexpr PlanP make_planp() {
    Alg A = make_alg();
    PlanP P{};
    for (int bi = 0; bi < 12; ++bi) {
        P.b[bi].ngates = A.ngates[bi];
        for (int j = 0; j < 4; ++j) P.b[bi].gidx[j] = A.gidx[bi][j];
    }
    // T: packed(e, y) -> idx = e ^ (y<<4) ^ twist(y)
    Lin T{};
    for (int j = 0; j < 4; ++j) T.col[j] = 1 << j;
    for (int k = 0; k < 10; ++k) T.col[4 + k] = (1 << (4 + k)) ^ (int)TW.t[k];

    // Lambda_w = T o F_w^{-1}; staging uses Lambda_0, reader r uses Lambda_{r-1}
    {
        Lin L0 = lin_compose(T, lin_inverse(A.F[0]));
        for (int bit = 0; bit < NW; ++bit) P.stB[bit] = (unsigned)lin_apply(L0, 1 << bit) * 4u;
    }
    for (int r = 1; r < 12; ++r) {
        Lin Lw = lin_compose(T, lin_inverse(A.F[r - 1]));
        for (int k = 0; k < 10; ++k) P.b[r].rdy[k] = (unsigned)lin_apply(Lw, A.cvecA[r][k]) * 4u;
        for (int e = 0; e < 16; ++e) P.b[r].rde[e] = (unsigned)lin_apply(Lw, A.comboA[r][e]) * 4u;
    }
    for (int w = 0; w < NW; ++w) {
        int zrw = A.Rf[13 - w];
        unsigned ym = 0;
        for (int k = 0; k < 10; ++k) ym |= (unsigned)parity14(A.cvecA[11][k] & zrw) << k;
        int qm = parity14(A.basisA[11][2] & zrw) | (parity14(A.basisA[11][3] & zrw) << 1);
        P.ykey[w] = ym | ((unsigned)qm << 10);
        P.zsel[w] = parity14(A.basisA[11][0] & zrw) | (parity14(A.basisA[11][1] & zrw) << 1);
    }
    for (int k = 0; k < 10; ++k) P.tw[k] = TW.t[k];
    return P;
}

constexpr PlanP PL = make_planp();

// per-tile byte offsets: t-bits are y-bits 4,5 -> idx bits 8,9 -> byte<<2,
// plus their twist columns (idx units -> byte = idx<<2)
constexpr unsigned TILE_OFF[4] = {
    0u,
    (1u << 10) ^ (PL.tw[4] << 2),
    (1u << 11) ^ (PL.tw[5] << 2),
    (1u << 10) ^ (1u << 11) ^ ((PL.tw[4] ^ PL.tw[5]) << 2)
};

// fp32 (r,i) -> packed f16 dword, round-to-nearest-even (unbiased)
__device__ __forceinline__ unsigned pk_rn(float r, float i) {
    const unsigned hr = (unsigned)__builtin_bit_cast(unsigned short, (_Float16)r);
    const unsigned hi = (unsigned)__builtin_bit_cast(unsigned short, (_Float16)i);
    return hr | (hi << 16);
}
// packed f16 dword -> fp32 (r,i)
__device__ __forceinline__ float2 up(unsigned d) {
    float2 c;
    c.x = (float)__builtin_bit_cast(_Float16, (unsigned short)(d & 0xffffu));
    c.y = (float)__builtin_bit_cast(_Float16, (unsigned short)(d >> 16));
    return c;
}

__device__ __forceinline__ f4 mfh(u4v a, u4v b, f4 c) {
    return __builtin_amdgcn_mfma_f32_16x16x32_f16(
        __builtin_bit_cast(h8, a), __builtin_bit_cast(h8, b), c, 0, 0, 0);
}

// scattered-read base for reader batch B: XOR-select over y-bits (n,wid) and
// q-part; per-tile t adds rdy[4]/rdy[5]; 4 entries at {0, rde1, rde2, rde3}.
#define RD_SREP(B)                                                     \
    unsigned srep = 0;                                                 \
    srep ^= (n & 1u)   ? B.rdy[0] : 0u;                                \
    srep ^= (n & 2u)   ? B.rdy[1] : 0u;                                \
    srep ^= (n & 4u)   ? B.rdy[2] : 0u;                                \
    srep ^= (n & 8u)   ? B.rdy[3] : 0u;                                \
    srep ^= (wid & 1u) ? B.rdy[6] : 0u;                                \
    srep ^= (wid & 2u) ? B.rdy[7] : 0u;                                \
    srep ^= (wid & 4u) ? B.rdy[8] : 0u;                                \
    srep ^= (wid & 8u) ? B.rdy[9] : 0u;                                \
    srep ^= (q & 1u)   ? B.rde[4] : 0u;                                \
    srep ^= (q & 2u)   ? B.rde[8] : 0u;

template <int BI>
__device__ __forceinline__ void mfma_batch(char* __restrict__ lds, const float* __restrict__ gm,
                                           unsigned* __restrict__ atab, const unsigned bnq) {
    constexpr BatchP B = PL.b[BI];
    const unsigned tid = threadIdx.x;
    const unsigned lane = tid & 63u, wid = tid >> 6;
    const unsigned n = lane & 15u, q = lane >> 4;

    __syncthreads();   // prev batch stores visible; prev atab reads done

    // ---- A-table build (threads 0..255), f16 hi/lo, concurrent with phase A ----
    if (tid < 256) {
        const unsigned m = tid >> 4, ein = tid & 15u;
        float wr = 1.f, wi = 0.f;
        #pragma unroll
        for (int j = 0; j < 4; ++j) {
            if (j < B.ngates) {
                const unsigned mj = (m >> j) & 1u, ej = (ein >> j) & 1u;
                const float ur = gm[B.gidx[j] * 8 + (int)(mj * 4u + ej * 2u)];
                const float ui = gm[B.gidx[j] * 8 + (int)(mj * 4u + ej * 2u) + 1];
                const float nr = wr * ur - wi * ui;
                const float ni = wr * ui + wi * ur;
                wr = nr; wi = ni;
            }
        }
        if (B.ngates < 4 && (((m ^ ein) >> B.ngates) != 0u)) { wr = 0.f; wi = 0.f; }
        const float nwi = -wi;
        const unsigned h0 = pk_rn(wr, nwi);          // (Wr_hi, -Wi_hi) r-out
        const float2 h0f = up(h0);
        const unsigned l0 = pk_rn(wr - h0f.x, nwi - h0f.y);
        const unsigned h1 = pk_rn(wi, wr);           // (Wi_hi, Wr_hi) i-out
        const float2 h1f = up(h1);
        const unsigned l1 = pk_rn(wi - h1f.x, wr - h1f.y);
        const unsigned o = m * 16u + ein;
        atab[o]        = h0;
        atab[256 + o]  = l0;
        atab[512 + o]  = h1;
        atab[768 + o]  = l1;
    }

    // ---- phase A: pure loads (state IS the f16 B-fragment) ----
    u4v bfr[4];
    if constexpr (BI == 0) {
        #pragma unroll
        for (int t = 0; t < 4; ++t) {
            bfr[t] = *(const u4v*)(lds + (bnq ^ TILE_OFF[t]));
        }
    } else {
        RD_SREP(B)
        #pragma unroll
        for (int t = 0; t < 4; ++t) {
            const unsigned st = srep ^ ((t & 1) ? B.rdy[4] : 0u) ^ ((t & 2) ? B.rdy[5] : 0u);
            const unsigned c0 = *(const unsigned*)(lds + st);
            const unsigned c1 = *(const unsigned*)(lds + (st ^ B.rde[1]));
            const unsigned c2 = *(const unsigned*)(lds + (st ^ B.rde[2]));
            const unsigned c3 = *(const unsigned*)(lds + (st ^ B.rde[3]));
            u4v v; v.x = c0; v.y = c1; v.z = c2; v.w = c3;
            bfr[t] = v;
        }
    }

    __syncthreads();   // all reads done + atab ready

    // ---- phase B: 4 mfma/tile + RNE pack + 1 clean b128 store/tile ----
    const u4v A0 = *(const u4v*)&atab[(n << 4) + (q << 2)];
    const u4v A1 = *(const u4v*)&atab[256 + (n << 4) + (q << 2)];
    const u4v A2 = *(const u4v*)&atab[512 + (n << 4) + (q << 2)];
    const u4v A3 = *(const u4v*)&atab[768 + (n << 4) + (q << 2)];

    #pragma unroll
    for (int t = 0; t < 4; ++t) {
        f4 ar = {0.f, 0.f, 0.f, 0.f};
        f4 ai = {0.f, 0.f, 0.f, 0.f};
        ar = mfh(A0, bfr[t], ar);
        ai = mfh(A2, bfr[t], ai);
        ar = mfh(A1, bfr[t], ar);
        ai = mfh(A3, bfr[t], ai);
        u4v s;
        s.x = pk_rn(ar.x, ai.x);
        s.y = pk_rn(ar.y, ai.y);
        s.z = pk_rn(ar.z, ai.z);
        s.w = pk_rn(ar.w, ai.w);
        *(u4v*)(lds + (bnq ^ TILE_OFF[t])) = s;
    }
}

// complex 2x2 butterfly
#define BFC(A, B_, ua, ub) { const float2 t0 = A, t1 = B_; \
    A.x  = ua.x * t0.x - ua.y * t0.y + ua.z * t1.x - ua.w * t1.y; \
    A.y  = ua.x * t0.y + ua.y * t0.x + ua.z * t1.y + ua.w * t1.x; \
    B_.x = ub.x * t0.x - ub.y * t0.y + ub.z * t1.x - ub.w * t1.y; \
    B_.y = ub.x * t0.y + ub.y * t0.x + ub.z * t1.y + ub.w * t1.x; }

__device__ __forceinline__ float tail_batch(char* __restrict__ lds, const float* __restrict__ gm,
                                            const float* __restrict__ g_hw) {
    constexpr BatchP B = PL.b[11];   // ngates == 2
    const unsigned tid = threadIdx.x;
    const unsigned lane = tid & 63u, wid = tid >> 6;
    const unsigned n = lane & 15u, q = lane >> 4;
    __syncthreads();
    const f4 u0a = *(const f4*)&gm[B.gidx[0] * 8];
    const f4 u0b = *(const f4*)&gm[B.gidx[0] * 8 + 4];
    const f4 u1a = *(const f4*)&gm[B.gidx[1] * 8];
    const f4 u1b = *(const f4*)&gm[B.gidx[1] * 8 + 4];
    float hwv[NW];
    #pragma unroll
    for (int w = 0; w < NW; ++w) hwv[w] = g_hw[w];
    float acc = 0.f;
    RD_SREP(B)
    #pragma unroll
    for (int t = 0; t < 4; ++t) {
        const unsigned st = srep ^ ((t & 1) ? B.rdy[4] : 0u) ^ ((t & 2) ? B.rdy[5] : 0u);
        float2 c0 = up(*(const unsigned*)(lds + st));
        float2 c1 = up(*(const unsigned*)(lds + (st ^ B.rde[1])));
        float2 c2 = up(*(const unsigned*)(lds + (st ^ B.rde[2])));
        float2 c3 = up(*(const unsigned*)(lds + (st ^ B.rde[3])));
        BFC(c0, c1, u0a, u0b)  BFC(c2, c3, u0a, u0b)   // gate 0: slot bit 0
        BFC(c0, c2, u1a, u1b)  BFC(c1, c3, u1a, u1b)   // gate 1: slot bit 1
        const float p0 = c0.x * c0.x + c0.y * c0.y;
        const float p1 = c1.x * c1.x + c1.y * c1.y;
        const float p2 = c2.x * c2.x + c2.y * c2.y;
        const float p3 = c3.x * c3.x + c3.y * c3.y;
        const float sa = p0 + p1, sb = p0 - p1, sc = p2 + p3, sd = p2 - p3;
        const float W4[4] = {sa + sc, sb + sd, sa - sc, sb - sd};
        const unsigned y = (wid << 6) | ((unsigned)t << 4) | n;
        const unsigned key = y | (q << 10);
        #pragma unroll
        for (int w = 0; w < NW; ++w) {
            const unsigned sg = ((unsigned)__popc(key & PL.ykey[w])) << 31;
            const float s = __uint_as_float(__float_as_uint(hwv[w]) ^ sg);
            acc += W4[PL.zsel[w]] * s;
        }
    }
    return acc;
}

__global__ __launch_bounds__(BLOCK, 8) void qsim_kernel(
    const float* __restrict__ g_sr, const float* __restrict__ g_si,
    const float* __restrict__ g_params, const float* __restrict__ g_hw,
    const float* __restrict__ g_hb, float* __restrict__ g_out)
{
    extern __shared__ char lds[];                    // 16384 packed-f16 amps (64 KiB)
    __shared__ __align__(16) float gm[NGAT * 8];
    __shared__ __align__(16) unsigned atab[1024];    // 4 A-tables, 16x32 f16 each
    __shared__ float red[BLOCK / 64];

    const unsigned tid = threadIdx.x;
    const int b = blockIdx.x;
    const float* __restrict__ srcr = g_sr + (size_t)b * DIM;
    const float* __restrict__ srci = g_si + (size_t)b * DIM;

    // ---- gate matrices U = RZ @ RY @ RX ----
    if (tid < NGAT) {
        const float tx = g_params[tid * 3 + 0];
        const float ty = g_params[tid * 3 + 1];
        const float tz = g_params[tid * 3 + 2];
        const float cx = cosf(0.5f * tx), sx = sinf(0.5f * tx);
        const float cy = cosf(0.5f * ty), sy = sinf(0.5f * ty);
        const float cz = cosf(0.5f * tz), sz = sinf(0.5f * tz);
        const float a00r = cy * cx,  a00i = sy * sx;
        const float a01r = -sy * cx, a01i = -cy * sx;
        const float a10r = sy * cx,  a10i = -cy * sx;
        const float a11r = cy * cx,  a11i = -sy * sx;
        gm[tid * 8 + 0] = cz * a00r + sz * a00i;
        gm[tid * 8 + 1] = cz * a00i - sz * a00r;
        gm[tid * 8 + 2] = cz * a01r + sz * a01i;
        gm[tid * 8 + 3] = cz * a01i - sz * a01r;
        gm[tid * 8 + 4] = cz * a10r - sz * a10i;
        gm[tid * 8 + 5] = cz * a10i + sz * a10r;
        gm[tid * 8 + 6] = cz * a11r - sz * a11i;
        gm[tid * 8 + 7] = cz * a11i + sz * a11r;
    }

    // writer-frame base for this thread (computed ONCE; T twist folded in).
    // twist cols are multiples of 4 -> b128 quads stay contiguous in e.
    const unsigned lane0 = tid & 63u, wid0 = tid >> 6;
    const unsigned n0 = lane0 & 15u, q0 = lane0 >> 4;
    unsigned twv = 0;
    #pragma unroll
    for (int k = 0; k < 4; ++k) twv ^= ((n0 >> k) & 1u) ? PL.tw[k] : 0u;
    #pragma unroll
    for (int k = 0; k < 4; ++k) twv ^= ((wid0 >> k) & 1u) ? PL.tw[6 + k] : 0u;
    const unsigned bnq = ((wid0 << 10) ^ (n0 << 4) ^ (q0 << 2) ^ twv) << 2;

    // ---- staging: global fp32 -> packed f16 in Lambda_0 layout ----
    unsigned bb = 0;
    #pragma unroll
    for (int k = 0; k < 10; ++k) bb ^= ((tid >> k) & 1u) ? PL.stB[k + 2] : 0u;
    #pragma unroll
    for (int it = 0; it < 4; ++it) {
        const int x = (int)tid * 4 + it * 4096;
        const f4 r4 = *(const f4*)(srcr + x);
        const f4 i4 = *(const f4*)(srci + x);
        const unsigned base = bb ^ ((it & 1) ? PL.stB[12] : 0u) ^ ((it & 2) ? PL.stB[13] : 0u);
        *(unsigned*)(lds + base) = pk_rn(r4.x, i4.x);
        *(unsigned*)(lds + (base ^ PL.stB[0])) = pk_rn(r4.y, i4.y);
        *(unsigned*)(lds + (base ^ PL.stB[1])) = pk_rn(r4.z, i4.z);
        *(unsigned*)(lds + (base ^ (PL.stB[0] ^ PL.stB[1]))) = pk_rn(r4.w, i4.w);
    }

    mfma_batch<0>(lds, gm, atab, bnq);
    mfma_batch<1>(lds, gm, atab, bnq);
    mfma_batch<2>(lds, gm, atab, bnq);
    mfma_batch<3>(lds, gm, atab, bnq);
    mfma_batch<4>(lds, gm, atab, bnq);
    mfma_batch<5>(lds, gm, atab, bnq);
    mfma_batch<6>(lds, gm, atab, bnq);
    mfma_batch<7>(lds, gm, atab, bnq);
    mfma_batch<8>(lds, gm, atab, bnq);
    mfma_batch<9>(lds, gm, atab, bnq);
    mfma_batch<10>(lds, gm, atab, bnq);

    float acc = tail_batch(lds, gm, g_hw);

    // ---- reduce ----
    #pragma unroll
    for (int off = 32; off > 0; off >>= 1) acc += __shfl_down(acc, off);
    const int lane = tid & 63, wid = tid >> 6;
    if (lane == 0) red[wid] = acc;
    __syncthreads();
    if (tid == 0) {
        float s = 0.0f;
        #pragma unroll
        for (int k = 0; k < BLOCK / 64; ++k) s += red[k];
        g_out[b] = s + g_hb[0];
    }
}

extern "C" void kernel_launch(void* const* d_in, const int* in_sizes, int n_in,
                              void* d_out, int out_size, void* d_ws, size_t ws_size,
                              hipStream_t stream) {
    const float* sr = (const float*)d_in[0];
    const float* si = (const float*)d_in[1];
    const float* vp = (const float*)d_in[2];
    const float* hw = (const float*)d_in[3];
    const float* hb = (const float*)d_in[4];
    float* out = (float*)d_out;

    dim3 grid(out_size);          // 1024 batch elements, one block each
    dim3 block(BLOCK);
    size_t shmem = (size_t)DIM * 4;  // 64 KiB dynamic LDS (packed f16 amps)
    qsim_kernel<<<grid, block, shmem, stream>>>(sr, si, vp, hw, hb, out);
}

// Round 8
// 192.377 us; speedup vs baseline: 1.3276x; 1.0657x over previous
//
#include <hip/hip_runtime.h>

#define NW 14
#define NL 3
#define NGAT 42            // 3 layers x 14 rotation gates
#define DIM 16384          // 2^14 amplitudes
#define BLOCK 1024

// ---------------------------------------------------------------------------
// Round 19: r17 base (fp16 @ 4 B/amp, 2 blocks/CU, 107us steady, passing)
// with the W-LO CORRECTION DROPPED. r18's batch-pair fusion failed absmax
// (4.3e-3 ~ a low-order-term defect not locatable by inspection) — parked.
// Precision budget: r17's 2.44e-4 absmax = 12 RNE state-roundings @ ~2^-11
// relative. Hi-only W adds 11 comparable perturbations (unitary row norms ->
// same magnitude class) -> ~sqrt(23/12) = 1.38x -> ~3.4e-4, still 2.5x
// under the 8.4e-4 threshold. Savings/thread: 88 of 264 MFMAs, 22 b128
// table reads, half the table build. Executed-op count is the one signal
// that has reliably moved time (r16); conflicts/phase moves were not.
// Everything else is byte-identical to the passing r17 kernel.
// ---------------------------------------------------------------------------

typedef float        f4  __attribute__((ext_vector_type(4)));
typedef _Float16     h8  __attribute__((ext_vector_type(8)));
typedef unsigned int u4v __attribute__((ext_vector_type(4)));

constexpr int parity14(int v) { int p = 0; for (int i = 0; i < NW; ++i) p ^= (v >> i) & 1; return p; }
constexpr int hibit(int v) { int h = -1; for (int i = 0; i < NW; ++i) if ((v >> i) & 1) h = i; return h; }

struct Lin { int col[NW]; };

constexpr int lin_apply(const Lin& M, int x) {
    int r = 0;
    for (int i = 0; i < NW; ++i) if ((x >> i) & 1) r ^= M.col[i];
    return r;
}
constexpr Lin lin_inverse(const Lin& M) {
    int E[NW] = {}, P[NW] = {};
    for (int i = 0; i < NW; ++i) {
        int v = M.col[i], p = 1 << i;
        while (v) {
            int h = hibit(v);
            if (!E[h]) { E[h] = v; P[h] = p; break; }
            v ^= E[h]; p ^= P[h];
        }
    }
    Lin R{};
    for (int i = 0; i < NW; ++i) {
        int v = 1 << i, p = 0;
        while (v) { int h = hibit(v); v ^= E[h]; p ^= P[h]; }
        R.col[i] = p;
    }
    return R;
}
constexpr Lin lin_compose(const Lin& A, const Lin& B) {
    Lin R{};
    for (int i = 0; i < NW; ++i) R.col[i] = lin_apply(A, B.col[i]);
    return R;
}

// ---- algorithm structure (frames, cosets, duality corrections) ----
struct Alg {
    int ngates[12];
    int gidx[12][4];
    int basisA[12][4];
    int comboA[12][16];
    int cvecA[12][10];
    Lin F[12];
    int Rf[NW];         // final Z-row masks for the tail features
};

constexpr Alg make_alg() {
    Alg A{};
    int R[NW] = {}, C[NW] = {};
    for (int p = 0; p < NW; ++p) { R[p] = 1 << p; C[p] = 1 << p; }
    int bi = 0;
    for (int l = 0; l < NL; ++l) {
        const int sizes[4] = {4, 4, 4, 2};
        int w0 = 0;
        for (int s = 0; s < 4; ++s) {
            const int ng = sizes[s];
            A.ngates[bi] = ng;
            int basis[4] = {}, rr[4] = {};
            for (int j = 0; j < ng; ++j) {
                int w = w0 + j, p = 13 - w;
                basis[j] = C[p];
                rr[j] = R[p];
                A.gidx[bi][j] = l * NW + w;
            }
            // echelon for independence
            int ech[4] = {}; int ne = 0;
            for (int j = 0; j < ng; ++j) {
                int v = basis[j];
                bool ch = true;
                while (ch) { ch = false;
                    for (int k = 0; k < ne; ++k)
                        if (v && ((v >> hibit(ech[k])) & 1)) { v ^= ech[k]; ch = true; }
                }
                ech[ne++] = v;
            }
            // pad to 4 from null space of gate parity masks
            int nb = ng;
            for (int cand = 1; cand < DIM && nb < 4; ++cand) {
                bool ok = true;
                for (int j = 0; j < ng; ++j) if (parity14(cand & rr[j])) { ok = false; break; }
                if (!ok) continue;
                int v = cand;
                bool ch = true;
                while (ch) { ch = false;
                    for (int k = 0; k < ne; ++k)
                        if (v && ((v >> hibit(ech[k])) & 1)) { v ^= ech[k]; ch = true; }
                }
                if (v) { basis[nb++] = cand; ech[ne++] = v; }
            }
            // pivots & non-pivot positions
            int piv[4] = {};
            for (int k = 0; k < 4; ++k) piv[k] = hibit(ech[k]);
            for (int a = 0; a < 4; ++a)
                for (int b2 = a + 1; b2 < 4; ++b2)
                    if (piv[b2] < piv[a]) { int t = piv[a]; piv[a] = piv[b2]; piv[b2] = t; }
            int npp[10] = {}; int nn = 0;
            for (int bit = 0; bit < NW; ++bit) {
                bool isp = false;
                for (int k = 0; k < 4; ++k) if (piv[k] == bit) isp = true;
                if (!isp) npp[nn++] = bit;
            }
            // duality-corrected coset directions
            for (int k = 0; k < 10; ++k) {
                int c = 1 << npp[k];
                for (int j = 0; j < ng; ++j) if ((rr[j] >> npp[k]) & 1) c ^= basis[j];
                A.cvecA[bi][k] = c;
            }
            for (int e = 0; e < 16; ++e) {
                int v = 0;
                for (int j = 0; j < 4; ++j) if ((e >> j) & 1) v ^= basis[j];
                A.comboA[bi][e] = v;
            }
            for (int j = 0; j < 4; ++j) A.basisA[bi][j] = basis[j];
            for (int j = 0; j < 4; ++j) A.F[bi].col[j] = basis[j];
            for (int k = 0; k < 10; ++k) A.F[bi].col[4 + k] = A.cvecA[bi][k];
            w0 += ng;
            ++bi;
        }
        // CNOT chain (w,w+1) w=0..12 then (13,0)
        for (int w = 0; w < NW; ++w) {
            int c = w, t = (w + 1) % NW;
            int pc = 13 - c, pt = 13 - t;
            R[pt] ^= R[pc];
            C[pc] ^= C[pt];
        }
    }
    for (int p = 0; p < NW; ++p) A.Rf[p] = R[p];
    return A;
}

// ---- compile-time bank-conflict twist search (b32 rank-5 model) ----
struct Twist { unsigned t[10]; };

// rank of width-bit vectors over GF(2)
constexpr int rankv(const int* v, int nv, int width) {
    int basis[8] = {};
    int rk = 0;
    for (int i = 0; i < nv; ++i) {
        int x = v[i] & ((1 << width) - 1);
        for (int b = width - 1; b >= 0; --b) {
            if (!((x >> b) & 1)) continue;
            if (basis[b]) { x ^= basis[b]; continue; }
            basis[b] = x; ++rk; break;
        }
    }
    return rk;
}

// bank-image of pre-vector u (packed (e,y) space): idx bits [4:0]
constexpr int img5(int u, const unsigned* t) {
    int r = u & 31;
    for (int k = 0; k < 10; ++k) if ((u >> (4 + k)) & 1) r ^= (int)t[k];
    return r;
}

// b32 readers conflict-free iff the 5 half-wave lane-direction vectors span
// the 5-bit bank space (rank 5; 2-way-IN-PHASE is NOT free for b32).
// HARD: writer b128 quad-bank span {4^(t0>>2), t1>>2, t2>>2, t3>>2} rank 3.
constexpr int eval5(const unsigned* t, const int (*preR)[5], const int* preS) {
    {
        int w[4] = { 4 ^ (int)((t[0] >> 2) & 7), (int)((t[1] >> 2) & 7),
                     (int)((t[2] >> 2) & 7), (int)((t[3] >> 2) & 7) };
        if (rankv(w, 4, 3) < 3) return -1;
    }
    int sc = 0;
    for (int r = 1; r < 12; ++r) {
        int v[5];
        for (int i = 0; i < 5; ++i) v[i] = img5(preR[r][i], t);
        sc += rankv(v, 5, 5);
    }
    {
        int v[5];
        for (int i = 0; i < 5; ++i) v[i] = img5(preS[i], t);
        sc += rankv(v, 5, 5);
    }
    return sc;   // max 12*5 = 60
}

constexpr Twist find_twist() {
    Alg A = make_alg();
    int preR[12][5] = {};
    for (int r = 1; r < 12; ++r) {
        Lin Fi = lin_inverse(A.F[r - 1]);
        for (int k = 0; k < 4; ++k) preR[r][k] = lin_apply(Fi, A.cvecA[r][k]);
        preR[r][4] = lin_apply(Fi, A.basisA[r][2]);
    }
    int preS[5] = {};
    {
        Lin F0i = lin_inverse(A.F[0]);
        for (int k = 0; k < 5; ++k) preS[k] = lin_apply(F0i, 1 << (k + 2));
    }
    Twist best{};
    for (int k = 0; k < 10; ++k) best.t[k] = 0;
    int bs = eval5(best.t, preR, preS);
    unsigned x = 0x9E3779B9u;
    for (int s = 0; s < 2; ++s) {
        Twist cur{};
        if (s == 0) {
            for (int k = 0; k < 10; ++k) cur.t[k] = 0;
        } else {
            for (int k = 0; k < 10; ++k) {
                x = x * 1664525u + 1013904223u;
                const unsigned m = (k == 0) ? 3u : 7u;
                cur.t[k] = ((x >> 13) & m) << 2;
            }
        }
        int cs = eval5(cur.t, preR, preS);
        for (int pass = 0; pass < 2; ++pass) {
            for (int k = 0; k < 10; ++k) {
                unsigned bc = cur.t[k];
                int bv = cs;
                const unsigned lim = (k == 0) ? 16u : 32u;   // t0: bits[3:2] only
                for (unsigned c = 0; c < lim; c += 4) {
                    cur.t[k] = c;
                    const int e = eval5(cur.t, preR, preS);
                    if (e > bv) { bv = e; bc = c; }
                }
                cur.t[k] = bc;
                cs = bv;
            }
        }
        if (cs > bs) { bs = cs; best = cur; }
    }
    return best;
}

constexpr Twist TW = find_twist();

struct BatchP {
    int ngates;
    int gidx[4];
    unsigned rdy[10];   // byte: 4 * Lambda_{r-1}(cvec_r[k])  (y-bit directions)
    unsigned rde[16];   // byte: 4 * Lambda_{r-1}(combo_r[e]) (e-directions)
};
struct PlanP {
    BatchP b[12];
    unsigned stB[14];   // staging: byte 4 * Lambda_0(1<<bit)
    unsigned ykey[14];  // tail: parity mask over key = y | (q<<10)
    int zsel[14];       // tail: Walsh index from basis[0,1] parities
    unsigned tw[10];    // T twist columns (idx units, multiples of 4)
};

constexpr PlanP make_planp() {
    Alg A = make_alg();
    PlanP P{};
    for (int bi = 0; bi < 12; ++bi) {
        P.b[bi].ngates = A.ngates[bi];
        for (int j = 0; j < 4; ++j) P.b[bi].gidx[j] = A.gidx[bi][j];
    }
    // T: packed(e, y) -> idx = e ^ (y<<4) ^ twist(y)
    Lin T{};
    for (int j = 0; j < 4; ++j) T.col[j] = 1 << j;
    for (int k = 0; k < 10; ++k) T.col[4 + k] = (1 << (4 + k)) ^ (int)TW.t[k];

    // Lambda_w = T o F_w^{-1}; staging uses Lambda_0, reader r uses Lambda_{r-1}
    {
        Lin L0 = lin_compose(T, lin_inverse(A.F[0]));
        for (int bit = 0; bit < NW; ++bit) P.stB[bit] = (unsigned)lin_apply(L0, 1 << bit) * 4u;
    }
    for (int r = 1; r < 12; ++r) {
        Lin Lw = lin_compose(T, lin_inverse(A.F[r - 1]));
        for (int k = 0; k < 10; ++k) P.b[r].rdy[k] = (unsigned)lin_apply(Lw, A.cvecA[r][k]) * 4u;
        for (int e = 0; e < 16; ++e) P.b[r].rde[e] = (unsigned)lin_apply(Lw, A.comboA[r][e]) * 4u;
    }
    for (int w = 0; w < NW; ++w) {
        int zrw = A.Rf[13 - w];
        unsigned ym = 0;
        for (int k = 0; k < 10; ++k) ym |= (unsigned)parity14(A.cvecA[11][k] & zrw) << k;
        int qm = parity14(A.basisA[11][2] & zrw) | (parity14(A.basisA[11][3] & zrw) << 1);
        P.ykey[w] = ym | ((unsigned)qm << 10);
        P.zsel[w] = parity14(A.basisA[11][0] & zrw) | (parity14(A.basisA[11][1] & zrw) << 1);
    }
    for (int k = 0; k < 10; ++k) P.tw[k] = TW.t[k];
    return P;
}

constexpr PlanP PL = make_planp();

// per-tile byte offsets: t-bits are y-bits 4,5 -> idx bits 8,9 -> byte<<2,
// plus their twist columns (idx units -> byte = idx<<2)
constexpr unsigned TILE_OFF[4] = {
    0u,
    (1u << 10) ^ (PL.tw[4] << 2),
    (1u << 11) ^ (PL.tw[5] << 2),
    (1u << 10) ^ (1u << 11) ^ ((PL.tw[4] ^ PL.tw[5]) << 2)
};

// fp32 (r,i) -> packed f16 dword, round-to-nearest-even (unbiased)
__device__ __forceinline__ unsigned pk_rn(float r, float i) {
    const unsigned hr = (unsigned)__builtin_bit_cast(unsigned short, (_Float16)r);
    const unsigned hi = (unsigned)__builtin_bit_cast(unsigned short, (_Float16)i);
    return hr | (hi << 16);
}
// packed f16 dword -> fp32 (r,i)
__device__ __forceinline__ float2 up(unsigned d) {
    float2 c;
    c.x = (float)__builtin_bit_cast(_Float16, (unsigned short)(d & 0xffffu));
    c.y = (float)__builtin_bit_cast(_Float16, (unsigned short)(d >> 16));
    return c;
}

__device__ __forceinline__ f4 mfh(u4v a, u4v b, f4 c) {
    return __builtin_amdgcn_mfma_f32_16x16x32_f16(
        __builtin_bit_cast(h8, a), __builtin_bit_cast(h8, b), c, 0, 0, 0);
}

// scattered-read base for reader batch B: XOR-select over y-bits (n,wid) and
// q-part; per-tile t adds rdy[4]/rdy[5]; 4 entries at {0, rde1, rde2, rde3}.
#define RD_SREP(B)                                                     \
    unsigned srep = 0;                                                 \
    srep ^= (n & 1u)   ? B.rdy[0] : 0u;                                \
    srep ^= (n & 2u)   ? B.rdy[1] : 0u;                                \
    srep ^= (n & 4u)   ? B.rdy[2] : 0u;                                \
    srep ^= (n & 8u)   ? B.rdy[3] : 0u;                                \
    srep ^= (wid & 1u) ? B.rdy[6] : 0u;                                \
    srep ^= (wid & 2u) ? B.rdy[7] : 0u;                                \
    srep ^= (wid & 4u) ? B.rdy[8] : 0u;                                \
    srep ^= (wid & 8u) ? B.rdy[9] : 0u;                                \
    srep ^= (q & 1u)   ? B.rde[4] : 0u;                                \
    srep ^= (q & 2u)   ? B.rde[8] : 0u;

template <int BI>
__device__ __forceinline__ void mfma_batch(char* __restrict__ lds, const float* __restrict__ gm,
                                           unsigned* __restrict__ atab, const unsigned bnq) {
    constexpr BatchP B = PL.b[BI];
    const unsigned tid = threadIdx.x;
    const unsigned lane = tid & 63u, wid = tid >> 6;
    const unsigned n = lane & 15u, q = lane >> 4;

    __syncthreads();   // prev batch stores visible; prev atab reads done

    // ---- A-table build (threads 0..255), f16 HI-ONLY, concurrent w/ phase A ----
    if (tid < 256) {
        const unsigned m = tid >> 4, ein = tid & 15u;
        float wr = 1.f, wi = 0.f;
        #pragma unroll
        for (int j = 0; j < 4; ++j) {
            if (j < B.ngates) {
                const unsigned mj = (m >> j) & 1u, ej = (ein >> j) & 1u;
                const float ur = gm[B.gidx[j] * 8 + (int)(mj * 4u + ej * 2u)];
                const float ui = gm[B.gidx[j] * 8 + (int)(mj * 4u + ej * 2u) + 1];
                const float nr = wr * ur - wi * ui;
                const float ni = wr * ui + wi * ur;
                wr = nr; wi = ni;
            }
        }
        if (B.ngates < 4 && (((m ^ ein) >> B.ngates) != 0u)) { wr = 0.f; wi = 0.f; }
        const unsigned o = m * 16u + ein;
        atab[o]        = pk_rn(wr, -wi);   // (Wr, -Wi) -> real output
        atab[256 + o]  = pk_rn(wi, wr);    // (Wi,  Wr) -> imag output
    }

    // ---- phase A: pure loads (state IS the f16 B-fragment) ----
    u4v bfr[4];
    if constexpr (BI == 0) {
        #pragma unroll
        for (int t = 0; t < 4; ++t) {
            bfr[t] = *(const u4v*)(lds + (bnq ^ TILE_OFF[t]));
        }
    } else {
        RD_SREP(B)
        #pragma unroll
        for (int t = 0; t < 4; ++t) {
            const unsigned st = srep ^ ((t & 1) ? B.rdy[4] : 0u) ^ ((t & 2) ? B.rdy[5] : 0u);
            const unsigned c0 = *(const unsigned*)(lds + st);
            const unsigned c1 = *(const unsigned*)(lds + (st ^ B.rde[1]));
            const unsigned c2 = *(const unsigned*)(lds + (st ^ B.rde[2]));
            const unsigned c3 = *(const unsigned*)(lds + (st ^ B.rde[3]));
            u4v v; v.x = c0; v.y = c1; v.z = c2; v.w = c3;
            bfr[t] = v;
        }
    }

    __syncthreads();   // all reads done + atab ready

    // ---- phase B: 2 mfma/tile + RNE pack + 1 clean b128 store/tile ----
    const u4v A0 = *(const u4v*)&atab[(n << 4) + (q << 2)];
    const u4v A1 = *(const u4v*)&atab[256 + (n << 4) + (q << 2)];

    #pragma unroll
    for (int t = 0; t < 4; ++t) {
        f4 ar = {0.f, 0.f, 0.f, 0.f};
        f4 ai = {0.f, 0.f, 0.f, 0.f};
        ar = mfh(A0, bfr[t], ar);
        ai = mfh(A1, bfr[t], ai);
        u4v s;
        s.x = pk_rn(ar.x, ai.x);
        s.y = pk_rn(ar.y, ai.y);
        s.z = pk_rn(ar.z, ai.z);
        s.w = pk_rn(ar.w, ai.w);
        *(u4v*)(lds + (bnq ^ TILE_OFF[t])) = s;
    }
}

// complex 2x2 butterfly
#define BFC(A, B_, ua, ub) { const float2 t0 = A, t1 = B_; \
    A.x  = ua.x * t0.x - ua.y * t0.y + ua.z * t1.x - ua.w * t1.y; \
    A.y  = ua.x * t0.y + ua.y * t0.x + ua.z * t1.y + ua.w * t1.x; \
    B_.x = ub.x * t0.x - ub.y * t0.y + ub.z * t1.x - ub.w * t1.y; \
    B_.y = ub.x * t0.y + ub.y * t0.x + ub.z * t1.y + ub.w * t1.x; }

__device__ __forceinline__ float tail_batch(char* __restrict__ lds, const float* __restrict__ gm,
                                            const float* __restrict__ g_hw) {
    constexpr BatchP B = PL.b[11];   // ngates == 2
    const unsigned tid = threadIdx.x;
    const unsigned lane = tid & 63u, wid = tid >> 6;
    const unsigned n = lane & 15u, q = lane >> 4;
    __syncthreads();
    const f4 u0a = *(const f4*)&gm[B.gidx[0] * 8];
    const f4 u0b = *(const f4*)&gm[B.gidx[0] * 8 + 4];
    const f4 u1a = *(const f4*)&gm[B.gidx[1] * 8];
    const f4 u1b = *(const f4*)&gm[B.gidx[1] * 8 + 4];
    float hwv[NW];
    #pragma unroll
    for (int w = 0; w < NW; ++w) hwv[w] = g_hw[w];
    float acc = 0.f;
    RD_SREP(B)
    #pragma unroll
    for (int t = 0; t < 4; ++t) {
        const unsigned st = srep ^ ((t & 1) ? B.rdy[4] : 0u) ^ ((t & 2) ? B.rdy[5] : 0u);
        float2 c0 = up(*(const unsigned*)(lds + st));
        float2 c1 = up(*(const unsigned*)(lds + (st ^ B.rde[1])));
        float2 c2 = up(*(const unsigned*)(lds + (st ^ B.rde[2])));
        float2 c3 = up(*(const unsigned*)(lds + (st ^ B.rde[3])));
        BFC(c0, c1, u0a, u0b)  BFC(c2, c3, u0a, u0b)   // gate 0: slot bit 0
        BFC(c0, c2, u1a, u1b)  BFC(c1, c3, u1a, u1b)   // gate 1: slot bit 1
        const float p0 = c0.x * c0.x + c0.y * c0.y;
        const float p1 = c1.x * c1.x + c1.y * c1.y;
        const float p2 = c2.x * c2.x + c2.y * c2.y;
        const float p3 = c3.x * c3.x + c3.y * c3.y;
        const float sa = p0 + p1, sb = p0 - p1, sc = p2 + p3, sd = p2 - p3;
        const float W4[4] = {sa + sc, sb + sd, sa - sc, sb - sd};
        const unsigned y = (wid << 6) | ((unsigned)t << 4) | n;
        const unsigned key = y | (q << 10);
        #pragma unroll
        for (int w = 0; w < NW; ++w) {
            const unsigned sg = ((unsigned)__popc(key & PL.ykey[w])) << 31;
            const float s = __uint_as_float(__float_as_uint(hwv[w]) ^ sg);
            acc += W4[PL.zsel[w]] * s;
        }
    }
    return acc;
}

__global__ __launch_bounds__(BLOCK, 8) void qsim_kernel(
    const float* __restrict__ g_sr, const float* __restrict__ g_si,
    const float* __restrict__ g_params, const float* __restrict__ g_hw,
    const float* __restrict__ g_hb, float* __restrict__ g_out)
{
    extern __shared__ char lds[];                    // 16384 packed-f16 amps (64 KiB)
    __shared__ __align__(16) float gm[NGAT * 8];
    __shared__ __align__(16) unsigned atab[512];     // 2 A-tables (hi-only), 16x32 f16
    __shared__ float red[BLOCK / 64];

    const unsigned tid = threadIdx.x;
    const int b = blockIdx.x;
    const float* __restrict__ srcr = g_sr + (size_t)b * DIM;
    const float* __restrict__ srci = g_si + (size_t)b * DIM;

    // ---- gate matrices U = RZ @ RY @ RX ----
    if (tid < NGAT) {
        const float tx = g_params[tid * 3 + 0];
        const float ty = g_params[tid * 3 + 1];
        const float tz = g_params[tid * 3 + 2];
        const float cx = cosf(0.5f * tx), sx = sinf(0.5f * tx);
        const float cy = cosf(0.5f * ty), sy = sinf(0.5f * ty);
        const float cz = cosf(0.5f * tz), sz = sinf(0.5f * tz);
        const float a00r = cy * cx,  a00i = sy * sx;
        const float a01r = -sy * cx, a01i = -cy * sx;
        const float a10r = sy * cx,  a10i = -cy * sx;
        const float a11r = cy * cx,  a11i = -sy * sx;
        gm[tid * 8 + 0] = cz * a00r + sz * a00i;
        gm[tid * 8 + 1] = cz * a00i - sz * a00r;
        gm[tid * 8 + 2] = cz * a01r + sz * a01i;
        gm[tid * 8 + 3] = cz * a01i - sz * a01r;
        gm[tid * 8 + 4] = cz * a10r - sz * a10i;
        gm[tid * 8 + 5] = cz * a10i + sz * a10r;
        gm[tid * 8 + 6] = cz * a11r - sz * a11i;
        gm[tid * 8 + 7] = cz * a11i + sz * a11r;
    }

    // writer-frame base for this thread (computed ONCE; T twist folded in).
    // twist cols are multiples of 4 -> b128 quads stay contiguous in e.
    const unsigned lane0 = tid & 63u, wid0 = tid >> 6;
    const unsigned n0 = lane0 & 15u, q0 = lane0 >> 4;
    unsigned twv = 0;
    #pragma unroll
    for (int k = 0; k < 4; ++k) twv ^= ((n0 >> k) & 1u) ? PL.tw[k] : 0u;
    #pragma unroll
    for (int k = 0; k < 4; ++k) twv ^= ((wid0 >> k) & 1u) ? PL.tw[6 + k] : 0u;
    const unsigned bnq = ((wid0 << 10) ^ (n0 << 4) ^ (q0 << 2) ^ twv) << 2;

    // ---- staging: global fp32 -> packed f16 in Lambda_0 layout ----
    unsigned bb = 0;
    #pragma unroll
    for (int k = 0; k < 10; ++k) bb ^= ((tid >> k) & 1u) ? PL.stB[k + 2] : 0u;
    #pragma unroll
    for (int it = 0; it < 4; ++it) {
        const int x = (int)tid * 4 + it * 4096;
        const f4 r4 = *(const f4*)(srcr + x);
        const f4 i4 = *(const f4*)(srci + x);
        const unsigned base = bb ^ ((it & 1) ? PL.stB[12] : 0u) ^ ((it & 2) ? PL.stB[13] : 0u);
        *(unsigned*)(lds + base) = pk_rn(r4.x, i4.x);
        *(unsigned*)(lds + (base ^ PL.stB[0])) = pk_rn(r4.y, i4.y);
        *(unsigned*)(lds + (base ^ PL.stB[1])) = pk_rn(r4.z, i4.z);
        *(unsigned*)(lds + (base ^ (PL.stB[0] ^ PL.stB[1]))) = pk_rn(r4.w, i4.w);
    }

    mfma_batch<0>(lds, gm, atab, bnq);
    mfma_batch<1>(lds, gm, atab, bnq);
    mfma_batch<2>(lds, gm, atab, bnq);
    mfma_batch<3>(lds, gm, atab, bnq);
    mfma_batch<4>(lds, gm, atab, bnq);
    mfma_batch<5>(lds, gm, atab, bnq);
    mfma_batch<6>(lds, gm, atab, bnq);
    mfma_batch<7>(lds, gm, atab, bnq);
    mfma_batch<8>(lds, gm, atab, bnq);
    mfma_batch<9>(lds, gm, atab, bnq);
    mfma_batch<10>(lds, gm, atab, bnq);

    float acc = tail_batch(lds, gm, g_hw);

    // ---- reduce ----
    #pragma unroll
    for (int off = 32; off > 0; off >>= 1) acc += __shfl_down(acc, off);
    const int lane = tid & 63, wid = tid >> 6;
    if (lane == 0) red[wid] = acc;
    __syncthreads();
    if (tid == 0) {
        float s = 0.0f;
        #pragma unroll
        for (int k = 0; k < BLOCK / 64; ++k) s += red[k];
        g_out[b] = s + g_hb[0];
    }
}

extern "C" void kernel_launch(void* const* d_in, const int* in_sizes, int n_in,
                              void* d_out, int out_size, void* d_ws, size_t ws_size,
                              hipStream_t stream) {
    const float* sr = (const float*)d_in[0];
    const float* si = (const float*)d_in[1];
    const float* vp = (const float*)d_in[2];
    const float* hw = (const float*)d_in[3];
    const float* hb = (const float*)d_in[4];
    float* out = (float*)d_out;

    dim3 grid(out_size);          // 1024 batch elements, one block each
    dim3 block(BLOCK);
    size_t shmem = (size_t)DIM * 4;  // 64 KiB dynamic LDS (packed f16 amps)
    qsim_kernel<<<grid, block, shmem, stream>>>(sr, si, vp, hw, hb, out);
}

// Round 9
// 190.899 us; speedup vs baseline: 1.3378x; 1.0077x over previous
//
#include <hip/hip_runtime.h>

#define NW 14
#define NL 3
#define NGAT 42            // 3 layers x 14 rotation gates
#define DIM 16384          // 2^14 amplitudes
#define BLOCK 1024

// ---------------------------------------------------------------------------
// Round 20: r19 base (fp16 @ 4B/amp, hi-only W, 95us steady, absmax 1.22e-4)
// + A-TABLE SWIZZLE. Diagnosis: atab b128 reads at dword n*16+q*4 are an
// 8-way bank conflict (16-lane phase: q const, n=0..15 -> banks 16n+4q mod 32
// = two 4-bank groups, 8 lanes each; b128 floor is 2-way). 22 reads/thread
// ~ 40k of the measured ~62k conflict-cycles/CU — and the twist never
// touches atab, explaining why SQ_LDS_BANK_CONFLICT was insensitive to all
// state-layout changes (r16-r19). At 77% occupancy the LDS pipe is now the
// critical resource (~80% of wall incl. conflicts), so this should pay.
// Fix: store (m,ein) at m*16 + (ein ^ (m&12)); read with tix =
// (n<<4) + ((q<<2) ^ (n&12)). ein[1:0] intact -> b128 quads contiguous;
// per-phase banks become 16*n0 + 4*(q^n[3:2]) -> exact 2-way floor.
// Build writes remain conflict-free (same address set, permuted).
// Arithmetic bit-identical to r19.
// ---------------------------------------------------------------------------

typedef float        f4  __attribute__((ext_vector_type(4)));
typedef _Float16     h8  __attribute__((ext_vector_type(8)));
typedef unsigned int u4v __attribute__((ext_vector_type(4)));

constexpr int parity14(int v) { int p = 0; for (int i = 0; i < NW; ++i) p ^= (v >> i) & 1; return p; }
constexpr int hibit(int v) { int h = -1; for (int i = 0; i < NW; ++i) if ((v >> i) & 1) h = i; return h; }

struct Lin { int col[NW]; };

constexpr int lin_apply(const Lin& M, int x) {
    int r = 0;
    for (int i = 0; i < NW; ++i) if ((x >> i) & 1) r ^= M.col[i];
    return r;
}
constexpr Lin lin_inverse(const Lin& M) {
    int E[NW] = {}, P[NW] = {};
    for (int i = 0; i < NW; ++i) {
        int v = M.col[i], p = 1 << i;
        while (v) {
            int h = hibit(v);
            if (!E[h]) { E[h] = v; P[h] = p; break; }
            v ^= E[h]; p ^= P[h];
        }
    }
    Lin R{};
    for (int i = 0; i < NW; ++i) {
        int v = 1 << i, p = 0;
        while (v) { int h = hibit(v); v ^= E[h]; p ^= P[h]; }
        R.col[i] = p;
    }
    return R;
}
constexpr Lin lin_compose(const Lin& A, const Lin& B) {
    Lin R{};
    for (int i = 0; i < NW; ++i) R.col[i] = lin_apply(A, B.col[i]);
    return R;
}

// ---- algorithm structure (frames, cosets, duality corrections) ----
struct Alg {
    int ngates[12];
    int gidx[12][4];
    int basisA[12][4];
    int comboA[12][16];
    int cvecA[12][10];
    Lin F[12];
    int Rf[NW];         // final Z-row masks for the tail features
};

constexpr Alg make_alg() {
    Alg A{};
    int R[NW] = {}, C[NW] = {};
    for (int p = 0; p < NW; ++p) { R[p] = 1 << p; C[p] = 1 << p; }
    int bi = 0;
    for (int l = 0; l < NL; ++l) {
        const int sizes[4] = {4, 4, 4, 2};
        int w0 = 0;
        for (int s = 0; s < 4; ++s) {
            const int ng = sizes[s];
            A.ngates[bi] = ng;
            int basis[4] = {}, rr[4] = {};
            for (int j = 0; j < ng; ++j) {
                int w = w0 + j, p = 13 - w;
                basis[j] = C[p];
                rr[j] = R[p];
                A.gidx[bi][j] = l * NW + w;
            }
            // echelon for independence
            int ech[4] = {}; int ne = 0;
            for (int j = 0; j < ng; ++j) {
                int v = basis[j];
                bool ch = true;
                while (ch) { ch = false;
                    for (int k = 0; k < ne; ++k)
                        if (v && ((v >> hibit(ech[k])) & 1)) { v ^= ech[k]; ch = true; }
                }
                ech[ne++] = v;
            }
            // pad to 4 from null space of gate parity masks
            int nb = ng;
            for (int cand = 1; cand < DIM && nb < 4; ++cand) {
                bool ok = true;
                for (int j = 0; j < ng; ++j) if (parity14(cand & rr[j])) { ok = false; break; }
                if (!ok) continue;
                int v = cand;
                bool ch = true;
                while (ch) { ch = false;
                    for (int k = 0; k < ne; ++k)
                        if (v && ((v >> hibit(ech[k])) & 1)) { v ^= ech[k]; ch = true; }
                }
                if (v) { basis[nb++] = cand; ech[ne++] = v; }
            }
            // pivots & non-pivot positions
            int piv[4] = {};
            for (int k = 0; k < 4; ++k) piv[k] = hibit(ech[k]);
            for (int a = 0; a < 4; ++a)
                for (int b2 = a + 1; b2 < 4; ++b2)
                    if (piv[b2] < piv[a]) { int t = piv[a]; piv[a] = piv[b2]; piv[b2] = t; }
            int npp[10] = {}; int nn = 0;
            for (int bit = 0; bit < NW; ++bit) {
                bool isp = false;
                for (int k = 0; k < 4; ++k) if (piv[k] == bit) isp = true;
                if (!isp) npp[nn++] = bit;
            }
            // duality-corrected coset directions
            for (int k = 0; k < 10; ++k) {
                int c = 1 << npp[k];
                for (int j = 0; j < ng; ++j) if ((rr[j] >> npp[k]) & 1) c ^= basis[j];
                A.cvecA[bi][k] = c;
            }
            for (int e = 0; e < 16; ++e) {
                int v = 0;
                for (int j = 0; j < 4; ++j) if ((e >> j) & 1) v ^= basis[j];
                A.comboA[bi][e] = v;
            }
            for (int j = 0; j < 4; ++j) A.basisA[bi][j] = basis[j];
            for (int j = 0; j < 4; ++j) A.F[bi].col[j] = basis[j];
            for (int k = 0; k < 10; ++k) A.F[bi].col[4 + k] = A.cvecA[bi][k];
            w0 += ng;
            ++bi;
        }
        // CNOT chain (w,w+1) w=0..12 then (13,0)
        for (int w = 0; w < NW; ++w) {
            int c = w, t = (w + 1) % NW;
            int pc = 13 - c, pt = 13 - t;
            R[pt] ^= R[pc];
            C[pc] ^= C[pt];
        }
    }
    for (int p = 0; p < NW; ++p) A.Rf[p] = R[p];
    return A;
}

// ---- compile-time bank-conflict twist search (b32 rank-5 model) ----
struct Twist { unsigned t[10]; };

// rank of width-bit vectors over GF(2)
constexpr int rankv(const int* v, int nv, int width) {
    int basis[8] = {};
    int rk = 0;
    for (int i = 0; i < nv; ++i) {
        int x = v[i] & ((1 << width) - 1);
        for (int b = width - 1; b >= 0; --b) {
            if (!((x >> b) & 1)) continue;
            if (basis[b]) { x ^= basis[b]; continue; }
            basis[b] = x; ++rk; break;
        }
    }
    return rk;
}

// bank-image of pre-vector u (packed (e,y) space): idx bits [4:0]
constexpr int img5(int u, const unsigned* t) {
    int r = u & 31;
    for (int k = 0; k < 10; ++k) if ((u >> (4 + k)) & 1) r ^= (int)t[k];
    return r;
}

// b32 readers conflict-free iff the 5 half-wave lane-direction vectors span
// the 5-bit bank space (rank 5; 2-way-IN-PHASE is NOT free for b32).
// HARD: writer b128 quad-bank span {4^(t0>>2), t1>>2, t2>>2, t3>>2} rank 3.
constexpr int eval5(const unsigned* t, const int (*preR)[5], const int* preS) {
    {
        int w[4] = { 4 ^ (int)((t[0] >> 2) & 7), (int)((t[1] >> 2) & 7),
                     (int)((t[2] >> 2) & 7), (int)((t[3] >> 2) & 7) };
        if (rankv(w, 4, 3) < 3) return -1;
    }
    int sc = 0;
    for (int r = 1; r < 12; ++r) {
        int v[5];
        for (int i = 0; i < 5; ++i) v[i] = img5(preR[r][i], t);
        sc += rankv(v, 5, 5);
    }
    {
        int v[5];
        for (int i = 0; i < 5; ++i) v[i] = img5(preS[i], t);
        sc += rankv(v, 5, 5);
    }
    return sc;   // max 12*5 = 60
}

constexpr Twist find_twist() {
    Alg A = make_alg();
    int preR[12][5] = {};
    for (int r = 1; r < 12; ++r) {
        Lin Fi = lin_inverse(A.F[r - 1]);
        for (int k = 0; k < 4; ++k) preR[r][k] = lin_apply(Fi, A.cvecA[r][k]);
        preR[r][4] = lin_apply(Fi, A.basisA[r][2]);
    }
    int preS[5] = {};
    {
        Lin F0i = lin_inverse(A.F[0]);
        for (int k = 0; k < 5; ++k) preS[k] = lin_apply(F0i, 1 << (k + 2));
    }
    Twist best{};
    for (int k = 0; k < 10; ++k) best.t[k] = 0;
    int bs = eval5(best.t, preR, preS);
    unsigned x = 0x9E3779B9u;
    for (int s = 0; s < 2; ++s) {
        Twist cur{};
        if (s == 0) {
            for (int k = 0; k < 10; ++k) cur.t[k] = 0;
        } else {
            for (int k = 0; k < 10; ++k) {
                x = x * 1664525u + 1013904223u;
                const unsigned m = (k == 0) ? 3u : 7u;
                cur.t[k] = ((x >> 13) & m) << 2;
            }
        }
        int cs = eval5(cur.t, preR, preS);
        for (int pass = 0; pass < 2; ++pass) {
            for (int k = 0; k < 10; ++k) {
                unsigned bc = cur.t[k];
                int bv = cs;
                const unsigned lim = (k == 0) ? 16u : 32u;   // t0: bits[3:2] only
                for (unsigned c = 0; c < lim; c += 4) {
                    cur.t[k] = c;
                    const int e = eval5(cur.t, preR, preS);
                    if (e > bv) { bv = e; bc = c; }
                }
                cur.t[k] = bc;
                cs = bv;
            }
        }
        if (cs > bs) { bs = cs; best = cur; }
    }
    return best;
}

constexpr Twist TW = find_twist();

struct BatchP {
    int ngates;
    int gidx[4];
    unsigned rdy[10];   // byte: 4 * Lambda_{r-1}(cvec_r[k])  (y-bit directions)
    unsigned rde[16];   // byte: 4 * Lambda_{r-1}(combo_r[e]) (e-directions)
};
struct PlanP {
    BatchP b[12];
    unsigned stB[14];   // staging: byte 4 * Lambda_0(1<<bit)
    unsigned ykey[14];  // tail: parity mask over key = y | (q<<10)
    int zsel[14];       // tail: Walsh index from basis[0,1] parities
    unsigned tw[10];    // T twist columns (idx units, multiples of 4)
};

constexpr PlanP make_planp() {
    Alg A = make_alg();
    PlanP P{};
    for (int bi = 0; bi < 12; ++bi) {
        P.b[bi].ngates = A.ngates[bi];
        for (int j = 0; j < 4; ++j) P.b[bi].gidx[j] = A.gidx[bi][j];
    }
    // T: packed(e, y) -> idx = e ^ (y<<4) ^ twist(y)
    Lin T{};
    for (int j = 0; j < 4; ++j) T.col[j] = 1 << j;
    for (int k = 0; k < 10; ++k) T.col[4 + k] = (1 << (4 + k)) ^ (int)TW.t[k];

    // Lambda_w = T o F_w^{-1}; staging uses Lambda_0, reader r uses Lambda_{r-1}
    {
        Lin L0 = lin_compose(T, lin_inverse(A.F[0]));
        for (int bit = 0; bit < NW; ++bit) P.stB[bit] = (unsigned)lin_apply(L0, 1 << bit) * 4u;
    }
    for (int r = 1; r < 12; ++r) {
        Lin Lw = lin_compose(T, lin_inverse(A.F[r - 1]));
        for (int k = 0; k < 10; ++k) P.b[r].rdy[k] = (unsigned)lin_apply(Lw, A.cvecA[r][k]) * 4u;
        for (int e = 0; e < 16; ++e) P.b[r].rde[e] = (unsigned)lin_apply(Lw, A.comboA[r][e]) * 4u;
    }
    for (int w = 0; w < NW; ++w) {
        int zrw = A.Rf[13 - w];
        unsigned ym = 0;
        for (int k = 0; k < 10; ++k) ym |= (unsigned)parity14(A.cvecA[11][k] & zrw) << k;
        int qm = parity14(A.basisA[11][2] & zrw) | (parity14(A.basisA[11][3] & zrw) << 1);
        P.ykey[w] = ym | ((unsigned)qm << 10);
        P.zsel[w] = parity14(A.basisA[11][0] & zrw) | (parity14(A.basisA[11][1] & zrw) << 1);
    }
    for (int k = 0; k < 10; ++k) P.tw[k] = TW.t[k];
    return P;
}

constexpr PlanP PL = make_planp();

// per-tile byte offsets: t-bits are y-bits 4,5 -> idx bits 8,9 -> byte<<2,
// plus their twist columns (idx units -> byte = idx<<2)
constexpr unsigned TILE_OFF[4] = {
    0u,
    (1u << 10) ^ (PL.tw[4] << 2),
    (1u << 11) ^ (PL.tw[5] << 2),
    (1u << 10) ^ (1u << 11) ^ ((PL.tw[4] ^ PL.tw[5]) << 2)
};

// fp32 (r,i) -> packed f16 dword, round-to-nearest-even (unbiased)
__device__ __forceinline__ unsigned pk_rn(float r, float i) {
    const unsigned hr = (unsigned)__builtin_bit_cast(unsigned short, (_Float16)r);
    const unsigned hi = (unsigned)__builtin_bit_cast(unsigned short, (_Float16)i);
    return hr | (hi << 16);
}
// packed f16 dword -> fp32 (r,i)
__device__ __forceinline__ float2 up(unsigned d) {
    float2 c;
    c.x = (float)__builtin_bit_cast(_Float16, (unsigned short)(d & 0xffffu));
    c.y = (float)__builtin_bit_cast(_Float16, (unsigned short)(d >> 16));
    return c;
}

__device__ __forceinline__ f4 mfh(u4v a, u4v b, f4 c) {
    return __builtin_amdgcn_mfma_f32_16x16x32_f16(
        __builtin_bit_cast(h8, a), __builtin_bit_cast(h8, b), c, 0, 0, 0);
}

// scattered-read base for reader batch B: XOR-select over y-bits (n,wid) and
// q-part; per-tile t adds rdy[4]/rdy[5]; 4 entries at {0, rde1, rde2, rde3}.
#define RD_SREP(B)                                                     \
    unsigned srep = 0;                                                 \
    srep ^= (n & 1u)   ? B.rdy[0] : 0u;                                \
    srep ^= (n & 2u)   ? B.rdy[1] : 0u;                                \
    srep ^= (n & 4u)   ? B.rdy[2] : 0u;                                \
    srep ^= (n & 8u)   ? B.rdy[3] : 0u;                                \
    srep ^= (wid & 1u) ? B.rdy[6] : 0u;                                \
    srep ^= (wid & 2u) ? B.rdy[7] : 0u;                                \
    srep ^= (wid & 4u) ? B.rdy[8] : 0u;                                \
    srep ^= (wid & 8u) ? B.rdy[9] : 0u;                                \
    srep ^= (q & 1u)   ? B.rde[4] : 0u;                                \
    srep ^= (q & 2u)   ? B.rde[8] : 0u;

template <int BI>
__device__ __forceinline__ void mfma_batch(char* __restrict__ lds, const float* __restrict__ gm,
                                           unsigned* __restrict__ atab, const unsigned bnq) {
    constexpr BatchP B = PL.b[BI];
    const unsigned tid = threadIdx.x;
    const unsigned lane = tid & 63u, wid = tid >> 6;
    const unsigned n = lane & 15u, q = lane >> 4;

    __syncthreads();   // prev batch stores visible; prev atab reads done

    // ---- A-table build (threads 0..255), f16 HI-ONLY, SWIZZLED layout ----
    // store (m, ein) at m*16 + (ein ^ (m&12)): ein[1:0] intact (b128 quads
    // contiguous), ein[3:2] XOR m[3:2] -> read phases hit 2-way floor.
    if (tid < 256) {
        const unsigned m = tid >> 4, ein = tid & 15u;
        float wr = 1.f, wi = 0.f;
        #pragma unroll
        for (int j = 0; j < 4; ++j) {
            if (j < B.ngates) {
                const unsigned mj = (m >> j) & 1u, ej = (ein >> j) & 1u;
                const float ur = gm[B.gidx[j] * 8 + (int)(mj * 4u + ej * 2u)];
                const float ui = gm[B.gidx[j] * 8 + (int)(mj * 4u + ej * 2u) + 1];
                const float nr = wr * ur - wi * ui;
                const float ni = wr * ui + wi * ur;
                wr = nr; wi = ni;
            }
        }
        if (B.ngates < 4 && (((m ^ ein) >> B.ngates) != 0u)) { wr = 0.f; wi = 0.f; }
        const unsigned o = m * 16u + (ein ^ (m & 12u));
        atab[o]        = pk_rn(wr, -wi);   // (Wr, -Wi) -> real output
        atab[256 + o]  = pk_rn(wi, wr);    // (Wi,  Wr) -> imag output
    }

    // ---- phase A: pure loads (state IS the f16 B-fragment) ----
    u4v bfr[4];
    if constexpr (BI == 0) {
        #pragma unroll
        for (int t = 0; t < 4; ++t) {
            bfr[t] = *(const u4v*)(lds + (bnq ^ TILE_OFF[t]));
        }
    } else {
        RD_SREP(B)
        #pragma unroll
        for (int t = 0; t < 4; ++t) {
            const unsigned st = srep ^ ((t & 1) ? B.rdy[4] : 0u) ^ ((t & 2) ? B.rdy[5] : 0u);
            const unsigned c0 = *(const unsigned*)(lds + st);
            const unsigned c1 = *(const unsigned*)(lds + (st ^ B.rde[1]));
            const unsigned c2 = *(const unsigned*)(lds + (st ^ B.rde[2]));
            const unsigned c3 = *(const unsigned*)(lds + (st ^ B.rde[3]));
            u4v v; v.x = c0; v.y = c1; v.z = c2; v.w = c3;
            bfr[t] = v;
        }
    }

    __syncthreads();   // all reads done + atab ready

    // ---- phase B: 2 mfma/tile + RNE pack + 1 clean b128 store/tile ----
    const unsigned tix = (n << 4) + (((q << 2) ^ (n & 12u)));
    const u4v A0 = *(const u4v*)&atab[tix];
    const u4v A1 = *(const u4v*)&atab[256 + tix];

    #pragma unroll
    for (int t = 0; t < 4; ++t) {
        f4 ar = {0.f, 0.f, 0.f, 0.f};
        f4 ai = {0.f, 0.f, 0.f, 0.f};
        ar = mfh(A0, bfr[t], ar);
        ai = mfh(A1, bfr[t], ai);
        u4v s;
        s.x = pk_rn(ar.x, ai.x);
        s.y = pk_rn(ar.y, ai.y);
        s.z = pk_rn(ar.z, ai.z);
        s.w = pk_rn(ar.w, ai.w);
        *(u4v*)(lds + (bnq ^ TILE_OFF[t])) = s;
    }
}

// complex 2x2 butterfly
#define BFC(A, B_, ua, ub) { const float2 t0 = A, t1 = B_; \
    A.x  = ua.x * t0.x - ua.y * t0.y + ua.z * t1.x - ua.w * t1.y; \
    A.y  = ua.x * t0.y + ua.y * t0.x + ua.z * t1.y + ua.w * t1.x; \
    B_.x = ub.x * t0.x - ub.y * t0.y + ub.z * t1.x - ub.w * t1.y; \
    B_.y = ub.x * t0.y + ub.y * t0.x + ub.z * t1.y + ub.w * t1.x; }

__device__ __forceinline__ float tail_batch(char* __restrict__ lds, const float* __restrict__ gm,
                                            const float* __restrict__ g_hw) {
    constexpr BatchP B = PL.b[11];   // ngates == 2
    const unsigned tid = threadIdx.x;
    const unsigned lane = tid & 63u, wid = tid >> 6;
    const unsigned n = lane & 15u, q = lane >> 4;
    __syncthreads();
    const f4 u0a = *(const f4*)&gm[B.gidx[0] * 8];
    const f4 u0b = *(const f4*)&gm[B.gidx[0] * 8 + 4];
    const f4 u1a = *(const f4*)&gm[B.gidx[1] * 8];
    const f4 u1b = *(const f4*)&gm[B.gidx[1] * 8 + 4];
    float hwv[NW];
    #pragma unroll
    for (int w = 0; w < NW; ++w) hwv[w] = g_hw[w];
    float acc = 0.f;
    RD_SREP(B)
    #pragma unroll
    for (int t = 0; t < 4; ++t) {
        const unsigned st = srep ^ ((t & 1) ? B.rdy[4] : 0u) ^ ((t & 2) ? B.rdy[5] : 0u);
        float2 c0 = up(*(const unsigned*)(lds + st));
        float2 c1 = up(*(const unsigned*)(lds + (st ^ B.rde[1])));
        float2 c2 = up(*(const unsigned*)(lds + (st ^ B.rde[2])));
        float2 c3 = up(*(const unsigned*)(lds + (st ^ B.rde[3])));
        BFC(c0, c1, u0a, u0b)  BFC(c2, c3, u0a, u0b)   // gate 0: slot bit 0
        BFC(c0, c2, u1a, u1b)  BFC(c1, c3, u1a, u1b)   // gate 1: slot bit 1
        const float p0 = c0.x * c0.x + c0.y * c0.y;
        const float p1 = c1.x * c1.x + c1.y * c1.y;
        const float p2 = c2.x * c2.x + c2.y * c2.y;
        const float p3 = c3.x * c3.x + c3.y * c3.y;
        const float sa = p0 + p1, sb = p0 - p1, sc = p2 + p3, sd = p2 - p3;
        const float W4[4] = {sa + sc, sb + sd, sa - sc, sb - sd};
        const unsigned y = (wid << 6) | ((unsigned)t << 4) | n;
        const unsigned key = y | (q << 10);
        #pragma unroll
        for (int w = 0; w < NW; ++w) {
            const unsigned sg = ((unsigned)__popc(key & PL.ykey[w])) << 31;
            const float s = __uint_as_float(__float_as_uint(hwv[w]) ^ sg);
            acc += W4[PL.zsel[w]] * s;
        }
    }
    return acc;
}

__global__ __launch_bounds__(BLOCK, 8) void qsim_kernel(
    const float* __restrict__ g_sr, const float* __restrict__ g_si,
    const float* __restrict__ g_params, const float* __restrict__ g_hw,
    const float* __restrict__ g_hb, float* __restrict__ g_out)
{
    extern __shared__ char lds[];                    // 16384 packed-f16 amps (64 KiB)
    __shared__ __align__(16) float gm[NGAT * 8];
    __shared__ __align__(16) unsigned atab[512];     // 2 A-tables (hi-only), swizzled
    __shared__ float red[BLOCK / 64];

    const unsigned tid = threadIdx.x;
    const int b = blockIdx.x;
    const float* __restrict__ srcr = g_sr + (size_t)b * DIM;
    const float* __restrict__ srci = g_si + (size_t)b * DIM;

    // ---- gate matrices U = RZ @ RY @ RX ----
    if (tid < NGAT) {
        const float tx = g_params[tid * 3 + 0];
        const float ty = g_params[tid * 3 + 1];
        const float tz = g_params[tid * 3 + 2];
        const float cx = cosf(0.5f * tx), sx = sinf(0.5f * tx);
        const float cy = cosf(0.5f * ty), sy = sinf(0.5f * ty);
        const float cz = cosf(0.5f * tz), sz = sinf(0.5f * tz);
        const float a00r = cy * cx,  a00i = sy * sx;
        const float a01r = -sy * cx, a01i = -cy * sx;
        const float a10r = sy * cx,  a10i = -cy * sx;
        const float a11r = cy * cx,  a11i = -sy * sx;
        gm[tid * 8 + 0] = cz * a00r + sz * a00i;
        gm[tid * 8 + 1] = cz * a00i - sz * a00r;
        gm[tid * 8 + 2] = cz * a01r + sz * a01i;
        gm[tid * 8 + 3] = cz * a01i - sz * a01r;
        gm[tid * 8 + 4] = cz * a10r - sz * a10i;
        gm[tid * 8 + 5] = cz * a10i + sz * a10r;
        gm[tid * 8 + 6] = cz * a11r - sz * a11i;
        gm[tid * 8 + 7] = cz * a11i + sz * a11r;
    }

    // writer-frame base for this thread (computed ONCE; T twist folded in).
    // twist cols are multiples of 4 -> b128 quads stay contiguous in e.
    const unsigned lane0 = tid & 63u, wid0 = tid >> 6;
    const unsigned n0 = lane0 & 15u, q0 = lane0 >> 4;
    unsigned twv = 0;
    #pragma unroll
    for (int k = 0; k < 4; ++k) twv ^= ((n0 >> k) & 1u) ? PL.tw[k] : 0u;
    #pragma unroll
    for (int k = 0; k < 4; ++k) twv ^= ((wid0 >> k) & 1u) ? PL.tw[6 + k] : 0u;
    const unsigned bnq = ((wid0 << 10) ^ (n0 << 4) ^ (q0 << 2) ^ twv) << 2;

    // ---- staging: global fp32 -> packed f16 in Lambda_0 layout ----
    unsigned bb = 0;
    #pragma unroll
    for (int k = 0; k < 10; ++k) bb ^= ((tid >> k) & 1u) ? PL.stB[k + 2] : 0u;
    #pragma unroll
    for (int it = 0; it < 4; ++it) {
        const int x = (int)tid * 4 + it * 4096;
        const f4 r4 = *(const f4*)(srcr + x);
        const f4 i4 = *(const f4*)(srci + x);
        const unsigned base = bb ^ ((it & 1) ? PL.stB[12] : 0u) ^ ((it & 2) ? PL.stB[13] : 0u);
        *(unsigned*)(lds + base) = pk_rn(r4.x, i4.x);
        *(unsigned*)(lds + (base ^ PL.stB[0])) = pk_rn(r4.y, i4.y);
        *(unsigned*)(lds + (base ^ PL.stB[1])) = pk_rn(r4.z, i4.z);
        *(unsigned*)(lds + (base ^ (PL.stB[0] ^ PL.stB[1]))) = pk_rn(r4.w, i4.w);
    }

    mfma_batch<0>(lds, gm, atab, bnq);
    mfma_batch<1>(lds, gm, atab, bnq);
    mfma_batch<2>(lds, gm, atab, bnq);
    mfma_batch<3>(lds, gm, atab, bnq);
    mfma_batch<4>(lds, gm, atab, bnq);
    mfma_batch<5>(lds, gm, atab, bnq);
    mfma_batch<6>(lds, gm, atab, bnq);
    mfma_batch<7>(lds, gm, atab, bnq);
    mfma_batch<8>(lds, gm, atab, bnq);
    mfma_batch<9>(lds, gm, atab, bnq);
    mfma_batch<10>(lds, gm, atab, bnq);

    float acc = tail_batch(lds, gm, g_hw);

    // ---- reduce ----
    #pragma unroll
    for (int off = 32; off > 0; off >>= 1) acc += __shfl_down(acc, off);
    const int lane = tid & 63, wid = tid >> 6;
    if (lane == 0) red[wid] = acc;
    __syncthreads();
    if (tid == 0) {
        float s = 0.0f;
        #pragma unroll
        for (int k = 0; k < BLOCK / 64; ++k) s += red[k];
        g_out[b] = s + g_hb[0];
    }
}

extern "C" void kernel_launch(void* const* d_in, const int* in_sizes, int n_in,
                              void* d_out, int out_size, void* d_ws, size_t ws_size,
                              hipStream_t stream) {
    const float* sr = (const float*)d_in[0];
    const float* si = (const float*)d_in[1];
    const float* vp = (const float*)d_in[2];
    const float* hw = (const float*)d_in[3];
    const float* hb = (const float*)d_in[4];
    float* out = (float*)d_out;

    dim3 grid(out_size);          // 1024 batch elements, one block each
    dim3 block(BLOCK);
    size_t shmem = (size_t)DIM * 4;  // 64 KiB dynamic LDS (packed f16 amps)
    qsim_kernel<<<grid, block, shmem, stream>>>(sr, si, vp, hw, hb, out);
}

// Round 10
// 186.812 us; speedup vs baseline: 1.3671x; 1.0219x over previous
//
#include <hip/hip_runtime.h>

#define NW 14
#define NL 3
#define NGAT 42            // 3 layers x 14 rotation gates
#define DIM 16384          // 2^14 amplitudes
#define BLOCK 1024

// ---------------------------------------------------------------------------
// Round 21: r20 base (94us steady, absmax 1.22e-4) + SINGLE-PAIR FUSION of
// batches 0+1 (layer-0 wires 0-7). Purpose: isolate the r18 pair-fusion
// algebra with minimal blast radius. At layer 0 R=C=identity, so all frames
// are unit vectors and duality corrections provably vanish — the cleanest
// instance of the two-sided transform:
//   stage 1: D1 = mfh(A=state-frag, B=Wa-table)  — the table read at the
//     B-operand address pattern o = c*16+k yields B[k][c]=Wa[c][k], so
//     D1[eB][eA'] = sum_eA M[eA][eB]*Wa[eA'][eA] = (Wa*M)^T. The D-layout
//     (row=(l>>4)*4+reg, col=l&15) IS the B-fragment layout (kpair,col),
//     so pk(D1) feeds stage 2 with zero data movement.
//   stage 2: D2 = mfh(A=Wb-table, B=pk(D1)):
//     D2[eB'][eA'] = sum_eB Wb[eB'][eB] P^T[eB][eA'] = (Wa(x)Wb applied).
// Write frame Fp0: e-slots = basisB, n-slots = basisA, outer unchanged.
// Plan deltas ONLY: staging->Fin, pair0 block, batch-2 reader frame->Fp0.
// Batches 2-10 + tail byte-identical to r20. Pair-0 reads/writes are
// per-thread-private clean b128s -> no mid-batch WAR barrier; 2 barriers
// replace the old 4. Decision: pass -> extend to all pairs next round;
// fail -> pair algebra is broken, abandon permanently.
// ---------------------------------------------------------------------------

typedef float        f4  __attribute__((ext_vector_type(4)));
typedef _Float16     h8  __attribute__((ext_vector_type(8)));
typedef unsigned int u4v __attribute__((ext_vector_type(4)));

constexpr int parity14(int v) { int p = 0; for (int i = 0; i < NW; ++i) p ^= (v >> i) & 1; return p; }
constexpr int hibit(int v) { int h = -1; for (int i = 0; i < NW; ++i) if ((v >> i) & 1) h = i; return h; }

struct Lin { int col[NW]; };

constexpr int lin_apply(const Lin& M, int x) {
    int r = 0;
    for (int i = 0; i < NW; ++i) if ((x >> i) & 1) r ^= M.col[i];
    return r;
}
constexpr Lin lin_inverse(const Lin& M) {
    int E[NW] = {}, P[NW] = {};
    for (int i = 0; i < NW; ++i) {
        int v = M.col[i], p = 1 << i;
        while (v) {
            int h = hibit(v);
            if (!E[h]) { E[h] = v; P[h] = p; break; }
            v ^= E[h]; p ^= P[h];
        }
    }
    Lin R{};
    for (int i = 0; i < NW; ++i) {
        int v = 1 << i, p = 0;
        while (v) { int h = hibit(v); v ^= E[h]; p ^= P[h]; }
        R.col[i] = p;
    }
    return R;
}
constexpr Lin lin_compose(const Lin& A, const Lin& B) {
    Lin R{};
    for (int i = 0; i < NW; ++i) R.col[i] = lin_apply(A, B.col[i]);
    return R;
}

// ---- algorithm structure (frames, cosets, duality corrections) ----
struct Alg {
    int ngates[12];
    int gidx[12][4];
    int basisA[12][4];
    int comboA[12][16];
    int cvecA[12][10];
    Lin F[12];
    int Rf[NW];         // final Z-row masks for the tail features
};

constexpr Alg make_alg() {
    Alg A{};
    int R[NW] = {}, C[NW] = {};
    for (int p = 0; p < NW; ++p) { R[p] = 1 << p; C[p] = 1 << p; }
    int bi = 0;
    for (int l = 0; l < NL; ++l) {
        const int sizes[4] = {4, 4, 4, 2};
        int w0 = 0;
        for (int s = 0; s < 4; ++s) {
            const int ng = sizes[s];
            A.ngates[bi] = ng;
            int basis[4] = {}, rr[4] = {};
            for (int j = 0; j < ng; ++j) {
                int w = w0 + j, p = 13 - w;
                basis[j] = C[p];
                rr[j] = R[p];
                A.gidx[bi][j] = l * NW + w;
            }
            // echelon for independence
            int ech[4] = {}; int ne = 0;
            for (int j = 0; j < ng; ++j) {
                int v = basis[j];
                bool ch = true;
                while (ch) { ch = false;
                    for (int k = 0; k < ne; ++k)
                        if (v && ((v >> hibit(ech[k])) & 1)) { v ^= ech[k]; ch = true; }
                }
                ech[ne++] = v;
            }
            // pad to 4 from null space of gate parity masks
            int nb = ng;
            for (int cand = 1; cand < DIM && nb < 4; ++cand) {
                bool ok = true;
                for (int j = 0; j < ng; ++j) if (parity14(cand & rr[j])) { ok = false; break; }
                if (!ok) continue;
                int v = cand;
                bool ch = true;
                while (ch) { ch = false;
                    for (int k = 0; k < ne; ++k)
                        if (v && ((v >> hibit(ech[k])) & 1)) { v ^= ech[k]; ch = true; }
                }
                if (v) { basis[nb++] = cand; ech[ne++] = v; }
            }
            // pivots & non-pivot positions
            int piv[4] = {};
            for (int k = 0; k < 4; ++k) piv[k] = hibit(ech[k]);
            for (int a = 0; a < 4; ++a)
                for (int b2 = a + 1; b2 < 4; ++b2)
                    if (piv[b2] < piv[a]) { int t = piv[a]; piv[a] = piv[b2]; piv[b2] = t; }
            int npp[10] = {}; int nn = 0;
            for (int bit = 0; bit < NW; ++bit) {
                bool isp = false;
                for (int k = 0; k < 4; ++k) if (piv[k] == bit) isp = true;
                if (!isp) npp[nn++] = bit;
            }
            // duality-corrected coset directions
            for (int k = 0; k < 10; ++k) {
                int c = 1 << npp[k];
                for (int j = 0; j < ng; ++j) if ((rr[j] >> npp[k]) & 1) c ^= basis[j];
                A.cvecA[bi][k] = c;
            }
            for (int e = 0; e < 16; ++e) {
                int v = 0;
                for (int j = 0; j < 4; ++j) if ((e >> j) & 1) v ^= basis[j];
                A.comboA[bi][e] = v;
            }
            for (int j = 0; j < 4; ++j) A.basisA[bi][j] = basis[j];
            for (int j = 0; j < 4; ++j) A.F[bi].col[j] = basis[j];
            for (int k = 0; k < 10; ++k) A.F[bi].col[4 + k] = A.cvecA[bi][k];
            w0 += ng;
            ++bi;
        }
        // CNOT chain (w,w+1) w=0..12 then (13,0)
        for (int w = 0; w < NW; ++w) {
            int c = w, t = (w + 1) % NW;
            int pc = 13 - c, pt = 13 - t;
            R[pt] ^= R[pc];
            C[pc] ^= C[pt];
        }
    }
    for (int p = 0; p < NW; ++p) A.Rf[p] = R[p];
    return A;
}

// ---- pair-0 frames (layer 0: R=C=identity, corrections vanish) ----
// Fin (staging / pair-0 read): e-slots = basisA (wires 0-3), n-slots =
// basisB (wires 4-7), outer = remaining units.
constexpr Lin make_fin() {
    Lin F{};
    for (int j = 0; j < 4; ++j) F.col[j]     = 1 << (13 - j);  // bA: C at wire j
    for (int j = 0; j < 4; ++j) F.col[4 + j] = 1 << (9 - j);   // bB: C at wire 4+j
    for (int k = 0; k < 6; ++k) F.col[8 + k] = 1 << (5 - k);   // outer units
    return F;
}
// Fp0 (pair-0 write): e-slots = basisB (eB'), n-slots = basisA (eA').
constexpr Lin make_fp0() {
    Lin F{};
    for (int j = 0; j < 4; ++j) F.col[j]     = 1 << (9 - j);
    for (int j = 0; j < 4; ++j) F.col[4 + j] = 1 << (13 - j);
    for (int k = 0; k < 6; ++k) F.col[8 + k] = 1 << (5 - k);
    return F;
}
constexpr Lin FIN = make_fin();
constexpr Lin FP0 = make_fp0();

// ---- compile-time bank-conflict twist search (b32 rank-5 model) ----
struct Twist { unsigned t[10]; };

constexpr int rankv(const int* v, int nv, int width) {
    int basis[8] = {};
    int rk = 0;
    for (int i = 0; i < nv; ++i) {
        int x = v[i] & ((1 << width) - 1);
        for (int b = width - 1; b >= 0; --b) {
            if (!((x >> b) & 1)) continue;
            if (basis[b]) { x ^= basis[b]; continue; }
            basis[b] = x; ++rk; break;
        }
    }
    return rk;
}

constexpr int img5(int u, const unsigned* t) {
    int r = u & 31;
    for (int k = 0; k < 10; ++k) if ((u >> (4 + k)) & 1) r ^= (int)t[k];
    return r;
}

// readers: batches 2..11 (batch 2 reads FP0) + tail + staging (FIN)
constexpr int eval5(const unsigned* t, const int (*preR)[5], const int* preS) {
    {
        int w[4] = { 4 ^ (int)((t[0] >> 2) & 7), (int)((t[1] >> 2) & 7),
                     (int)((t[2] >> 2) & 7), (int)((t[3] >> 2) & 7) };
        if (rankv(w, 4, 3) < 3) return -1;
    }
    int sc = 0;
    for (int r = 2; r < 12; ++r) {
        int v[5];
        for (int i = 0; i < 5; ++i) v[i] = img5(preR[r][i], t);
        sc += rankv(v, 5, 5);
    }
    {
        int v[5];
        for (int i = 0; i < 5; ++i) v[i] = img5(preS[i], t);
        sc += rankv(v, 5, 5);
    }
    return sc;   // max 11*5 = 55
}

constexpr Twist find_twist() {
    Alg A = make_alg();
    int preR[12][5] = {};
    for (int r = 2; r < 12; ++r) {
        Lin Fprev = (r == 2) ? FP0 : A.F[r - 1];
        Lin Fi = lin_inverse(Fprev);
        for (int k = 0; k < 4; ++k) preR[r][k] = lin_apply(Fi, A.cvecA[r][k]);
        preR[r][4] = lin_apply(Fi, A.basisA[r][2]);
    }
    int preS[5] = {};
    {
        Lin F0i = lin_inverse(FIN);
        for (int k = 0; k < 5; ++k) preS[k] = lin_apply(F0i, 1 << (k + 2));
    }
    Twist best{};
    for (int k = 0; k < 10; ++k) best.t[k] = 0;
    int bs = eval5(best.t, preR, preS);
    unsigned x = 0x9E3779B9u;
    for (int s = 0; s < 2; ++s) {
        Twist cur{};
        if (s == 0) {
            for (int k = 0; k < 10; ++k) cur.t[k] = 0;
        } else {
            for (int k = 0; k < 10; ++k) {
                x = x * 1664525u + 1013904223u;
                const unsigned m = (k == 0) ? 3u : 7u;
                cur.t[k] = ((x >> 13) & m) << 2;
            }
        }
        int cs = eval5(cur.t, preR, preS);
        for (int pass = 0; pass < 2; ++pass) {
            for (int k = 0; k < 10; ++k) {
                unsigned bc = cur.t[k];
                int bv = cs;
                const unsigned lim = (k == 0) ? 16u : 32u;   // t0: bits[3:2] only
                for (unsigned c = 0; c < lim; c += 4) {
                    cur.t[k] = c;
                    const int e = eval5(cur.t, preR, preS);
                    if (e > bv) { bv = e; bc = c; }
                }
                cur.t[k] = bc;
                cs = bv;
            }
        }
        if (cs > bs) { bs = cs; best = cur; }
    }
    return best;
}

constexpr Twist TW = find_twist();

struct BatchP {
    int ngates;
    int gidx[4];
    unsigned rdy[10];   // byte: 4 * Lambda_{r-1}(cvec_r[k])  (y-bit directions)
    unsigned rde[16];   // byte: 4 * Lambda_{r-1}(combo_r[e]) (e-directions)
};
struct PlanP {
    BatchP b[12];
    unsigned stB[14];   // staging: byte 4 * (T o FIN^-1)(1<<bit)
    unsigned ykey[14];  // tail: parity mask over key = y | (q<<10)
    int zsel[14];       // tail: Walsh index from basis[0,1] parities
    unsigned tw[10];    // T twist columns (idx units, multiples of 4)
};

constexpr PlanP make_planp() {
    Alg A = make_alg();
    PlanP P{};
    for (int bi = 0; bi < 12; ++bi) {
        P.b[bi].ngates = A.ngates[bi];
        for (int j = 0; j < 4; ++j) P.b[bi].gidx[j] = A.gidx[bi][j];
    }
    // T: packed(e, y) -> idx = e ^ (y<<4) ^ twist(y)
    Lin T{};
    for (int j = 0; j < 4; ++j) T.col[j] = 1 << j;
    for (int k = 0; k < 10; ++k) T.col[4 + k] = (1 << (4 + k)) ^ (int)TW.t[k];

    // staging uses FIN; batch 2 reads FP0; batches 3..11 read F[r-1]
    {
        Lin L0 = lin_compose(T, lin_inverse(FIN));
        for (int bit = 0; bit < NW; ++bit) P.stB[bit] = (unsigned)lin_apply(L0, 1 << bit) * 4u;
    }
    for (int r = 2; r < 12; ++r) {
        Lin Fprev = (r == 2) ? FP0 : A.F[r - 1];
        Lin Lw = lin_compose(T, lin_inverse(Fprev));
        for (int k = 0; k < 10; ++k) P.b[r].rdy[k] = (unsigned)lin_apply(Lw, A.cvecA[r][k]) * 4u;
        for (int e = 0; e < 16; ++e) P.b[r].rde[e] = (unsigned)lin_apply(Lw, A.comboA[r][e]) * 4u;
    }
    for (int w = 0; w < NW; ++w) {
        int zrw = A.Rf[13 - w];
        unsigned ym = 0;
        for (int k = 0; k < 10; ++k) ym |= (unsigned)parity14(A.cvecA[11][k] & zrw) << k;
        int qm = parity14(A.basisA[11][2] & zrw) | (parity14(A.basisA[11][3] & zrw) << 1);
        P.ykey[w] = ym | ((unsigned)qm << 10);
        P.zsel[w] = parity14(A.basisA[11][0] & zrw) | (parity14(A.basisA[11][1] & zrw) << 1);
    }
    for (int k = 0; k < 10; ++k) P.tw[k] = TW.t[k];
    return P;
}

constexpr PlanP PL = make_planp();

// per-tile byte offsets: t-bits are y-bits 4,5 -> idx bits 8,9 -> byte<<2,
// plus their twist columns (idx units -> byte = idx<<2)
constexpr unsigned TILE_OFF[4] = {
    0u,
    (1u << 10) ^ (PL.tw[4] << 2),
    (1u << 11) ^ (PL.tw[5] << 2),
    (1u << 10) ^ (1u << 11) ^ ((PL.tw[4] ^ PL.tw[5]) << 2)
};

// fp32 (r,i) -> packed f16 dword, round-to-nearest-even (unbiased)
__device__ __forceinline__ unsigned pk_rn(float r, float i) {
    const unsigned hr = (unsigned)__builtin_bit_cast(unsigned short, (_Float16)r);
    const unsigned hi = (unsigned)__builtin_bit_cast(unsigned short, (_Float16)i);
    return hr | (hi << 16);
}
// packed f16 dword -> fp32 (r,i)
__device__ __forceinline__ float2 up(unsigned d) {
    float2 c;
    c.x = (float)__builtin_bit_cast(_Float16, (unsigned short)(d & 0xffffu));
    c.y = (float)__builtin_bit_cast(_Float16, (unsigned short)(d >> 16));
    return c;
}

__device__ __forceinline__ f4 mfh(u4v a, u4v b, f4 c) {
    return __builtin_amdgcn_mfma_f32_16x16x32_f16(
        __builtin_bit_cast(h8, a), __builtin_bit_cast(h8, b), c, 0, 0, 0);
}

// scattered-read base for reader batch B: XOR-select over y-bits (n,wid) and
// q-part; per-tile t adds rdy[4]/rdy[5]; 4 entries at {0, rde1, rde2, rde3}.
#define RD_SREP(B)                                                     \
    unsigned srep = 0;                                                 \
    srep ^= (n & 1u)   ? B.rdy[0] : 0u;                                \
    srep ^= (n & 2u)   ? B.rdy[1] : 0u;                                \
    srep ^= (n & 4u)   ? B.rdy[2] : 0u;                                \
    srep ^= (n & 8u)   ? B.rdy[3] : 0u;                                \
    srep ^= (wid & 1u) ? B.rdy[6] : 0u;                                \
    srep ^= (wid & 2u) ? B.rdy[7] : 0u;                                \
    srep ^= (wid & 4u) ? B.rdy[8] : 0u;                                \
    srep ^= (wid & 8u) ? B.rdy[9] : 0u;                                \
    srep ^= (q & 1u)   ? B.rde[4] : 0u;                                \
    srep ^= (q & 2u)   ? B.rde[8] : 0u;

// ---- fused pair 0: layer-0 wires 0-7, clean per-thread b128 read/write ----
__device__ __forceinline__ void mfma_pair0(char* __restrict__ lds, const float* __restrict__ gm,
                                           unsigned* __restrict__ atab, const unsigned bnq) {
    const unsigned tid = threadIdx.x;
    const unsigned lane = tid & 63u, wid = tid >> 6;
    const unsigned n = lane & 15u, q = lane >> 4;

    __syncthreads();   // staging visible

    // build BOTH W tables (hi-only, swizzled): Wa (gates 0-3) -> atab[0..511],
    // Wb (gates 4-7) -> atab[512..1023]
    if (tid < 512) {
        const unsigned idx = tid & 255u;
        const unsigned m = idx >> 4, ein = idx & 15u;
        const int gbase = (tid < 256) ? 0 : 4;
        float wr = 1.f, wi = 0.f;
        #pragma unroll
        for (int j = 0; j < 4; ++j) {
            const unsigned mj = (m >> j) & 1u, ej = (ein >> j) & 1u;
            const float ur = gm[(gbase + j) * 8 + (int)(mj * 4u + ej * 2u)];
            const float ui = gm[(gbase + j) * 8 + (int)(mj * 4u + ej * 2u) + 1];
            const float nr = wr * ur - wi * ui;
            const float ni = wr * ui + wi * ur;
            wr = nr; wi = ni;
        }
        const unsigned o = m * 16u + (ein ^ (m & 12u));
        unsigned* __restrict__ tab = atab + ((tid < 256) ? 0 : 512);
        tab[o]        = pk_rn(wr, -wi);   // (Wr, -Wi)
        tab[256 + o]  = pk_rn(wi, wr);    // (Wi,  Wr)
    }

    // clean b128 reads: fragment M[eA = q*4+dword][eB = n] (per-thread-private
    // slots: the write below targets the SAME addresses -> no WAR barrier)
    u4v bfr[4];
    #pragma unroll
    for (int t = 0; t < 4; ++t) {
        bfr[t] = *(const u4v*)(lds + (bnq ^ TILE_OFF[t]));
    }

    __syncthreads();   // tables ready

    const unsigned tix = (n << 4) + (((q << 2) ^ (n & 12u)));
    const u4v War = *(const u4v*)&atab[tix];         // stage-1 B-operand
    const u4v Wai = *(const u4v*)&atab[256 + tix];
    const u4v Wbr = *(const u4v*)&atab[512 + tix];   // stage-2 A-operand
    const u4v Wbi = *(const u4v*)&atab[768 + tix];

    #pragma unroll
    for (int t = 0; t < 4; ++t) {
        // stage 1: D1 = (Wa * M)^T  (A = state, B = Wa-table)
        f4 dr = {0.f, 0.f, 0.f, 0.f};
        f4 di = {0.f, 0.f, 0.f, 0.f};
        dr = mfh(bfr[t], War, dr);
        di = mfh(bfr[t], Wai, di);
        u4v pb;
        pb.x = pk_rn(dr.x, di.x);
        pb.y = pk_rn(dr.y, di.y);
        pb.z = pk_rn(dr.z, di.z);
        pb.w = pk_rn(dr.w, di.w);
        // stage 2: D2 = Wb * D1  (A = Wb-table, B = packed D1)
        f4 ar = {0.f, 0.f, 0.f, 0.f};
        f4 ai = {0.f, 0.f, 0.f, 0.f};
        ar = mfh(Wbr, pb, ar);
        ai = mfh(Wbi, pb, ai);
        u4v s;
        s.x = pk_rn(ar.x, ai.x);
        s.y = pk_rn(ar.y, ai.y);
        s.z = pk_rn(ar.z, ai.z);
        s.w = pk_rn(ar.w, ai.w);
        *(u4v*)(lds + (bnq ^ TILE_OFF[t])) = s;
    }
}

template <int BI>
__device__ __forceinline__ void mfma_batch(char* __restrict__ lds, const float* __restrict__ gm,
                                           unsigned* __restrict__ atab, const unsigned bnq) {
    constexpr BatchP B = PL.b[BI];
    const unsigned tid = threadIdx.x;
    const unsigned lane = tid & 63u, wid = tid >> 6;
    const unsigned n = lane & 15u, q = lane >> 4;

    __syncthreads();   // prev batch stores visible; prev atab reads done

    // ---- A-table build (threads 0..255), f16 HI-ONLY, SWIZZLED layout ----
    if (tid < 256) {
        const unsigned m = tid >> 4, ein = tid & 15u;
        float wr = 1.f, wi = 0.f;
        #pragma unroll
        for (int j = 0; j < 4; ++j) {
            if (j < B.ngates) {
                const unsigned mj = (m >> j) & 1u, ej = (ein >> j) & 1u;
                const float ur = gm[B.gidx[j] * 8 + (int)(mj * 4u + ej * 2u)];
                const float ui = gm[B.gidx[j] * 8 + (int)(mj * 4u + ej * 2u) + 1];
                const float nr = wr * ur - wi * ui;
                const float ni = wr * ui + wi * ur;
                wr = nr; wi = ni;
            }
        }
        if (B.ngates < 4 && (((m ^ ein) >> B.ngates) != 0u)) { wr = 0.f; wi = 0.f; }
        const unsigned o = m * 16u + (ein ^ (m & 12u));
        atab[o]        = pk_rn(wr, -wi);   // (Wr, -Wi) -> real output
        atab[256 + o]  = pk_rn(wi, wr);    // (Wi,  Wr) -> imag output
    }

    // ---- phase A: pure loads (state IS the f16 B-fragment) ----
    u4v bfr[4];
    {
        RD_SREP(B)
        #pragma unroll
        for (int t = 0; t < 4; ++t) {
            const unsigned st = srep ^ ((t & 1) ? B.rdy[4] : 0u) ^ ((t & 2) ? B.rdy[5] : 0u);
            const unsigned c0 = *(const unsigned*)(lds + st);
            const unsigned c1 = *(const unsigned*)(lds + (st ^ B.rde[1]));
            const unsigned c2 = *(const unsigned*)(lds + (st ^ B.rde[2]));
            const unsigned c3 = *(const unsigned*)(lds + (st ^ B.rde[3]));
            u4v v; v.x = c0; v.y = c1; v.z = c2; v.w = c3;
            bfr[t] = v;
        }
    }

    __syncthreads();   // all reads done + atab ready

    // ---- phase B: 2 mfma/tile + RNE pack + 1 clean b128 store/tile ----
    const unsigned tix = (n << 4) + (((q << 2) ^ (n & 12u)));
    const u4v A0 = *(const u4v*)&atab[tix];
    const u4v A1 = *(const u4v*)&atab[256 + tix];

    #pragma unroll
    for (int t = 0; t < 4; ++t) {
        f4 ar = {0.f, 0.f, 0.f, 0.f};
        f4 ai = {0.f, 0.f, 0.f, 0.f};
        ar = mfh(A0, bfr[t], ar);
        ai = mfh(A1, bfr[t], ai);
        u4v s;
        s.x = pk_rn(ar.x, ai.x);
        s.y = pk_rn(ar.y, ai.y);
        s.z = pk_rn(ar.z, ai.z);
        s.w = pk_rn(ar.w, ai.w);
        *(u4v*)(lds + (bnq ^ TILE_OFF[t])) = s;
    }
}

// complex 2x2 butterfly
#define BFC(A, B_, ua, ub) { const float2 t0 = A, t1 = B_; \
    A.x  = ua.x * t0.x - ua.y * t0.y + ua.z * t1.x - ua.w * t1.y; \
    A.y  = ua.x * t0.y + ua.y * t0.x + ua.z * t1.y + ua.w * t1.x; \
    B_.x = ub.x * t0.x - ub.y * t0.y + ub.z * t1.x - ub.w * t1.y; \
    B_.y = ub.x * t0.y + ub.y * t0.x + ub.z * t1.y + ub.w * t1.x; }

__device__ __forceinline__ float tail_batch(char* __restrict__ lds, const float* __restrict__ gm,
                                            const float* __restrict__ g_hw) {
    constexpr BatchP B = PL.b[11];   // ngates == 2
    const unsigned tid = threadIdx.x;
    const unsigned lane = tid & 63u, wid = tid >> 6;
    const unsigned n = lane & 15u, q = lane >> 4;
    __syncthreads();
    const f4 u0a = *(const f4*)&gm[B.gidx[0] * 8];
    const f4 u0b = *(const f4*)&gm[B.gidx[0] * 8 + 4];
    const f4 u1a = *(const f4*)&gm[B.gidx[1] * 8];
    const f4 u1b = *(const f4*)&gm[B.gidx[1] * 8 + 4];
    float hwv[NW];
    #pragma unroll
    for (int w = 0; w < NW; ++w) hwv[w] = g_hw[w];
    float acc = 0.f;
    RD_SREP(B)
    #pragma unroll
    for (int t = 0; t < 4; ++t) {
        const unsigned st = srep ^ ((t & 1) ? B.rdy[4] : 0u) ^ ((t & 2) ? B.rdy[5] : 0u);
        float2 c0 = up(*(const unsigned*)(lds + st));
        float2 c1 = up(*(const unsigned*)(lds + (st ^ B.rde[1])));
        float2 c2 = up(*(const unsigned*)(lds + (st ^ B.rde[2])));
        float2 c3 = up(*(const unsigned*)(lds + (st ^ B.rde[3])));
        BFC(c0, c1, u0a, u0b)  BFC(c2, c3, u0a, u0b)   // gate 0: slot bit 0
        BFC(c0, c2, u1a, u1b)  BFC(c1, c3, u1a, u1b)   // gate 1: slot bit 1
        const float p0 = c0.x * c0.x + c0.y * c0.y;
        const float p1 = c1.x * c1.x + c1.y * c1.y;
        const float p2 = c2.x * c2.x + c2.y * c2.y;
        const float p3 = c3.x * c3.x + c3.y * c3.y;
        const float sa = p0 + p1, sb = p0 - p1, sc = p2 + p3, sd = p2 - p3;
        const float W4[4] = {sa + sc, sb + sd, sa - sc, sb - sd};
        const unsigned y = (wid << 6) | ((unsigned)t << 4) | n;
        const unsigned key = y | (q << 10);
        #pragma unroll
        for (int w = 0; w < NW; ++w) {
            const unsigned sg = ((unsigned)__popc(key & PL.ykey[w])) << 31;
            const float s = __uint_as_float(__float_as_uint(hwv[w]) ^ sg);
            acc += W4[PL.zsel[w]] * s;
        }
    }
    return acc;
}

__global__ __launch_bounds__(BLOCK, 8) void qsim_kernel(
    const float* __restrict__ g_sr, const float* __restrict__ g_si,
    const float* __restrict__ g_params, const float* __restrict__ g_hw,
    const float* __restrict__ g_hb, float* __restrict__ g_out)
{
    extern __shared__ char lds[];                    // 16384 packed-f16 amps (64 KiB)
    __shared__ __align__(16) float gm[NGAT * 8];
    __shared__ __align__(16) unsigned atab[1024];    // Wa(512) + Wb(512) for pair0; batches use [0..511]
    __shared__ float red[BLOCK / 64];

    const unsigned tid = threadIdx.x;
    const int b = blockIdx.x;
    const float* __restrict__ srcr = g_sr + (size_t)b * DIM;
    const float* __restrict__ srci = g_si + (size_t)b * DIM;

    // ---- gate matrices U = RZ @ RY @ RX ----
    if (tid < NGAT) {
        const float tx = g_params[tid * 3 + 0];
        const float ty = g_params[tid * 3 + 1];
        const float tz = g_params[tid * 3 + 2];
        const float cx = cosf(0.5f * tx), sx = sinf(0.5f * tx);
        const float cy = cosf(0.5f * ty), sy = sinf(0.5f * ty);
        const float cz = cosf(0.5f * tz), sz = sinf(0.5f * tz);
        const float a00r = cy * cx,  a00i = sy * sx;
        const float a01r = -sy * cx, a01i = -cy * sx;
        const float a10r = sy * cx,  a10i = -cy * sx;
        const float a11r = cy * cx,  a11i = -sy * sx;
        gm[tid * 8 + 0] = cz * a00r + sz * a00i;
        gm[tid * 8 + 1] = cz * a00i - sz * a00r;
        gm[tid * 8 + 2] = cz * a01r + sz * a01i;
        gm[tid * 8 + 3] = cz * a01i - sz * a01r;
        gm[tid * 8 + 4] = cz * a10r - sz * a10i;
        gm[tid * 8 + 5] = cz * a10i + sz * a10r;
        gm[tid * 8 + 6] = cz * a11r - sz * a11i;
        gm[tid * 8 + 7] = cz * a11i + sz * a11r;
    }

    // writer-frame base for this thread (computed ONCE; T twist folded in).
    const unsigned lane0 = tid & 63u, wid0 = tid >> 6;
    const unsigned n0 = lane0 & 15u, q0 = lane0 >> 4;
    unsigned twv = 0;
    #pragma unroll
    for (int k = 0; k < 4; ++k) twv ^= ((n0 >> k) & 1u) ? PL.tw[k] : 0u;
    #pragma unroll
    for (int k = 0; k < 4; ++k) twv ^= ((wid0 >> k) & 1u) ? PL.tw[6 + k] : 0u;
    const unsigned bnq = ((wid0 << 10) ^ (n0 << 4) ^ (q0 << 2) ^ twv) << 2;

    // ---- staging: global fp32 -> packed f16 in (T o FIN^-1) layout ----
    unsigned bb = 0;
    #pragma unroll
    for (int k = 0; k < 10; ++k) bb ^= ((tid >> k) & 1u) ? PL.stB[k + 2] : 0u;
    #pragma unroll
    for (int it = 0; it < 4; ++it) {
        const int x = (int)tid * 4 + it * 4096;
        const f4 r4 = *(const f4*)(srcr + x);
        const f4 i4 = *(const f4*)(srci + x);
        const unsigned base = bb ^ ((it & 1) ? PL.stB[12] : 0u) ^ ((it & 2) ? PL.stB[13] : 0u);
        *(unsigned*)(lds + base) = pk_rn(r4.x, i4.x);
        *(unsigned*)(lds + (base ^ PL.stB[0])) = pk_rn(r4.y, i4.y);
        *(unsigned*)(lds + (base ^ PL.stB[1])) = pk_rn(r4.z, i4.z);
        *(unsigned*)(lds + (base ^ (PL.stB[0] ^ PL.stB[1]))) = pk_rn(r4.w, i4.w);
    }

    mfma_pair0(lds, gm, atab, bnq);      // fused batches 0+1 (wires 0-7, layer 0)
    mfma_batch<2>(lds, gm, atab, bnq);
    mfma_batch<3>(lds, gm, atab, bnq);
    mfma_batch<4>(lds, gm, atab, bnq);
    mfma_batch<5>(lds, gm, atab, bnq);
    mfma_batch<6>(lds, gm, atab, bnq);
    mfma_batch<7>(lds, gm, atab, bnq);
    mfma_batch<8>(lds, gm, atab, bnq);
    mfma_batch<9>(lds, gm, atab, bnq);
    mfma_batch<10>(lds, gm, atab, bnq);

    float acc = tail_batch(lds, gm, g_hw);

    // ---- reduce ----
    #pragma unroll
    for (int off = 32; off > 0; off >>= 1) acc += __shfl_down(acc, off);
    const int lane = tid & 63, wid = tid >> 6;
    if (lane == 0) red[wid] = acc;
    __syncthreads();
    if (tid == 0) {
        float s = 0.0f;
        #pragma unroll
        for (int k = 0; k < BLOCK / 64; ++k) s += red[k];
        g_out[b] = s + g_hb[0];
    }
}

extern "C" void kernel_launch(void* const* d_in, const int* in_sizes, int n_in,
                              void* d_out, int out_size, void* d_ws, size_t ws_size,
                              hipStream_t stream) {
    const float* sr = (const float*)d_in[0];
    const float* si = (const float*)d_in[1];
    const float* vp = (const float*)d_in[2];
    const float* hw = (const float*)d_in[3];
    const float* hb = (const float*)d_in[4];
    float* out = (float*)d_out;

    dim3 grid(out_size);          // 1024 batch elements, one block each
    dim3 block(BLOCK);
    size_t shmem = (size_t)DIM * 4;  // 64 KiB dynamic LDS (packed f16 amps)
    qsim_kernel<<<grid, block, shmem, stream>>>(sr, si, vp, hw, hb, out);
}